// Round 1
// baseline (4819.932 us; speedup 1.0000x reference)
//
#include <hip/hip_runtime.h>
#include <math.h>

#define S_LEN 2048
#define D_DIM 2048
#define H_NUM 32
#define HD_DIM 64
#define FF_DIM 8192
#define QMAX 255.0f
#define NEGF (-3.402823466e+38f)

__device__ __forceinline__ float wred_sum(float v) {
#pragma unroll
  for (int o = 1; o < 64; o <<= 1) v += __shfl_xor(v, o, 64);
  return v;
}
__device__ __forceinline__ float wred_min(float v) {
#pragma unroll
  for (int o = 1; o < 64; o <<= 1) v = fminf(v, __shfl_xor(v, o, 64));
  return v;
}
__device__ __forceinline__ float wred_max(float v) {
#pragma unroll
  for (int o = 1; o < 64; o <<= 1) v = fmaxf(v, __shfl_xor(v, o, 64));
  return v;
}

// ---------------- LayerNorm + per-token fake quant (D=2048) ----------------
__global__ __launch_bounds__(256) void ln_quant(const float* __restrict__ x,
                                                const float* __restrict__ g,
                                                const float* __restrict__ bvec,
                                                float* __restrict__ out) {
  __shared__ float buf[D_DIM];
  __shared__ float red[8];
  const int row = blockIdx.x, tid = threadIdx.x;
  const float* xr = x + (size_t)row * D_DIM;
  float* orow = out + (size_t)row * D_DIM;

  float s = 0.f, ss = 0.f;
  for (int i = tid; i < D_DIM; i += 256) { float v = xr[i]; s += v; ss += v * v; }
  s = wred_sum(s); ss = wred_sum(ss);
  if ((tid & 63) == 0) { red[tid >> 6] = s; red[4 + (tid >> 6)] = ss; }
  __syncthreads();
  float mu = (red[0] + red[1] + red[2] + red[3]) / (float)D_DIM;
  float var = (red[4] + red[5] + red[6] + red[7]) / (float)D_DIM - mu * mu;
  float rstd = 1.0f / sqrtf(var + 1e-5f);
  __syncthreads();

  float mn = 0.f, mx = 0.f;
  for (int i = tid; i < D_DIM; i += 256) {
    float v = (xr[i] - mu) * rstd * g[i] + bvec[i];
    buf[i] = v;
    mn = fminf(mn, v); mx = fmaxf(mx, v);
  }
  mn = wred_min(mn); mx = wred_max(mx);
  if ((tid & 63) == 0) { red[tid >> 6] = mn; red[4 + (tid >> 6)] = mx; }
  __syncthreads();
  mn = fminf(fminf(red[0], red[1]), fminf(red[2], red[3]));
  mx = fmaxf(fmaxf(red[4], red[5]), fmaxf(red[6], red[7]));
  float scale = fmaxf((mx - mn) / QMAX, 1e-5f);
  float zp = rintf(-mn / scale);
  for (int i = tid; i < D_DIM; i += 256) {
    float v = buf[i];
    float q = fminf(fmaxf(rintf(v / scale) + zp, 0.f), QMAX);
    orow[i] = (q - zp) * scale;
  }
}

// ---------------- per-row (token) fake quant, in place; optional alpha/relu ----------------
__global__ __launch_bounds__(256) void act_quant(float* __restrict__ x, int N,
                                                 float alpha, int do_relu) {
  __shared__ float red[8];
  const int row = blockIdx.x, tid = threadIdx.x;
  float* xr = x + (size_t)row * N;
  float mn = 0.f, mx = 0.f;
  for (int i = tid; i < N; i += 256) {
    float v = xr[i] * alpha;
    if (do_relu) v = fmaxf(v, 0.f);
    mn = fminf(mn, v); mx = fmaxf(mx, v);
  }
  mn = wred_min(mn); mx = wred_max(mx);
  if ((tid & 63) == 0) { red[tid >> 6] = mn; red[4 + (tid >> 6)] = mx; }
  __syncthreads();
  mn = fminf(fminf(red[0], red[1]), fminf(red[2], red[3]));
  mx = fmaxf(fmaxf(red[4], red[5]), fmaxf(red[6], red[7]));
  float scale = fmaxf((mx - mn) / QMAX, 1e-5f);
  float zp = rintf(-mn / scale);
  for (int i = tid; i < N; i += 256) {
    float v = xr[i] * alpha;
    if (do_relu) v = fmaxf(v, 0.f);
    float q = fminf(fmaxf(rintf(v / scale) + zp, 0.f), QMAX);
    xr[i] = (q - zp) * scale;
  }
}

// ---------------- per-output-channel weight quant params ----------------
__global__ __launch_bounds__(256) void wparams(const float* __restrict__ W,
                                               float* __restrict__ sc,
                                               float* __restrict__ zp, int K) {
  __shared__ float red[8];
  const int row = blockIdx.x, tid = threadIdx.x;
  const float* wr = W + (size_t)row * K;
  float mn = 0.f, mx = 0.f;
  for (int i = tid; i < K; i += 256) { float v = wr[i]; mn = fminf(mn, v); mx = fmaxf(mx, v); }
  mn = wred_min(mn); mx = wred_max(mx);
  if ((tid & 63) == 0) { red[tid >> 6] = mn; red[4 + (tid >> 6)] = mx; }
  __syncthreads();
  if (tid == 0) {
    mn = fminf(fminf(red[0], red[1]), fminf(red[2], red[3]));
    mx = fmaxf(fmaxf(red[4], red[5]), fmaxf(red[6], red[7]));
    float s = fmaxf((mx - mn) / QMAX, 1e-5f);
    sc[row] = s;
    zp[row] = rintf(-mn / s);
  }
}

__device__ __forceinline__ float dqw(float w, float s, float z) {
  float q = fminf(fmaxf(rintf(w / s) + z, 0.f), QMAX);
  return (q - z) * s;
}

// ---------------- C[M,N] = A[M,K] @ fakequant(B[N,K])^T + bias (+res) ----------------
__global__ __launch_bounds__(256) void gemm_aq(
    const float* __restrict__ A, const float* __restrict__ B,
    const float* __restrict__ wsc, const float* __restrict__ wzp,
    const float* __restrict__ bias, const float* __restrict__ res,
    float* __restrict__ C, int M, int N, int K) {
  __shared__ float As[16][68];
  __shared__ float Bs[16][68];
  __shared__ float ssc[64], szp[64];
  const int tid = threadIdx.x;
  const int bm = blockIdx.y * 64, bn = blockIdx.x * 64;
  if (tid < 64) { ssc[tid] = wsc[bn + tid]; szp[tid] = wzp[bn + tid]; }
  __syncthreads();
  const int m4 = tid >> 2;          // 0..63
  const int kq4 = (tid & 3) * 4;    // 0,4,8,12
  const int ty = tid >> 4, tx = tid & 15;
  const float sB = ssc[m4], zB = szp[m4];
  float acc[4][4] = {};
  for (int k0 = 0; k0 < K; k0 += 16) {
    float4 av = *(const float4*)(A + (size_t)(bm + m4) * K + k0 + kq4);
    float4 bv = *(const float4*)(B + (size_t)(bn + m4) * K + k0 + kq4);
    As[kq4 + 0][m4] = av.x; As[kq4 + 1][m4] = av.y;
    As[kq4 + 2][m4] = av.z; As[kq4 + 3][m4] = av.w;
    Bs[kq4 + 0][m4] = dqw(bv.x, sB, zB); Bs[kq4 + 1][m4] = dqw(bv.y, sB, zB);
    Bs[kq4 + 2][m4] = dqw(bv.z, sB, zB); Bs[kq4 + 3][m4] = dqw(bv.w, sB, zB);
    __syncthreads();
#pragma unroll
    for (int kk = 0; kk < 16; ++kk) {
      float4 a4 = *(const float4*)&As[kk][ty * 4];
      float4 b4 = *(const float4*)&Bs[kk][tx * 4];
      float a[4] = {a4.x, a4.y, a4.z, a4.w};
      float b[4] = {b4.x, b4.y, b4.z, b4.w};
#pragma unroll
      for (int i = 0; i < 4; ++i)
#pragma unroll
        for (int j = 0; j < 4; ++j) acc[i][j] += a[i] * b[j];
    }
    __syncthreads();
  }
  float4 bv4 = *(const float4*)(bias + bn + tx * 4);
#pragma unroll
  for (int i = 0; i < 4; ++i) {
    int m = bm + ty * 4 + i;
    float4 o;
    o.x = acc[i][0] + bv4.x; o.y = acc[i][1] + bv4.y;
    o.z = acc[i][2] + bv4.z; o.w = acc[i][3] + bv4.w;
    if (res) {
      float4 rv = *(const float4*)(res + (size_t)m * N + bn + tx * 4);
      o.x += rv.x; o.y += rv.y; o.z += rv.z; o.w += rv.w;
    }
    *(float4*)(C + (size_t)m * N + bn + tx * 4) = o;
  }
}

// ---------------- attention pass A: per-row running max m and denom L ----------------
__global__ __launch_bounds__(256) void attn_ml(const float* __restrict__ Q,
                                               const float* __restrict__ Kmat,
                                               float* __restrict__ Mbuf,
                                               float* __restrict__ Lbuf) {
  __shared__ float qs[32][68];
  __shared__ float ks[64][68];
  const int h = blockIdx.y;
  const int i0 = blockIdx.x * 32;
  const int tid = threadIdx.x;
  for (int l = tid; l < 32 * 64; l += 256) {
    int r = l >> 6, d = l & 63;
    qs[r][d] = Q[(size_t)(i0 + r) * D_DIM + h * HD_DIM + d];
  }
  const int r = tid >> 3, jg = tid & 7;
  const int i = i0 + r;
  float mr = NEGF, lr = 0.f;
  const int jend = i0 + 31;
  for (int jt = 0; jt <= jend; jt += 64) {
    __syncthreads();
    for (int l = tid; l < 64 * 64; l += 256) {
      int rr = l >> 6, d = l & 63;
      ks[rr][d] = Kmat[(size_t)(jt + rr) * D_DIM + h * HD_DIM + d];
    }
    __syncthreads();
    float sv[8];
    float tmax = NEGF;
#pragma unroll
    for (int jj = 0; jj < 8; ++jj) {
      int jl = jg + jj * 8;
      int j = jt + jl;
      float s = NEGF;
      if (j <= i) {
        float a = 0.f;
#pragma unroll
        for (int d = 0; d < 64; d += 4) {
          float4 qa = *(const float4*)&qs[r][d];
          float4 kb = *(const float4*)&ks[jl][d];
          a += qa.x * kb.x + qa.y * kb.y + qa.z * kb.z + qa.w * kb.w;
        }
        s = a;
      }
      sv[jj] = s;
      tmax = fmaxf(tmax, s);
    }
    tmax = fmaxf(tmax, __shfl_xor(tmax, 1, 64));
    tmax = fmaxf(tmax, __shfl_xor(tmax, 2, 64));
    tmax = fmaxf(tmax, __shfl_xor(tmax, 4, 64));
    if (tmax > NEGF) {
      float mnew = fmaxf(mr, tmax);
      float sum = 0.f;
#pragma unroll
      for (int jj = 0; jj < 8; ++jj)
        sum += (sv[jj] > NEGF) ? expf(sv[jj] - mnew) : 0.f;
      sum += __shfl_xor(sum, 1, 64);
      sum += __shfl_xor(sum, 2, 64);
      sum += __shfl_xor(sum, 4, 64);
      lr = (mr == NEGF) ? sum : lr * expf(mr - mnew) + sum;
      mr = mnew;
    }
  }
  if (jg == 0) {
    Mbuf[(size_t)h * S_LEN + i] = mr;
    Lbuf[(size_t)h * S_LEN + i] = lr;
  }
}

// ---------------- attention pass B: ctx = quantprobs @ V ----------------
__global__ __launch_bounds__(256) void attn_pv(const float* __restrict__ Q,
                                               const float* __restrict__ Kmat,
                                               const float* __restrict__ V,
                                               const float* __restrict__ Mbuf,
                                               const float* __restrict__ Lbuf,
                                               float* __restrict__ Ctx) {
  __shared__ float qs[32][68];
  __shared__ float ks[64][68];
  __shared__ float vs[64][68];
  __shared__ float ps[32][68];
  const int h = blockIdx.y, i0 = blockIdx.x * 32, tid = threadIdx.x;
  for (int l = tid; l < 32 * 64; l += 256) {
    int r = l >> 6, d = l & 63;
    qs[r][d] = Q[(size_t)(i0 + r) * D_DIM + h * HD_DIM + d];
  }
  const int r = tid >> 3, jg = tid & 7;
  const int i = i0 + r;
  const float mi = Mbuf[(size_t)h * S_LEN + i];
  const float li = Lbuf[(size_t)h * S_LEN + i];
  const float scale_i = fmaxf((1.0f / li) / QMAX, 1e-5f);
  float acc[8] = {0.f, 0.f, 0.f, 0.f, 0.f, 0.f, 0.f, 0.f};
  const int jend = i0 + 31;
  for (int jt = 0; jt <= jend; jt += 64) {
    __syncthreads();
    for (int l = tid; l < 64 * 64; l += 256) {
      int rr = l >> 6, d = l & 63;
      ks[rr][d] = Kmat[(size_t)(jt + rr) * D_DIM + h * HD_DIM + d];
      vs[rr][d] = V[(size_t)(jt + rr) * D_DIM + h * HD_DIM + d];
    }
    __syncthreads();
#pragma unroll
    for (int jj = 0; jj < 8; ++jj) {
      int jl = jg + jj * 8;
      int j = jt + jl;
      float p = 0.f;
      if (j <= i) {
        float s = 0.f;
#pragma unroll
        for (int d = 0; d < 64; d += 4) {
          float4 qa = *(const float4*)&qs[r][d];
          float4 kb = *(const float4*)&ks[jl][d];
          s += qa.x * kb.x + qa.y * kb.y + qa.z * kb.z + qa.w * kb.w;
        }
        float e = expf(s - mi);
        float pr = e / li;
        float q8 = fminf(fmaxf(rintf(pr / scale_i), 0.f), QMAX);
        p = q8 * scale_i;
      }
      ps[r][jl] = p;
    }
    __syncthreads();
#pragma unroll 8
    for (int jl = 0; jl < 64; ++jl) {
      float pv = ps[r][jl];
      float4 v0 = *(const float4*)&vs[jl][jg * 8];
      float4 v1 = *(const float4*)&vs[jl][jg * 8 + 4];
      acc[0] += pv * v0.x; acc[1] += pv * v0.y; acc[2] += pv * v0.z; acc[3] += pv * v0.w;
      acc[4] += pv * v1.x; acc[5] += pv * v1.y; acc[6] += pv * v1.z; acc[7] += pv * v1.w;
    }
  }
  float4 o0 = {acc[0], acc[1], acc[2], acc[3]};
  float4 o1 = {acc[4], acc[5], acc[6], acc[7]};
  size_t base = (size_t)i * D_DIM + h * HD_DIM + jg * 8;
  *(float4*)&Ctx[base] = o0;
  *(float4*)&Ctx[base + 4] = o1;
}

extern "C" void kernel_launch(void* const* d_in, const int* in_sizes, int n_in,
                              void* d_out, int out_size, void* d_ws, size_t ws_size,
                              hipStream_t stream) {
  (void)in_sizes; (void)n_in; (void)out_size;
  const float* hs  = (const float*)d_in[0];
  // d_in[1] = attention_mask (causal; handled structurally)
  const float* Wq  = (const float*)d_in[2];
  const float* bq  = (const float*)d_in[3];
  const float* Wk  = (const float*)d_in[4];
  const float* bk  = (const float*)d_in[5];
  const float* Wv  = (const float*)d_in[6];
  const float* bv  = (const float*)d_in[7];
  const float* Wo  = (const float*)d_in[8];
  const float* bo  = (const float*)d_in[9];
  const float* g1  = (const float*)d_in[10];
  const float* be1 = (const float*)d_in[11];
  const float* W1  = (const float*)d_in[12];
  const float* bf1 = (const float*)d_in[13];
  const float* W2  = (const float*)d_in[14];
  const float* bf2 = (const float*)d_in[15];
  const float* g2  = (const float*)d_in[16];
  const float* be2 = (const float*)d_in[17];
  float* out = (float*)d_out;

  const size_t SD = (size_t)S_LEN * D_DIM;
  const size_t SF = (size_t)S_LEN * FF_DIM;
  float* f = (float*)d_ws;
  float* x1q = f; f += SD;
  float* qb  = f; f += SD;
  float* kb  = f; f += SD;
  float* vb  = f; f += SD;
  float* ctx = f; f += SD;
  float* h2  = f; f += SD;
  float* x2q = f; f += SD;
  float* f1  = f; f += SF;
  float* mb  = f; f += (size_t)H_NUM * S_LEN;
  float* lb  = f; f += (size_t)H_NUM * S_LEN;
  float* scq = f; f += D_DIM;  float* zpq = f; f += D_DIM;
  float* sck = f; f += D_DIM;  float* zpk = f; f += D_DIM;
  float* scv = f; f += D_DIM;  float* zpv = f; f += D_DIM;
  float* sco = f; f += D_DIM;  float* zpo = f; f += D_DIM;
  float* sc1 = f; f += FF_DIM; float* zp1 = f; f += FF_DIM;
  float* sc2 = f; f += D_DIM;  float* zp2 = f; f += D_DIM;
  size_t need = (size_t)(f - (float*)d_ws) * sizeof(float);
  if (ws_size < need) return;  // fail validation loudly rather than corrupt

  dim3 blk(256);

  ln_quant<<<S_LEN, blk, 0, stream>>>(hs, g1, be1, x1q);

  wparams<<<D_DIM, blk, 0, stream>>>(Wq, scq, zpq, D_DIM);
  wparams<<<D_DIM, blk, 0, stream>>>(Wk, sck, zpk, D_DIM);
  wparams<<<D_DIM, blk, 0, stream>>>(Wv, scv, zpv, D_DIM);
  wparams<<<D_DIM, blk, 0, stream>>>(Wo, sco, zpo, D_DIM);
  wparams<<<FF_DIM, blk, 0, stream>>>(W1, sc1, zp1, D_DIM);
  wparams<<<D_DIM, blk, 0, stream>>>(W2, sc2, zp2, FF_DIM);

  dim3 g22(D_DIM / 64, S_LEN / 64);
  gemm_aq<<<g22, blk, 0, stream>>>(x1q, Wq, scq, zpq, bq, nullptr, qb, S_LEN, D_DIM, D_DIM);
  gemm_aq<<<g22, blk, 0, stream>>>(x1q, Wk, sck, zpk, bk, nullptr, kb, S_LEN, D_DIM, D_DIM);
  gemm_aq<<<g22, blk, 0, stream>>>(x1q, Wv, scv, zpv, bv, nullptr, vb, S_LEN, D_DIM, D_DIM);

  act_quant<<<S_LEN, blk, 0, stream>>>(qb, D_DIM, 0.125f, 0);  // *SCALING then quant
  act_quant<<<S_LEN, blk, 0, stream>>>(kb, D_DIM, 1.0f, 0);
  act_quant<<<S_LEN, blk, 0, stream>>>(vb, D_DIM, 1.0f, 0);

  dim3 ga(S_LEN / 32, H_NUM);
  attn_ml<<<ga, blk, 0, stream>>>(qb, kb, mb, lb);
  attn_pv<<<ga, blk, 0, stream>>>(qb, kb, vb, mb, lb, ctx);

  act_quant<<<S_LEN, blk, 0, stream>>>(ctx, D_DIM, 1.0f, 0);
  gemm_aq<<<g22, blk, 0, stream>>>(ctx, Wo, sco, zpo, bo, hs, h2, S_LEN, D_DIM, D_DIM);

  ln_quant<<<S_LEN, blk, 0, stream>>>(h2, g2, be2, x2q);

  dim3 gff(FF_DIM / 64, S_LEN / 64);
  gemm_aq<<<gff, blk, 0, stream>>>(x2q, W1, sc1, zp1, bf1, nullptr, f1, S_LEN, FF_DIM, D_DIM);
  act_quant<<<S_LEN, blk, 0, stream>>>(f1, FF_DIM, 1.0f, 1);  // relu then quant
  gemm_aq<<<g22, blk, 0, stream>>>(f1, W2, sc2, zp2, bf2, h2, out, S_LEN, D_DIM, FF_DIM);
}

// Round 2
// 2141.857 us; speedup vs baseline: 2.2504x; 2.2504x over previous
//
#include <hip/hip_runtime.h>
#include <math.h>

#define S_LEN 2048
#define D_DIM 2048
#define H_NUM 32
#define HD_DIM 64
#define FF_DIM 8192
#define QMAX 255.0f
#define NEGF (-3.402823466e+38f)

typedef __attribute__((ext_vector_type(4))) float f32x4;
typedef __attribute__((ext_vector_type(8))) __bf16 bf16x8;
typedef unsigned short u16;

__device__ __forceinline__ u16 f32i_to_bf16(float v) {
  // v is an exact integer in [-255,255]: fp32 low 16 bits are zero -> exact bf16
  return (u16)(__float_as_uint(v) >> 16);
}

__device__ __forceinline__ float wred_sum(float v) {
#pragma unroll
  for (int o = 1; o < 64; o <<= 1) v += __shfl_xor(v, o, 64);
  return v;
}
__device__ __forceinline__ float wred_min(float v) {
#pragma unroll
  for (int o = 1; o < 64; o <<= 1) v = fminf(v, __shfl_xor(v, o, 64));
  return v;
}
__device__ __forceinline__ float wred_max(float v) {
#pragma unroll
  for (int o = 1; o < 64; o <<= 1) v = fmaxf(v, __shfl_xor(v, o, 64));
  return v;
}

__device__ __forceinline__ void gload_lds16(const void* g, void* l) {
  __builtin_amdgcn_global_load_lds(
      (__attribute__((address_space(1))) void*)(g),
      (__attribute__((address_space(3))) void*)(l), 16, 0, 0);
}

// ---- LayerNorm + per-token quant -> bf16 integer (q-zp) + row scale ----
__global__ __launch_bounds__(256) void ln_quant_bf16(const float* __restrict__ x,
                                                     const float* __restrict__ g,
                                                     const float* __restrict__ bvec,
                                                     u16* __restrict__ out,
                                                     float* __restrict__ srow) {
  __shared__ float buf[D_DIM];
  __shared__ float red[8];
  const int row = blockIdx.x, tid = threadIdx.x;
  const float* xr = x + (size_t)row * D_DIM;

  float s = 0.f, ss = 0.f;
  for (int i = tid; i < D_DIM; i += 256) { float v = xr[i]; s += v; ss += v * v; }
  s = wred_sum(s); ss = wred_sum(ss);
  if ((tid & 63) == 0) { red[tid >> 6] = s; red[4 + (tid >> 6)] = ss; }
  __syncthreads();
  float mu = (red[0] + red[1] + red[2] + red[3]) / (float)D_DIM;
  float var = (red[4] + red[5] + red[6] + red[7]) / (float)D_DIM - mu * mu;
  float rstd = 1.0f / sqrtf(var + 1e-5f);
  __syncthreads();

  float mn = 0.f, mx = 0.f;
  for (int i = tid; i < D_DIM; i += 256) {
    float v = (xr[i] - mu) * rstd * g[i] + bvec[i];
    buf[i] = v;
    mn = fminf(mn, v); mx = fmaxf(mx, v);
  }
  mn = wred_min(mn); mx = wred_max(mx);
  if ((tid & 63) == 0) { red[tid >> 6] = mn; red[4 + (tid >> 6)] = mx; }
  __syncthreads();
  mn = fminf(fminf(red[0], red[1]), fminf(red[2], red[3]));
  mx = fmaxf(fmaxf(red[4], red[5]), fmaxf(red[6], red[7]));
  float scale = fmaxf((mx - mn) / QMAX, 1e-5f);
  float zp = rintf(-mn / scale);
  if (tid == 0) srow[row] = scale;
  for (int i = tid; i < D_DIM; i += 256) {
    float q = fminf(fmaxf(rintf(buf[i] / scale) + zp, 0.f), QMAX);
    out[(size_t)row * D_DIM + i] = f32i_to_bf16(q - zp);
  }
}

// ---- fp32 row -> quant -> bf16 int + scale (optional relu) ----
__global__ __launch_bounds__(256) void act_quant_bf16(const float* __restrict__ x,
                                                      u16* __restrict__ out,
                                                      float* __restrict__ srow,
                                                      int N, int do_relu) {
  __shared__ float red[8];
  const int row = blockIdx.x, tid = threadIdx.x;
  const float* xr = x + (size_t)row * N;
  float mn = 0.f, mx = 0.f;
  for (int i = tid; i < N; i += 256) {
    float v = xr[i];
    if (do_relu) v = fmaxf(v, 0.f);
    mn = fminf(mn, v); mx = fmaxf(mx, v);
  }
  mn = wred_min(mn); mx = wred_max(mx);
  if ((tid & 63) == 0) { red[tid >> 6] = mn; red[4 + (tid >> 6)] = mx; }
  __syncthreads();
  mn = fminf(fminf(red[0], red[1]), fminf(red[2], red[3]));
  mx = fmaxf(fmaxf(red[4], red[5]), fmaxf(red[6], red[7]));
  float scale = fmaxf((mx - mn) / QMAX, 1e-5f);
  float zp = rintf(-mn / scale);
  if (tid == 0) srow[row] = scale;
  for (int i = tid; i < N; i += 256) {
    float v = xr[i];
    if (do_relu) v = fmaxf(v, 0.f);
    float q = fminf(fmaxf(rintf(v / scale) + zp, 0.f), QMAX);
    out[(size_t)row * N + i] = f32i_to_bf16(q - zp);
  }
}

// ---- per-row fp32 fake quant in place (q/k/v pre-attention) ----
__global__ __launch_bounds__(256) void act_quant(float* __restrict__ x, int N,
                                                 float alpha, int do_relu) {
  __shared__ float red[8];
  const int row = blockIdx.x, tid = threadIdx.x;
  float* xr = x + (size_t)row * N;
  float mn = 0.f, mx = 0.f;
  for (int i = tid; i < N; i += 256) {
    float v = xr[i] * alpha;
    if (do_relu) v = fmaxf(v, 0.f);
    mn = fminf(mn, v); mx = fmaxf(mx, v);
  }
  mn = wred_min(mn); mx = wred_max(mx);
  if ((tid & 63) == 0) { red[tid >> 6] = mn; red[4 + (tid >> 6)] = mx; }
  __syncthreads();
  mn = fminf(fminf(red[0], red[1]), fminf(red[2], red[3]));
  mx = fmaxf(fmaxf(red[4], red[5]), fmaxf(red[6], red[7]));
  float scale = fmaxf((mx - mn) / QMAX, 1e-5f);
  float zp = rintf(-mn / scale);
  for (int i = tid; i < N; i += 256) {
    float v = xr[i] * alpha;
    if (do_relu) v = fmaxf(v, 0.f);
    float q = fminf(fmaxf(rintf(v / scale) + zp, 0.f), QMAX);
    xr[i] = (q - zp) * scale;
  }
}

// ---- weight row quant -> bf16 int + per-row scale ----
__global__ __launch_bounds__(256) void wquant(const float* __restrict__ W,
                                              u16* __restrict__ Wi,
                                              float* __restrict__ sc, int K) {
  __shared__ float red[8];
  const int row = blockIdx.x, tid = threadIdx.x;
  const float* wr = W + (size_t)row * K;
  float mn = 0.f, mx = 0.f;
  for (int i = tid; i < K; i += 256) { float v = wr[i]; mn = fminf(mn, v); mx = fmaxf(mx, v); }
  mn = wred_min(mn); mx = wred_max(mx);
  if ((tid & 63) == 0) { red[tid >> 6] = mn; red[4 + (tid >> 6)] = mx; }
  __syncthreads();
  mn = fminf(fminf(red[0], red[1]), fminf(red[2], red[3]));
  mx = fmaxf(fmaxf(red[4], red[5]), fmaxf(red[6], red[7]));
  float scale = fmaxf((mx - mn) / QMAX, 1e-5f);
  float zp = rintf(-mn / scale);
  if (tid == 0) sc[row] = scale;
  for (int i = tid; i < K; i += 256) {
    float q = fminf(fmaxf(rintf(wr[i] / scale) + zp, 0.f), QMAX);
    Wi[(size_t)row * K + i] = f32i_to_bf16(q - zp);
  }
}

// ---- C[M,N] = (sa[i]*sb[n]) * (Aint[M,K] @ Bint[N,K]^T) + bias (+res), bf16 MFMA ----
__global__ __launch_bounds__(256) void gemm_mfma(
    const u16* __restrict__ A, const float* __restrict__ sa,
    const u16* __restrict__ B, const float* __restrict__ sb,
    const float* __restrict__ bias, const float* __restrict__ res,
    float* __restrict__ C, int M, int N, int K) {
  __shared__ __align__(16) u16 As[128 * 32];
  __shared__ __align__(16) u16 Bs[128 * 32];
  const int tid = threadIdx.x;
  const int wid = tid >> 6, lane = tid & 63;
  const int wr = wid >> 1, wc = wid & 1;
  const int lr = lane & 15, lk = lane >> 4;
  const int bm = blockIdx.y * 128, bn = blockIdx.x * 128;

  // staging geometry: unit u covers 8 bf16 (16B); row=u>>2, kchunk=(u&3)*8
  const int u0 = tid, u1 = 256 + tid;
  const int r0 = u0 >> 2, c0 = (u0 & 3) * 8;
  const int r1 = u1 >> 2, c1 = (u1 & 3) * 8;
  const size_t ldsb0 = (size_t)(wid * 64) * 8;        // lane0 unit of round 0
  const size_t ldsb1 = (size_t)(256 + wid * 64) * 8;  // lane0 unit of round 1

  f32x4 acc[4][4] = {};

  for (int k0 = 0; k0 < K; k0 += 32) {
    gload_lds16(A + (size_t)(bm + r0) * K + k0 + c0, As + ldsb0);
    gload_lds16(A + (size_t)(bm + r1) * K + k0 + c1, As + ldsb1);
    gload_lds16(B + (size_t)(bn + r0) * K + k0 + c0, Bs + ldsb0);
    gload_lds16(B + (size_t)(bn + r1) * K + k0 + c1, Bs + ldsb1);
    __syncthreads();  // drains vmcnt -> LDS tiles ready

    bf16x8 af[4], bf[4];
#pragma unroll
    for (int mi = 0; mi < 4; ++mi)
      af[mi] = *(const bf16x8*)&As[(size_t)(wr * 64 + mi * 16 + lr) * 32 + lk * 8];
#pragma unroll
    for (int ni = 0; ni < 4; ++ni)
      bf[ni] = *(const bf16x8*)&Bs[(size_t)(wc * 64 + ni * 16 + lr) * 32 + lk * 8];
#pragma unroll
    for (int mi = 0; mi < 4; ++mi)
#pragma unroll
      for (int ni = 0; ni < 4; ++ni)
        acc[mi][ni] = __builtin_amdgcn_mfma_f32_16x16x32_bf16(af[mi], bf[ni], acc[mi][ni], 0, 0, 0);
    __syncthreads();  // all waves done reading before next overwrite
  }

  const int col0 = bn + wc * 64 + lr;
  const int rbase = bm + wr * 64 + lk * 4;
#pragma unroll
  for (int ni = 0; ni < 4; ++ni) {
    const int col = col0 + ni * 16;
    const float sbc = sb[col];
    const float bc = bias[col];
#pragma unroll
    for (int mi = 0; mi < 4; ++mi) {
#pragma unroll
      for (int r = 0; r < 4; ++r) {
        const int row = rbase + mi * 16 + r;
        float v = acc[mi][ni][r] * sa[row] * sbc + bc;
        if (res) v += res[(size_t)row * N + col];
        C[(size_t)row * N + col] = v;
      }
    }
  }
}

// ---------------- attention pass A: per-row running max m and denom L ----------------
__global__ __launch_bounds__(256) void attn_ml(const float* __restrict__ Q,
                                               const float* __restrict__ Kmat,
                                               float* __restrict__ Mbuf,
                                               float* __restrict__ Lbuf) {
  __shared__ float qs[32][68];
  __shared__ float ks[64][68];
  const int h = blockIdx.y;
  const int i0 = blockIdx.x * 32;
  const int tid = threadIdx.x;
  for (int l = tid; l < 32 * 64; l += 256) {
    int r = l >> 6, d = l & 63;
    qs[r][d] = Q[(size_t)(i0 + r) * D_DIM + h * HD_DIM + d];
  }
  const int r = tid >> 3, jg = tid & 7;
  const int i = i0 + r;
  float mr = NEGF, lr = 0.f;
  const int jend = i0 + 31;
  for (int jt = 0; jt <= jend; jt += 64) {
    __syncthreads();
    for (int l = tid; l < 64 * 64; l += 256) {
      int rr = l >> 6, d = l & 63;
      ks[rr][d] = Kmat[(size_t)(jt + rr) * D_DIM + h * HD_DIM + d];
    }
    __syncthreads();
    float sv[8];
    float tmax = NEGF;
#pragma unroll
    for (int jj = 0; jj < 8; ++jj) {
      int jl = jg + jj * 8;
      int j = jt + jl;
      float s = NEGF;
      if (j <= i) {
        float a = 0.f;
#pragma unroll
        for (int d = 0; d < 64; d += 4) {
          float4 qa = *(const float4*)&qs[r][d];
          float4 kb = *(const float4*)&ks[jl][d];
          a += qa.x * kb.x + qa.y * kb.y + qa.z * kb.z + qa.w * kb.w;
        }
        s = a;
      }
      sv[jj] = s;
      tmax = fmaxf(tmax, s);
    }
    tmax = fmaxf(tmax, __shfl_xor(tmax, 1, 64));
    tmax = fmaxf(tmax, __shfl_xor(tmax, 2, 64));
    tmax = fmaxf(tmax, __shfl_xor(tmax, 4, 64));
    if (tmax > NEGF) {
      float mnew = fmaxf(mr, tmax);
      float sum = 0.f;
#pragma unroll
      for (int jj = 0; jj < 8; ++jj)
        sum += (sv[jj] > NEGF) ? expf(sv[jj] - mnew) : 0.f;
      sum += __shfl_xor(sum, 1, 64);
      sum += __shfl_xor(sum, 2, 64);
      sum += __shfl_xor(sum, 4, 64);
      lr = (mr == NEGF) ? sum : lr * expf(mr - mnew) + sum;
      mr = mnew;
    }
  }
  if (jg == 0) {
    Mbuf[(size_t)h * S_LEN + i] = mr;
    Lbuf[(size_t)h * S_LEN + i] = lr;
  }
}

// ---------------- attention pass B: ctx = quantprobs @ V ----------------
__global__ __launch_bounds__(256) void attn_pv(const float* __restrict__ Q,
                                               const float* __restrict__ Kmat,
                                               const float* __restrict__ V,
                                               const float* __restrict__ Mbuf,
                                               const float* __restrict__ Lbuf,
                                               float* __restrict__ Ctx) {
  __shared__ float qs[32][68];
  __shared__ float ks[64][68];
  __shared__ float vs[64][68];
  __shared__ float ps[32][68];
  const int h = blockIdx.y, i0 = blockIdx.x * 32, tid = threadIdx.x;
  for (int l = tid; l < 32 * 64; l += 256) {
    int r = l >> 6, d = l & 63;
    qs[r][d] = Q[(size_t)(i0 + r) * D_DIM + h * HD_DIM + d];
  }
  const int r = tid >> 3, jg = tid & 7;
  const int i = i0 + r;
  const float mi = Mbuf[(size_t)h * S_LEN + i];
  const float li = Lbuf[(size_t)h * S_LEN + i];
  const float scale_i = fmaxf((1.0f / li) / QMAX, 1e-5f);
  float acc[8] = {0.f, 0.f, 0.f, 0.f, 0.f, 0.f, 0.f, 0.f};
  const int jend = i0 + 31;
  for (int jt = 0; jt <= jend; jt += 64) {
    __syncthreads();
    for (int l = tid; l < 64 * 64; l += 256) {
      int rr = l >> 6, d = l & 63;
      ks[rr][d] = Kmat[(size_t)(jt + rr) * D_DIM + h * HD_DIM + d];
      vs[rr][d] = V[(size_t)(jt + rr) * D_DIM + h * HD_DIM + d];
    }
    __syncthreads();
#pragma unroll
    for (int jj = 0; jj < 8; ++jj) {
      int jl = jg + jj * 8;
      int j = jt + jl;
      float p = 0.f;
      if (j <= i) {
        float s = 0.f;
#pragma unroll
        for (int d = 0; d < 64; d += 4) {
          float4 qa = *(const float4*)&qs[r][d];
          float4 kb = *(const float4*)&ks[jl][d];
          s += qa.x * kb.x + qa.y * kb.y + qa.z * kb.z + qa.w * kb.w;
        }
        float e = expf(s - mi);
        float pr = e / li;
        float q8 = fminf(fmaxf(rintf(pr / scale_i), 0.f), QMAX);
        p = q8 * scale_i;
      }
      ps[r][jl] = p;
    }
    __syncthreads();
#pragma unroll 8
    for (int jl = 0; jl < 64; ++jl) {
      float pv = ps[r][jl];
      float4 v0 = *(const float4*)&vs[jl][jg * 8];
      float4 v1 = *(const float4*)&vs[jl][jg * 8 + 4];
      acc[0] += pv * v0.x; acc[1] += pv * v0.y; acc[2] += pv * v0.z; acc[3] += pv * v0.w;
      acc[4] += pv * v1.x; acc[5] += pv * v1.y; acc[6] += pv * v1.z; acc[7] += pv * v1.w;
    }
  }
  float4 o0 = {acc[0], acc[1], acc[2], acc[3]};
  float4 o1 = {acc[4], acc[5], acc[6], acc[7]};
  size_t base = (size_t)i * D_DIM + h * HD_DIM + jg * 8;
  *(float4*)&Ctx[base] = o0;
  *(float4*)&Ctx[base + 4] = o1;
}

extern "C" void kernel_launch(void* const* d_in, const int* in_sizes, int n_in,
                              void* d_out, int out_size, void* d_ws, size_t ws_size,
                              hipStream_t stream) {
  (void)in_sizes; (void)n_in; (void)out_size;
  const float* hs  = (const float*)d_in[0];
  const float* Wq  = (const float*)d_in[2];
  const float* bq  = (const float*)d_in[3];
  const float* Wk  = (const float*)d_in[4];
  const float* bk  = (const float*)d_in[5];
  const float* Wv  = (const float*)d_in[6];
  const float* bv  = (const float*)d_in[7];
  const float* Wo  = (const float*)d_in[8];
  const float* bo  = (const float*)d_in[9];
  const float* g1  = (const float*)d_in[10];
  const float* be1 = (const float*)d_in[11];
  const float* W1  = (const float*)d_in[12];
  const float* bf1 = (const float*)d_in[13];
  const float* W2  = (const float*)d_in[14];
  const float* bf2 = (const float*)d_in[15];
  const float* g2  = (const float*)d_in[16];
  const float* be2 = (const float*)d_in[17];
  float* out = (float*)d_out;

  const size_t SD = (size_t)S_LEN * D_DIM;
  const size_t SF = (size_t)S_LEN * FF_DIM;  // == 4*SD
  const size_t HS = (size_t)H_NUM * S_LEN;

  float* f = (float*)d_ws;
  float* qb  = f; f += SD;
  float* kb  = f; f += SD;
  float* vb  = f; f += SD;
  float* ctx = f; f += SD;
  float* f1  = qb;  // alias: f1 [S,FF] spans qb..ctx (SF == 4*SD), lifetimes disjoint
  float* h2  = f; f += SD;
  float* mb  = f; f += HS;
  float* lb  = f; f += HS;
  float* sx  = f; f += S_LEN;   // activation row scales (x1 / ctx / x2, reused)
  float* sxf = f; f += S_LEN;   // f1 row scales
  float* swq = f; f += D_DIM;
  float* swk = f; f += D_DIM;
  float* swv = f; f += D_DIM;
  float* swo = f; f += D_DIM;
  float* sw1 = f; f += FF_DIM;
  float* sw2 = f; f += D_DIM;
  u16* xi  = (u16*)f;           // [S,D] bf16 ints (x1 / ctx / x2, reused)
  u16* f1i = xi + SD;           // [S,FF]
  u16* wqi = f1i + SF;
  u16* wki = wqi + SD;
  u16* wvi = wki + SD;
  u16* woi = wvi + SD;
  u16* w1i = woi + SD;          // [FF,D]
  u16* w2i = w1i + SF;          // [D,FF]
  size_t need = (size_t)((char*)(w2i + SF) - (char*)d_ws);
  if (ws_size < need) return;  // fail loudly rather than corrupt

  dim3 blk(256);

  // weight quantization (once per launch)
  wquant<<<D_DIM, blk, 0, stream>>>(Wq, wqi, swq, D_DIM);
  wquant<<<D_DIM, blk, 0, stream>>>(Wk, wki, swk, D_DIM);
  wquant<<<D_DIM, blk, 0, stream>>>(Wv, wvi, swv, D_DIM);
  wquant<<<D_DIM, blk, 0, stream>>>(Wo, woi, swo, D_DIM);
  wquant<<<FF_DIM, blk, 0, stream>>>(W1, w1i, sw1, D_DIM);
  wquant<<<D_DIM, blk, 0, stream>>>(W2, w2i, sw2, FF_DIM);

  ln_quant_bf16<<<S_LEN, blk, 0, stream>>>(hs, g1, be1, xi, sx);

  dim3 gdd(D_DIM / 128, S_LEN / 128);
  gemm_mfma<<<gdd, blk, 0, stream>>>(xi, sx, wqi, swq, bq, nullptr, qb, S_LEN, D_DIM, D_DIM);
  gemm_mfma<<<gdd, blk, 0, stream>>>(xi, sx, wki, swk, bk, nullptr, kb, S_LEN, D_DIM, D_DIM);
  gemm_mfma<<<gdd, blk, 0, stream>>>(xi, sx, wvi, swv, bv, nullptr, vb, S_LEN, D_DIM, D_DIM);

  act_quant<<<S_LEN, blk, 0, stream>>>(qb, D_DIM, 0.125f, 0);  // *SCALING then quant
  act_quant<<<S_LEN, blk, 0, stream>>>(kb, D_DIM, 1.0f, 0);
  act_quant<<<S_LEN, blk, 0, stream>>>(vb, D_DIM, 1.0f, 0);

  dim3 ga(S_LEN / 32, H_NUM);
  attn_ml<<<ga, blk, 0, stream>>>(qb, kb, mb, lb);
  attn_pv<<<ga, blk, 0, stream>>>(qb, kb, vb, mb, lb, ctx);

  act_quant_bf16<<<S_LEN, blk, 0, stream>>>(ctx, xi, sx, D_DIM, 0);
  gemm_mfma<<<gdd, blk, 0, stream>>>(xi, sx, woi, swo, bo, hs, h2, S_LEN, D_DIM, D_DIM);

  ln_quant_bf16<<<S_LEN, blk, 0, stream>>>(h2, g2, be2, xi, sx);

  dim3 gff(FF_DIM / 128, S_LEN / 128);
  gemm_mfma<<<gff, blk, 0, stream>>>(xi, sx, w1i, sw1, bf1, nullptr, f1, S_LEN, FF_DIM, D_DIM);
  act_quant_bf16<<<S_LEN, blk, 0, stream>>>(f1, f1i, sxf, FF_DIM, 1);  // relu then quant
  gemm_mfma<<<gdd, blk, 0, stream>>>(f1i, sxf, w2i, sw2, bf2, h2, out, S_LEN, D_DIM, FF_DIM);
}

// Round 3
// 1026.281 us; speedup vs baseline: 4.6965x; 2.0870x over previous
//
#include <hip/hip_runtime.h>
#include <hip/hip_bf16.h>
#include <math.h>

#define S_LEN 2048
#define D_DIM 2048
#define H_NUM 32
#define HD_DIM 64
#define FF_DIM 8192
#define QMAX 255.0f

typedef __attribute__((ext_vector_type(4))) float f32x4;
typedef __attribute__((ext_vector_type(8))) __bf16 bf16x8;
typedef unsigned short u16;

__device__ __forceinline__ u16 f32i_to_bf16(float v) {
  // v is an exact integer in [-255,255]: fp32 low 16 bits are zero -> exact bf16
  return (u16)(__float_as_uint(v) >> 16);
}
__device__ __forceinline__ u16 f32_to_bf16_rne(float v) {
  __bf16 b = (__bf16)v;
  return *(u16*)&b;
}

__device__ __forceinline__ float wred_sum(float v) {
#pragma unroll
  for (int o = 1; o < 64; o <<= 1) v += __shfl_xor(v, o, 64);
  return v;
}
__device__ __forceinline__ float wred_min(float v) {
#pragma unroll
  for (int o = 1; o < 64; o <<= 1) v = fminf(v, __shfl_xor(v, o, 64));
  return v;
}
__device__ __forceinline__ float wred_max(float v) {
#pragma unroll
  for (int o = 1; o < 64; o <<= 1) v = fmaxf(v, __shfl_xor(v, o, 64));
  return v;
}

__device__ __forceinline__ void gload_lds16(const void* g, void* l) {
  __builtin_amdgcn_global_load_lds(
      (__attribute__((address_space(1))) void*)(g),
      (__attribute__((address_space(3))) void*)(l), 16, 0, 0);
}

// ---- LayerNorm + per-token quant -> bf16 integer (q-zp) + row scale ----
__global__ __launch_bounds__(256) void ln_quant_bf16(const float* __restrict__ x,
                                                     const float* __restrict__ g,
                                                     const float* __restrict__ bvec,
                                                     u16* __restrict__ out,
                                                     float* __restrict__ srow) {
  __shared__ float buf[D_DIM];
  __shared__ float red[8];
  const int row = blockIdx.x, tid = threadIdx.x;
  const float* xr = x + (size_t)row * D_DIM;

  float s = 0.f, ss = 0.f;
  for (int i = tid; i < D_DIM; i += 256) { float v = xr[i]; s += v; ss += v * v; }
  s = wred_sum(s); ss = wred_sum(ss);
  if ((tid & 63) == 0) { red[tid >> 6] = s; red[4 + (tid >> 6)] = ss; }
  __syncthreads();
  float mu = (red[0] + red[1] + red[2] + red[3]) / (float)D_DIM;
  float var = (red[4] + red[5] + red[6] + red[7]) / (float)D_DIM - mu * mu;
  float rstd = 1.0f / sqrtf(var + 1e-5f);
  __syncthreads();

  float mn = 0.f, mx = 0.f;
  for (int i = tid; i < D_DIM; i += 256) {
    float v = (xr[i] - mu) * rstd * g[i] + bvec[i];
    buf[i] = v;
    mn = fminf(mn, v); mx = fmaxf(mx, v);
  }
  mn = wred_min(mn); mx = wred_max(mx);
  if ((tid & 63) == 0) { red[tid >> 6] = mn; red[4 + (tid >> 6)] = mx; }
  __syncthreads();
  mn = fminf(fminf(red[0], red[1]), fminf(red[2], red[3]));
  mx = fmaxf(fmaxf(red[4], red[5]), fmaxf(red[6], red[7]));
  float scale = fmaxf((mx - mn) / QMAX, 1e-5f);
  float zp = rintf(-mn / scale);
  if (tid == 0) srow[row] = scale;
  for (int i = tid; i < D_DIM; i += 256) {
    float q = fminf(fmaxf(rintf(buf[i] / scale) + zp, 0.f), QMAX);
    out[(size_t)row * D_DIM + i] = f32i_to_bf16(q - zp);
  }
}

// ---- fp32 row -> quant -> bf16 int + scale (alpha pre-scale, optional relu) ----
__global__ __launch_bounds__(256) void act_quant_bf16(const float* __restrict__ x,
                                                      u16* __restrict__ out,
                                                      float* __restrict__ srow,
                                                      int N, float alpha, int do_relu) {
  __shared__ float red[8];
  const int row = blockIdx.x, tid = threadIdx.x;
  const float* xr = x + (size_t)row * N;
  float mn = 0.f, mx = 0.f;
  for (int i = tid; i < N; i += 256) {
    float v = xr[i] * alpha;
    if (do_relu) v = fmaxf(v, 0.f);
    mn = fminf(mn, v); mx = fmaxf(mx, v);
  }
  mn = wred_min(mn); mx = wred_max(mx);
  if ((tid & 63) == 0) { red[tid >> 6] = mn; red[4 + (tid >> 6)] = mx; }
  __syncthreads();
  mn = fminf(fminf(red[0], red[1]), fminf(red[2], red[3]));
  mx = fmaxf(fmaxf(red[4], red[5]), fmaxf(red[6], red[7]));
  float scale = fmaxf((mx - mn) / QMAX, 1e-5f);
  float zp = rintf(-mn / scale);
  if (tid == 0) srow[row] = scale;
  for (int i = tid; i < N; i += 256) {
    float v = xr[i] * alpha;
    if (do_relu) v = fmaxf(v, 0.f);
    float q = fminf(fmaxf(rintf(v / scale) + zp, 0.f), QMAX);
    out[(size_t)row * N + i] = f32i_to_bf16(q - zp);
  }
}

// ---- fp32 row -> fake quant -> bf16 VALUES (for attention V operand) ----
__global__ __launch_bounds__(256) void act_quant_vf(const float* __restrict__ x,
                                                    u16* __restrict__ out, int N) {
  __shared__ float red[8];
  const int row = blockIdx.x, tid = threadIdx.x;
  const float* xr = x + (size_t)row * N;
  float mn = 0.f, mx = 0.f;
  for (int i = tid; i < N; i += 256) {
    float v = xr[i];
    mn = fminf(mn, v); mx = fmaxf(mx, v);
  }
  mn = wred_min(mn); mx = wred_max(mx);
  if ((tid & 63) == 0) { red[tid >> 6] = mn; red[4 + (tid >> 6)] = mx; }
  __syncthreads();
  mn = fminf(fminf(red[0], red[1]), fminf(red[2], red[3]));
  mx = fmaxf(fmaxf(red[4], red[5]), fmaxf(red[6], red[7]));
  float scale = fmaxf((mx - mn) / QMAX, 1e-5f);
  float zp = rintf(-mn / scale);
  for (int i = tid; i < N; i += 256) {
    float q = fminf(fmaxf(rintf(xr[i] / scale) + zp, 0.f), QMAX);
    out[(size_t)row * N + i] = f32_to_bf16_rne((q - zp) * scale);
  }
}

// ---- weight row quant -> bf16 int + per-row scale ----
__global__ __launch_bounds__(256) void wquant(const float* __restrict__ W,
                                              u16* __restrict__ Wi,
                                              float* __restrict__ sc, int K) {
  __shared__ float red[8];
  const int row = blockIdx.x, tid = threadIdx.x;
  const float* wr = W + (size_t)row * K;
  float mn = 0.f, mx = 0.f;
  for (int i = tid; i < K; i += 256) { float v = wr[i]; mn = fminf(mn, v); mx = fmaxf(mx, v); }
  mn = wred_min(mn); mx = wred_max(mx);
  if ((tid & 63) == 0) { red[tid >> 6] = mn; red[4 + (tid >> 6)] = mx; }
  __syncthreads();
  mn = fminf(fminf(red[0], red[1]), fminf(red[2], red[3]));
  mx = fmaxf(fmaxf(red[4], red[5]), fmaxf(red[6], red[7]));
  float scale = fmaxf((mx - mn) / QMAX, 1e-5f);
  float zp = rintf(-mn / scale);
  if (tid == 0) sc[row] = scale;
  for (int i = tid; i < K; i += 256) {
    float q = fminf(fmaxf(rintf(wr[i] / scale) + zp, 0.f), QMAX);
    Wi[(size_t)row * K + i] = f32i_to_bf16(q - zp);
  }
}

// ---- C[M,N] = (sa[i]*sb[n]) * (Aint[M,K] @ Bint[N,K]^T) + bias (+res), bf16 MFMA ----
__global__ __launch_bounds__(256) void gemm_mfma(
    const u16* __restrict__ A, const float* __restrict__ sa,
    const u16* __restrict__ B, const float* __restrict__ sb,
    const float* __restrict__ bias, const float* __restrict__ res,
    float* __restrict__ C, int M, int N, int K) {
  __shared__ __align__(16) u16 As[128 * 32];
  __shared__ __align__(16) u16 Bs[128 * 32];
  const int tid = threadIdx.x;
  const int wid = tid >> 6, lane = tid & 63;
  const int wr = wid >> 1, wc = wid & 1;
  const int lr = lane & 15, lk = lane >> 4;
  const int bm = blockIdx.y * 128, bn = blockIdx.x * 128;

  const int u0 = tid, u1 = 256 + tid;
  const int r0 = u0 >> 2, c0 = (u0 & 3) * 8;
  const int r1 = u1 >> 2, c1 = (u1 & 3) * 8;
  const size_t ldsb0 = (size_t)(wid * 64) * 8;
  const size_t ldsb1 = (size_t)(256 + wid * 64) * 8;

  f32x4 acc[4][4] = {};

  for (int k0 = 0; k0 < K; k0 += 32) {
    gload_lds16(A + (size_t)(bm + r0) * K + k0 + c0, As + ldsb0);
    gload_lds16(A + (size_t)(bm + r1) * K + k0 + c1, As + ldsb1);
    gload_lds16(B + (size_t)(bn + r0) * K + k0 + c0, Bs + ldsb0);
    gload_lds16(B + (size_t)(bn + r1) * K + k0 + c1, Bs + ldsb1);
    __syncthreads();

    bf16x8 af[4], bf[4];
#pragma unroll
    for (int mi = 0; mi < 4; ++mi)
      af[mi] = *(const bf16x8*)&As[(size_t)(wr * 64 + mi * 16 + lr) * 32 + lk * 8];
#pragma unroll
    for (int ni = 0; ni < 4; ++ni)
      bf[ni] = *(const bf16x8*)&Bs[(size_t)(wc * 64 + ni * 16 + lr) * 32 + lk * 8];
#pragma unroll
    for (int mi = 0; mi < 4; ++mi)
#pragma unroll
      for (int ni = 0; ni < 4; ++ni)
        acc[mi][ni] = __builtin_amdgcn_mfma_f32_16x16x32_bf16(af[mi], bf[ni], acc[mi][ni], 0, 0, 0);
    __syncthreads();
  }

  const int col0 = bn + wc * 64 + lr;
  const int rbase = bm + wr * 64 + lk * 4;
#pragma unroll
  for (int ni = 0; ni < 4; ++ni) {
    const int col = col0 + ni * 16;
    const float sbc = sb[col];
    const float bc = bias[col];
#pragma unroll
    for (int mi = 0; mi < 4; ++mi) {
#pragma unroll
      for (int r = 0; r < 4; ++r) {
        const int row = rbase + mi * 16 + r;
        float v = acc[mi][ni][r] * sa[row] * sbc + bc;
        if (res) v += res[(size_t)row * N + col];
        C[(size_t)row * N + col] = v;
      }
    }
  }
}

// ---- fused causal attention with quantized probs, MFMA both passes ----
// scores = (qint . kint) * sq_i * sk_j  (integer dot exact in fp32 accum)
// pass A: online m,L per row. pass B: q8 = clip(rint((e/L)/scale)), ctx = scale * (q8 @ Vf)
__global__ __launch_bounds__(256) void attn_fused(
    const u16* __restrict__ qi, const float* __restrict__ sq,
    const u16* __restrict__ ki, const float* __restrict__ sk,
    const u16* __restrict__ vf, float* __restrict__ ctx) {
  __shared__ __align__(16) u16 Qs[64][72];
  __shared__ __align__(16) u16 Ks[64][72];
  __shared__ __align__(16) u16 Ps[64][72];
  __shared__ __align__(16) u16 Vt[64][72];
  const int h = blockIdx.y;
  const int i0 = blockIdx.x * 64;
  const int tid = threadIdx.x;
  const int wid = tid >> 6, lane = tid & 63;
  const int lr = lane & 15, g = lane >> 4;
  const size_t hbase = (size_t)h * HD_DIM;

  // Q tile: 64 rows x 64 cols bf16-int
  for (int c = tid; c < 512; c += 256) {
    int r = c >> 3, ch = c & 7;
    *(float4*)&Qs[r][ch * 8] =
        *(const float4*)&qi[(size_t)(i0 + r) * D_DIM + hbase + ch * 8];
  }
  float sq4[4];
#pragma unroll
  for (int r = 0; r < 4; ++r) sq4[r] = sq[i0 + wid * 16 + g * 4 + r];
  __syncthreads();

  const int ntiles = i0 / 64 + 1;
  float m_r[4] = {-1e30f, -1e30f, -1e30f, -1e30f};
  float l_r[4] = {0.f, 0.f, 0.f, 0.f};

  // ---------- pass A: running max + denom ----------
  for (int t = 0; t < ntiles; ++t) {
    const int jt = t * 64;
    __syncthreads();
    for (int c = tid; c < 512; c += 256) {
      int r = c >> 3, ch = c & 7;
      *(float4*)&Ks[r][ch * 8] =
          *(const float4*)&ki[(size_t)(jt + r) * D_DIM + hbase + ch * 8];
    }
    __syncthreads();

    bf16x8 aq0 = *(const bf16x8*)&Qs[wid * 16 + lr][g * 8];
    bf16x8 aq1 = *(const bf16x8*)&Qs[wid * 16 + lr][32 + g * 8];
    f32x4 accs[4] = {};
#pragma unroll
    for (int ni = 0; ni < 4; ++ni) {
      bf16x8 b0 = *(const bf16x8*)&Ks[ni * 16 + lr][g * 8];
      bf16x8 b1 = *(const bf16x8*)&Ks[ni * 16 + lr][32 + g * 8];
      accs[ni] = __builtin_amdgcn_mfma_f32_16x16x32_bf16(aq0, b0, accs[ni], 0, 0, 0);
      accs[ni] = __builtin_amdgcn_mfma_f32_16x16x32_bf16(aq1, b1, accs[ni], 0, 0, 0);
    }

    float sv[4][4];
#pragma unroll
    for (int ni = 0; ni < 4; ++ni) {
      const float skc = sk[jt + ni * 16 + lr];
#pragma unroll
      for (int r = 0; r < 4; ++r) sv[ni][r] = accs[ni][r] * sq4[r] * skc;
    }
    if (t == ntiles - 1) {  // diagonal tile: mask j > i
      const int jcol = jt + lr, irow = i0 + wid * 16 + g * 4;
#pragma unroll
      for (int ni = 0; ni < 4; ++ni)
#pragma unroll
        for (int r = 0; r < 4; ++r)
          if (jcol + ni * 16 > irow + r) sv[ni][r] = -1e30f;
    }
#pragma unroll
    for (int r = 0; r < 4; ++r) {
      float tmax = fmaxf(fmaxf(sv[0][r], sv[1][r]), fmaxf(sv[2][r], sv[3][r]));
      tmax = fmaxf(tmax, __shfl_xor(tmax, 1, 64));
      tmax = fmaxf(tmax, __shfl_xor(tmax, 2, 64));
      tmax = fmaxf(tmax, __shfl_xor(tmax, 4, 64));
      tmax = fmaxf(tmax, __shfl_xor(tmax, 8, 64));
      float mnew = fmaxf(m_r[r], tmax);
      float sum = expf(sv[0][r] - mnew) + expf(sv[1][r] - mnew) +
                  expf(sv[2][r] - mnew) + expf(sv[3][r] - mnew);
      sum += __shfl_xor(sum, 1, 64);
      sum += __shfl_xor(sum, 2, 64);
      sum += __shfl_xor(sum, 4, 64);
      sum += __shfl_xor(sum, 8, 64);
      l_r[r] = l_r[r] * expf(m_r[r] - mnew) + sum;
      m_r[r] = mnew;
    }
  }

  // per-row quant params: scale = max((1/L)/255, 1e-5); p_int = rint(e/(L*scale))
  float qsc[4], idn[4];
#pragma unroll
  for (int r = 0; r < 4; ++r) {
    float sc = fmaxf((1.0f / l_r[r]) / QMAX, 1e-5f);
    qsc[r] = sc;
    idn[r] = 1.0f / (l_r[r] * sc);
  }

  // ---------- pass B: quantized probs @ V ----------
  f32x4 acco[4] = {};
  for (int t = 0; t < ntiles; ++t) {
    const int jt = t * 64;
    __syncthreads();
    for (int c = tid; c < 512; c += 256) {
      int r = c >> 3, ch = c & 7;
      *(float4*)&Ks[r][ch * 8] =
          *(const float4*)&ki[(size_t)(jt + r) * D_DIM + hbase + ch * 8];
    }
    // V^T tile: Vt[d][j] via reg-staged transpose
    for (int c = tid; c < 512; c += 256) {
      int jr = c & 63, ch = c >> 6;
      float4 v4 = *(const float4*)&vf[(size_t)(jt + jr) * D_DIM + hbase + ch * 8];
      const u16* vv = (const u16*)&v4;
#pragma unroll
      for (int e = 0; e < 8; ++e) Vt[ch * 8 + e][jr] = vv[e];
    }
    __syncthreads();

    bf16x8 aq0 = *(const bf16x8*)&Qs[wid * 16 + lr][g * 8];
    bf16x8 aq1 = *(const bf16x8*)&Qs[wid * 16 + lr][32 + g * 8];
    f32x4 accs[4] = {};
#pragma unroll
    for (int ni = 0; ni < 4; ++ni) {
      bf16x8 b0 = *(const bf16x8*)&Ks[ni * 16 + lr][g * 8];
      bf16x8 b1 = *(const bf16x8*)&Ks[ni * 16 + lr][32 + g * 8];
      accs[ni] = __builtin_amdgcn_mfma_f32_16x16x32_bf16(aq0, b0, accs[ni], 0, 0, 0);
      accs[ni] = __builtin_amdgcn_mfma_f32_16x16x32_bf16(aq1, b1, accs[ni], 0, 0, 0);
    }

    const bool diag = (t == ntiles - 1);
    const int jcol = jt + lr, irow = i0 + wid * 16 + g * 4;
#pragma unroll
    for (int ni = 0; ni < 4; ++ni) {
      const float skc = sk[jt + ni * 16 + lr];
#pragma unroll
      for (int r = 0; r < 4; ++r) {
        float s = accs[ni][r] * sq4[r] * skc;
        if (diag && (jcol + ni * 16 > irow + r)) s = -1e30f;
        float e = expf(s - m_r[r]);             // masked -> 0
        float q8 = fminf(fmaxf(rintf(e * idn[r]), 0.f), QMAX);
        Ps[wid * 16 + g * 4 + r][ni * 16 + lr] = f32i_to_bf16(q8);
      }
    }
    __syncthreads();  // Ps visible (wave-local in fact, kept for safety)

    bf16x8 ap0 = *(const bf16x8*)&Ps[wid * 16 + lr][g * 8];
    bf16x8 ap1 = *(const bf16x8*)&Ps[wid * 16 + lr][32 + g * 8];
#pragma unroll
    for (int ni = 0; ni < 4; ++ni) {
      bf16x8 b0 = *(const bf16x8*)&Vt[ni * 16 + lr][g * 8];
      bf16x8 b1 = *(const bf16x8*)&Vt[ni * 16 + lr][32 + g * 8];
      acco[ni] = __builtin_amdgcn_mfma_f32_16x16x32_bf16(ap0, b0, acco[ni], 0, 0, 0);
      acco[ni] = __builtin_amdgcn_mfma_f32_16x16x32_bf16(ap1, b1, acco[ni], 0, 0, 0);
    }
  }

#pragma unroll
  for (int ni = 0; ni < 4; ++ni) {
#pragma unroll
    for (int r = 0; r < 4; ++r) {
      const int row = i0 + wid * 16 + g * 4 + r;
      ctx[(size_t)row * D_DIM + hbase + ni * 16 + lr] = acco[ni][r] * qsc[r];
    }
  }
}

extern "C" void kernel_launch(void* const* d_in, const int* in_sizes, int n_in,
                              void* d_out, int out_size, void* d_ws, size_t ws_size,
                              hipStream_t stream) {
  (void)in_sizes; (void)n_in; (void)out_size;
  const float* hs  = (const float*)d_in[0];
  const float* Wq  = (const float*)d_in[2];
  const float* bq  = (const float*)d_in[3];
  const float* Wk  = (const float*)d_in[4];
  const float* bk  = (const float*)d_in[5];
  const float* Wv  = (const float*)d_in[6];
  const float* bv  = (const float*)d_in[7];
  const float* Wo  = (const float*)d_in[8];
  const float* bo  = (const float*)d_in[9];
  const float* g1  = (const float*)d_in[10];
  const float* be1 = (const float*)d_in[11];
  const float* W1  = (const float*)d_in[12];
  const float* bf1 = (const float*)d_in[13];
  const float* W2  = (const float*)d_in[14];
  const float* bf2 = (const float*)d_in[15];
  const float* g2  = (const float*)d_in[16];
  const float* be2 = (const float*)d_in[17];
  float* out = (float*)d_out;

  const size_t SD = (size_t)S_LEN * D_DIM;
  const size_t SF = (size_t)S_LEN * FF_DIM;  // == 4*SD

  float* f = (float*)d_ws;
  float* qb  = f; f += SD;
  float* kb  = f; f += SD;
  float* vb  = f; f += SD;
  float* ctx = f; f += SD;
  float* h2  = f; f += SD;
  float* f1  = qb;  // [S,FF] fp32, alias qb..ctx (lifetimes disjoint)
  float* sx  = f; f += S_LEN;
  float* sxf = f; f += S_LEN;
  float* sqv = f; f += S_LEN;
  float* skv = f; f += S_LEN;
  float* swq = f; f += D_DIM;
  float* swk = f; f += D_DIM;
  float* swv = f; f += D_DIM;
  float* swo = f; f += D_DIM;
  float* sw1 = f; f += FF_DIM;
  float* sw2 = f; f += D_DIM;
  u16* xi  = (u16*)f;           // [S,D] bf16 ints (x1 / ctx / x2, reused)
  u16* f1i = xi + SD;           // [S,FF] (late); early: aliases qi8/ki8/vfb
  u16* qi8 = f1i;               // [S,D] (dead before f1i written)
  u16* ki8 = f1i + SD;
  u16* vfb = f1i + 2 * SD;
  u16* wqi = f1i + SF;
  u16* wki = wqi + SD;
  u16* wvi = wki + SD;
  u16* woi = wvi + SD;
  u16* w1i = woi + SD;          // [FF,D]
  u16* w2i = w1i + SF;          // [D,FF]
  size_t need = (size_t)((char*)(w2i + SF) - (char*)d_ws);
  if (ws_size < need) return;  // fail loudly rather than corrupt

  dim3 blk(256);

  wquant<<<D_DIM, blk, 0, stream>>>(Wq, wqi, swq, D_DIM);
  wquant<<<D_DIM, blk, 0, stream>>>(Wk, wki, swk, D_DIM);
  wquant<<<D_DIM, blk, 0, stream>>>(Wv, wvi, swv, D_DIM);
  wquant<<<D_DIM, blk, 0, stream>>>(Wo, woi, swo, D_DIM);
  wquant<<<FF_DIM, blk, 0, stream>>>(W1, w1i, sw1, D_DIM);
  wquant<<<D_DIM, blk, 0, stream>>>(W2, w2i, sw2, FF_DIM);

  ln_quant_bf16<<<S_LEN, blk, 0, stream>>>(hs, g1, be1, xi, sx);

  dim3 gdd(D_DIM / 128, S_LEN / 128);
  gemm_mfma<<<gdd, blk, 0, stream>>>(xi, sx, wqi, swq, bq, nullptr, qb, S_LEN, D_DIM, D_DIM);
  gemm_mfma<<<gdd, blk, 0, stream>>>(xi, sx, wki, swk, bk, nullptr, kb, S_LEN, D_DIM, D_DIM);
  gemm_mfma<<<gdd, blk, 0, stream>>>(xi, sx, wvi, swv, bv, nullptr, vb, S_LEN, D_DIM, D_DIM);

  act_quant_bf16<<<S_LEN, blk, 0, stream>>>(qb, qi8, sqv, D_DIM, 0.125f, 0);  // *SCALING
  act_quant_bf16<<<S_LEN, blk, 0, stream>>>(kb, ki8, skv, D_DIM, 1.0f, 0);
  act_quant_vf<<<S_LEN, blk, 0, stream>>>(vb, vfb, D_DIM);

  dim3 ga(S_LEN / 64, H_NUM);
  attn_fused<<<ga, blk, 0, stream>>>(qi8, sqv, ki8, skv, vfb, ctx);

  act_quant_bf16<<<S_LEN, blk, 0, stream>>>(ctx, xi, sx, D_DIM, 1.0f, 0);
  gemm_mfma<<<gdd, blk, 0, stream>>>(xi, sx, woi, swo, bo, hs, h2, S_LEN, D_DIM, D_DIM);

  ln_quant_bf16<<<S_LEN, blk, 0, stream>>>(h2, g2, be2, xi, sx);

  dim3 gff(FF_DIM / 128, S_LEN / 128);
  gemm_mfma<<<gff, blk, 0, stream>>>(xi, sx, w1i, sw1, bf1, nullptr, f1, S_LEN, FF_DIM, D_DIM);
  act_quant_bf16<<<S_LEN, blk, 0, stream>>>(f1, f1i, sxf, FF_DIM, 1.0f, 1);  // relu
  gemm_mfma<<<gdd, blk, 0, stream>>>(f1i, sxf, w2i, sw2, bf2, h2, out, S_LEN, D_DIM, FF_DIM);
}

// Round 4
// 719.105 us; speedup vs baseline: 6.7027x; 1.4272x over previous
//
#include <hip/hip_runtime.h>
#include <hip/hip_bf16.h>
#include <math.h>

#define S_LEN 2048
#define D_DIM 2048
#define H_NUM 32
#define HD_DIM 64
#define FF_DIM 8192
#define QMAX 255.0f

typedef __attribute__((ext_vector_type(4))) float f32x4;
typedef __attribute__((ext_vector_type(8))) __bf16 bf16x8;
typedef unsigned short u16;

__device__ __forceinline__ u16 f32i_to_bf16(float v) {
  // v is an exact integer in [-255,255]: fp32 low 16 bits are zero -> exact bf16
  return (u16)(__float_as_uint(v) >> 16);
}
__device__ __forceinline__ u16 f32_to_bf16_rne(float v) {
  __bf16 b = (__bf16)v;
  return *(u16*)&b;
}

__device__ __forceinline__ float wred_sum(float v) {
#pragma unroll
  for (int o = 1; o < 64; o <<= 1) v += __shfl_xor(v, o, 64);
  return v;
}
__device__ __forceinline__ float wred_min(float v) {
#pragma unroll
  for (int o = 1; o < 64; o <<= 1) v = fminf(v, __shfl_xor(v, o, 64));
  return v;
}
__device__ __forceinline__ float wred_max(float v) {
#pragma unroll
  for (int o = 1; o < 64; o <<= 1) v = fmaxf(v, __shfl_xor(v, o, 64));
  return v;
}

__device__ __forceinline__ void gload_lds16(const void* g, void* l) {
  __builtin_amdgcn_global_load_lds(
      (__attribute__((address_space(1))) void*)(g),
      (__attribute__((address_space(3))) void*)(l), 16, 0, 0);
}

// ---- LayerNorm + per-token quant -> bf16 integer (q-zp) + row scale ----
__global__ __launch_bounds__(256) void ln_quant_bf16(const float* __restrict__ x,
                                                     const float* __restrict__ g,
                                                     const float* __restrict__ bvec,
                                                     u16* __restrict__ out,
                                                     float* __restrict__ srow) {
  __shared__ float buf[D_DIM];
  __shared__ float red[8];
  const int row = blockIdx.x, tid = threadIdx.x;
  const float4* xr = (const float4*)(x + (size_t)row * D_DIM);
  const float4* g4 = (const float4*)g;
  const float4* b4 = (const float4*)bvec;

  float4 v0 = xr[tid], v1 = xr[tid + 256];  // D/4 = 512 float4
  float s = v0.x + v0.y + v0.z + v0.w + v1.x + v1.y + v1.z + v1.w;
  float ss = v0.x * v0.x + v0.y * v0.y + v0.z * v0.z + v0.w * v0.w +
             v1.x * v1.x + v1.y * v1.y + v1.z * v1.z + v1.w * v1.w;
  s = wred_sum(s); ss = wred_sum(ss);
  if ((tid & 63) == 0) { red[tid >> 6] = s; red[4 + (tid >> 6)] = ss; }
  __syncthreads();
  float mu = (red[0] + red[1] + red[2] + red[3]) / (float)D_DIM;
  float var = (red[4] + red[5] + red[6] + red[7]) / (float)D_DIM - mu * mu;
  float rstd = 1.0f / sqrtf(var + 1e-5f);
  __syncthreads();

  float mn = 0.f, mx = 0.f;
  float4 n0, n1;
  {
    float4 gg = g4[tid], bb = b4[tid];
    n0.x = (v0.x - mu) * rstd * gg.x + bb.x; n0.y = (v0.y - mu) * rstd * gg.y + bb.y;
    n0.z = (v0.z - mu) * rstd * gg.z + bb.z; n0.w = (v0.w - mu) * rstd * gg.w + bb.w;
    gg = g4[tid + 256]; bb = b4[tid + 256];
    n1.x = (v1.x - mu) * rstd * gg.x + bb.x; n1.y = (v1.y - mu) * rstd * gg.y + bb.y;
    n1.z = (v1.z - mu) * rstd * gg.z + bb.z; n1.w = (v1.w - mu) * rstd * gg.w + bb.w;
    *(float4*)&buf[tid * 4] = n0;
    *(float4*)&buf[1024 + tid * 4] = n1;
    mn = fminf(mn, fminf(fminf(n0.x, n0.y), fminf(n0.z, n0.w)));
    mn = fminf(mn, fminf(fminf(n1.x, n1.y), fminf(n1.z, n1.w)));
    mx = fmaxf(mx, fmaxf(fmaxf(n0.x, n0.y), fmaxf(n0.z, n0.w)));
    mx = fmaxf(mx, fmaxf(fmaxf(n1.x, n1.y), fmaxf(n1.z, n1.w)));
  }
  mn = wred_min(mn); mx = wred_max(mx);
  if ((tid & 63) == 0) { red[tid >> 6] = mn; red[4 + (tid >> 6)] = mx; }
  __syncthreads();
  mn = fminf(fminf(red[0], red[1]), fminf(red[2], red[3]));
  mx = fmaxf(fmaxf(red[4], red[5]), fmaxf(red[6], red[7]));
  float scale = fmaxf((mx - mn) / QMAX, 1e-5f);
  float zp = rintf(-mn / scale);
  if (tid == 0) srow[row] = scale;
  ushort4 o0, o1;
  o0.x = f32i_to_bf16(fminf(fmaxf(rintf(n0.x / scale) + zp, 0.f), QMAX) - zp);
  o0.y = f32i_to_bf16(fminf(fmaxf(rintf(n0.y / scale) + zp, 0.f), QMAX) - zp);
  o0.z = f32i_to_bf16(fminf(fmaxf(rintf(n0.z / scale) + zp, 0.f), QMAX) - zp);
  o0.w = f32i_to_bf16(fminf(fmaxf(rintf(n0.w / scale) + zp, 0.f), QMAX) - zp);
  o1.x = f32i_to_bf16(fminf(fmaxf(rintf(n1.x / scale) + zp, 0.f), QMAX) - zp);
  o1.y = f32i_to_bf16(fminf(fmaxf(rintf(n1.y / scale) + zp, 0.f), QMAX) - zp);
  o1.z = f32i_to_bf16(fminf(fmaxf(rintf(n1.z / scale) + zp, 0.f), QMAX) - zp);
  o1.w = f32i_to_bf16(fminf(fmaxf(rintf(n1.w / scale) + zp, 0.f), QMAX) - zp);
  *(ushort4*)&out[(size_t)row * D_DIM + tid * 4] = o0;
  *(ushort4*)&out[(size_t)row * D_DIM + 1024 + tid * 4] = o1;
}

// ---- fp32 row -> quant -> bf16 int + scale (alpha pre-scale, optional relu) ----
__global__ __launch_bounds__(256) void act_quant_bf16(const float* __restrict__ x,
                                                      u16* __restrict__ out,
                                                      float* __restrict__ srow,
                                                      int N, float alpha, int do_relu) {
  __shared__ float red[8];
  const int row = blockIdx.x, tid = threadIdx.x;
  const float4* xr = (const float4*)(x + (size_t)row * N);
  const int N4 = N >> 2;
  float mn = 0.f, mx = 0.f;
  for (int i = tid; i < N4; i += 256) {
    float4 v = xr[i];
    v.x *= alpha; v.y *= alpha; v.z *= alpha; v.w *= alpha;
    if (do_relu) { v.x = fmaxf(v.x, 0.f); v.y = fmaxf(v.y, 0.f); v.z = fmaxf(v.z, 0.f); v.w = fmaxf(v.w, 0.f); }
    mn = fminf(mn, fminf(fminf(v.x, v.y), fminf(v.z, v.w)));
    mx = fmaxf(mx, fmaxf(fmaxf(v.x, v.y), fmaxf(v.z, v.w)));
  }
  mn = wred_min(mn); mx = wred_max(mx);
  if ((tid & 63) == 0) { red[tid >> 6] = mn; red[4 + (tid >> 6)] = mx; }
  __syncthreads();
  mn = fminf(fminf(red[0], red[1]), fminf(red[2], red[3]));
  mx = fmaxf(fmaxf(red[4], red[5]), fmaxf(red[6], red[7]));
  float scale = fmaxf((mx - mn) / QMAX, 1e-5f);
  float zp = rintf(-mn / scale);
  if (tid == 0) srow[row] = scale;
  for (int i = tid; i < N4; i += 256) {
    float4 v = xr[i];
    v.x *= alpha; v.y *= alpha; v.z *= alpha; v.w *= alpha;
    if (do_relu) { v.x = fmaxf(v.x, 0.f); v.y = fmaxf(v.y, 0.f); v.z = fmaxf(v.z, 0.f); v.w = fmaxf(v.w, 0.f); }
    ushort4 o;
    o.x = f32i_to_bf16(fminf(fmaxf(rintf(v.x / scale) + zp, 0.f), QMAX) - zp);
    o.y = f32i_to_bf16(fminf(fmaxf(rintf(v.y / scale) + zp, 0.f), QMAX) - zp);
    o.z = f32i_to_bf16(fminf(fmaxf(rintf(v.z / scale) + zp, 0.f), QMAX) - zp);
    o.w = f32i_to_bf16(fminf(fmaxf(rintf(v.w / scale) + zp, 0.f), QMAX) - zp);
    *(ushort4*)&out[(size_t)row * N + i * 4] = o;
  }
}

// ---- fp32 row -> fake quant -> bf16 VALUES (attention V operand) ----
__global__ __launch_bounds__(256) void act_quant_vf(const float* __restrict__ x,
                                                    u16* __restrict__ out, int N) {
  __shared__ float red[8];
  const int row = blockIdx.x, tid = threadIdx.x;
  const float4* xr = (const float4*)(x + (size_t)row * N);
  const int N4 = N >> 2;
  float mn = 0.f, mx = 0.f;
  for (int i = tid; i < N4; i += 256) {
    float4 v = xr[i];
    mn = fminf(mn, fminf(fminf(v.x, v.y), fminf(v.z, v.w)));
    mx = fmaxf(mx, fmaxf(fmaxf(v.x, v.y), fmaxf(v.z, v.w)));
  }
  mn = wred_min(mn); mx = wred_max(mx);
  if ((tid & 63) == 0) { red[tid >> 6] = mn; red[4 + (tid >> 6)] = mx; }
  __syncthreads();
  mn = fminf(fminf(red[0], red[1]), fminf(red[2], red[3]));
  mx = fmaxf(fmaxf(red[4], red[5]), fmaxf(red[6], red[7]));
  float scale = fmaxf((mx - mn) / QMAX, 1e-5f);
  float zp = rintf(-mn / scale);
  for (int i = tid; i < N4; i += 256) {
    float4 v = xr[i];
    ushort4 o;
    o.x = f32_to_bf16_rne((fminf(fmaxf(rintf(v.x / scale) + zp, 0.f), QMAX) - zp) * scale);
    o.y = f32_to_bf16_rne((fminf(fmaxf(rintf(v.y / scale) + zp, 0.f), QMAX) - zp) * scale);
    o.z = f32_to_bf16_rne((fminf(fmaxf(rintf(v.z / scale) + zp, 0.f), QMAX) - zp) * scale);
    o.w = f32_to_bf16_rne((fminf(fmaxf(rintf(v.w / scale) + zp, 0.f), QMAX) - zp) * scale);
    *(ushort4*)&out[(size_t)row * N + i * 4] = o;
  }
}

// ---- weight row quant -> bf16 int + per-row scale ----
__global__ __launch_bounds__(256) void wquant(const float* __restrict__ W,
                                              u16* __restrict__ Wi,
                                              float* __restrict__ sc, int K) {
  __shared__ float red[8];
  const int row = blockIdx.x, tid = threadIdx.x;
  const float4* wr = (const float4*)(W + (size_t)row * K);
  const int K4 = K >> 2;
  float mn = 0.f, mx = 0.f;
  for (int i = tid; i < K4; i += 256) {
    float4 v = wr[i];
    mn = fminf(mn, fminf(fminf(v.x, v.y), fminf(v.z, v.w)));
    mx = fmaxf(mx, fmaxf(fmaxf(v.x, v.y), fmaxf(v.z, v.w)));
  }
  mn = wred_min(mn); mx = wred_max(mx);
  if ((tid & 63) == 0) { red[tid >> 6] = mn; red[4 + (tid >> 6)] = mx; }
  __syncthreads();
  mn = fminf(fminf(red[0], red[1]), fminf(red[2], red[3]));
  mx = fmaxf(fmaxf(red[4], red[5]), fmaxf(red[6], red[7]));
  float scale = fmaxf((mx - mn) / QMAX, 1e-5f);
  float zp = rintf(-mn / scale);
  if (tid == 0) sc[row] = scale;
  for (int i = tid; i < K4; i += 256) {
    float4 v = wr[i];
    ushort4 o;
    o.x = f32i_to_bf16(fminf(fmaxf(rintf(v.x / scale) + zp, 0.f), QMAX) - zp);
    o.y = f32i_to_bf16(fminf(fmaxf(rintf(v.y / scale) + zp, 0.f), QMAX) - zp);
    o.z = f32i_to_bf16(fminf(fmaxf(rintf(v.z / scale) + zp, 0.f), QMAX) - zp);
    o.w = f32i_to_bf16(fminf(fmaxf(rintf(v.w / scale) + zp, 0.f), QMAX) - zp);
    *(ushort4*)&Wi[(size_t)row * K + i * 4] = o;
  }
}

// ---- 128x128 tile GEMM (for W1): C = sa*sb*(A@B^T) + bias ----
__global__ __launch_bounds__(256) void gemm_mfma(
    const u16* __restrict__ A, const float* __restrict__ sa,
    const u16* __restrict__ B, const float* __restrict__ sb,
    const float* __restrict__ bias, const float* __restrict__ res,
    float* __restrict__ C, int M, int N, int K) {
  __shared__ __align__(16) u16 As[128 * 32];
  __shared__ __align__(16) u16 Bs[128 * 32];
  const int tid = threadIdx.x;
  const int wid = tid >> 6, lane = tid & 63;
  const int wr = wid >> 1, wc = wid & 1;
  const int lr = lane & 15, lk = lane >> 4;
  const int bm = blockIdx.y * 128, bn = blockIdx.x * 128;

  const int r0 = tid >> 2, c0 = (tid & 3) * 8;
  const int r1 = (256 + tid) >> 2, c1 = (tid & 3) * 8;
  const size_t ldsb0 = (size_t)(wid * 64) * 8;
  const size_t ldsb1 = (size_t)(256 + wid * 64) * 8;

  f32x4 acc[4][4] = {};

  for (int k0 = 0; k0 < K; k0 += 32) {
    gload_lds16(A + (size_t)(bm + r0) * K + k0 + c0, As + ldsb0);
    gload_lds16(A + (size_t)(bm + r1) * K + k0 + c1, As + ldsb1);
    gload_lds16(B + (size_t)(bn + r0) * K + k0 + c0, Bs + ldsb0);
    gload_lds16(B + (size_t)(bn + r1) * K + k0 + c1, Bs + ldsb1);
    __syncthreads();

    bf16x8 af[4], bf[4];
#pragma unroll
    for (int mi = 0; mi < 4; ++mi)
      af[mi] = *(const bf16x8*)&As[(size_t)(wr * 64 + mi * 16 + lr) * 32 + lk * 8];
#pragma unroll
    for (int ni = 0; ni < 4; ++ni)
      bf[ni] = *(const bf16x8*)&Bs[(size_t)(wc * 64 + ni * 16 + lr) * 32 + lk * 8];
#pragma unroll
    for (int mi = 0; mi < 4; ++mi)
#pragma unroll
      for (int ni = 0; ni < 4; ++ni)
        acc[mi][ni] = __builtin_amdgcn_mfma_f32_16x16x32_bf16(af[mi], bf[ni], acc[mi][ni], 0, 0, 0);
    __syncthreads();
  }

  const int col0 = bn + wc * 64 + lr;
  const int rbase = bm + wr * 64 + lk * 4;
#pragma unroll
  for (int ni = 0; ni < 4; ++ni) {
    const int col = col0 + ni * 16;
    const float sbc = sb[col];
    const float bc = bias[col];
#pragma unroll
    for (int mi = 0; mi < 4; ++mi)
#pragma unroll
      for (int r = 0; r < 4; ++r) {
        const int row = rbase + mi * 16 + r;
        float v = acc[mi][ni][r] * sa[row] * sbc + bc;
        if (res) v += res[(size_t)row * N + col];
        C[(size_t)row * N + col] = v;
      }
  }
}

// ---- 128x64 tile GEMM body (better occupancy for D x D shapes) ----
__device__ __forceinline__ void gemm_bn64_body(
    const u16* __restrict__ A, const float* __restrict__ sa,
    const u16* __restrict__ B, const float* __restrict__ sb,
    const float* __restrict__ bias, const float* __restrict__ res,
    float* __restrict__ C, int N, int K, int bm, int bn,
    u16* As, u16* Bs) {
  const int tid = threadIdx.x;
  const int wid = tid >> 6, lane = tid & 63;
  const int wr = wid >> 1, wc = wid & 1;
  const int lr = lane & 15, lk = lane >> 4;

  const int r0 = tid >> 2, c0 = (tid & 3) * 8;     // A round 0 + B round
  const int r1 = (256 + tid) >> 2;                  // A round 1
  const size_t ldsb0 = (size_t)(wid * 64) * 8;
  const size_t ldsb1 = (size_t)(256 + wid * 64) * 8;

  f32x4 acc[4][2] = {};

  for (int k0 = 0; k0 < K; k0 += 32) {
    gload_lds16(A + (size_t)(bm + r0) * K + k0 + c0, As + ldsb0);
    gload_lds16(A + (size_t)(bm + r1) * K + k0 + c0, As + ldsb1);
    gload_lds16(B + (size_t)(bn + r0) * K + k0 + c0, Bs + ldsb0);
    __syncthreads();

    bf16x8 af[4], bf[2];
#pragma unroll
    for (int mi = 0; mi < 4; ++mi)
      af[mi] = *(const bf16x8*)&As[(size_t)(wr * 64 + mi * 16 + lr) * 32 + lk * 8];
#pragma unroll
    for (int ni = 0; ni < 2; ++ni)
      bf[ni] = *(const bf16x8*)&Bs[(size_t)(wc * 32 + ni * 16 + lr) * 32 + lk * 8];
#pragma unroll
    for (int mi = 0; mi < 4; ++mi)
#pragma unroll
      for (int ni = 0; ni < 2; ++ni)
        acc[mi][ni] = __builtin_amdgcn_mfma_f32_16x16x32_bf16(af[mi], bf[ni], acc[mi][ni], 0, 0, 0);
    __syncthreads();
  }

  const int col0 = bn + wc * 32 + lr;
  const int rbase = bm + wr * 64 + lk * 4;
#pragma unroll
  for (int ni = 0; ni < 2; ++ni) {
    const int col = col0 + ni * 16;
    const float sbc = sb[col - bn + bn];  // sb indexed globally below
    const float sbv = sb[col];
    const float bc = bias[col];
    (void)sbc;
#pragma unroll
    for (int mi = 0; mi < 4; ++mi)
#pragma unroll
      for (int r = 0; r < 4; ++r) {
        const int row = rbase + mi * 16 + r;
        float v = acc[mi][ni][r] * sa[row] * sbv + bc;
        if (res) v += res[(size_t)row * N + col];
        C[(size_t)row * N + col] = v;
      }
  }
}

__global__ __launch_bounds__(256) void gemm_bn64(
    const u16* __restrict__ A, const float* __restrict__ sa,
    const u16* __restrict__ B, const float* __restrict__ sb,
    const float* __restrict__ bias, const float* __restrict__ res,
    float* __restrict__ C, int N, int K) {
  __shared__ __align__(16) u16 As[128 * 32];
  __shared__ __align__(16) u16 Bs[64 * 32];
  gemm_bn64_body(A, sa, B, sb, bias, res, C, N, K,
                 blockIdx.y * 128, blockIdx.x * 64, As, Bs);
}

// fused QKV: blockIdx.x selects among {Wq,Wk,Wv} then runs the bn64 body
__global__ __launch_bounds__(256) void gemm_qkv(
    const u16* __restrict__ A, const float* __restrict__ sa,
    const u16* __restrict__ Bq, const float* __restrict__ sbq, const float* __restrict__ biasq, float* __restrict__ Cq,
    const u16* __restrict__ Bk, const float* __restrict__ sbk, const float* __restrict__ biask, float* __restrict__ Ck,
    const u16* __restrict__ Bv, const float* __restrict__ sbv, const float* __restrict__ biasv, float* __restrict__ Cv) {
  __shared__ __align__(16) u16 As[128 * 32];
  __shared__ __align__(16) u16 Bs[64 * 32];
  const int which = blockIdx.x >> 5;           // D/64 = 32 col-blocks each
  const int bn = (blockIdx.x & 31) * 64;
  const u16* B = (which == 0) ? Bq : (which == 1) ? Bk : Bv;
  const float* sb = (which == 0) ? sbq : (which == 1) ? sbk : sbv;
  const float* bias = (which == 0) ? biasq : (which == 1) ? biask : biasv;
  float* C = (which == 0) ? Cq : (which == 1) ? Ck : Cv;
  gemm_bn64_body(A, sa, B, sb, bias, nullptr, C, D_DIM, D_DIM,
                 blockIdx.y * 128, bn, As, Bs);
}

// ---- fused causal attention with quantized probs, MFMA both passes ----
__global__ __launch_bounds__(256) void attn_fused(
    const u16* __restrict__ qi, const float* __restrict__ sq,
    const u16* __restrict__ ki, const float* __restrict__ sk,
    const u16* __restrict__ vf, float* __restrict__ ctx) {
  __shared__ __align__(16) u16 Qs[64][72];
  __shared__ __align__(16) u16 Ks[64][72];
  __shared__ __align__(16) u16 Ps[64][72];
  __shared__ __align__(16) u16 Vt[64][72];
  // heavy-first order: first blocks get the largest i0 (most K tiles)
  const int bid = blockIdx.x;
  const int ti = (S_LEN / 64 - 1) - (bid >> 5);
  const int h = bid & (H_NUM - 1);
  const int i0 = ti * 64;
  const int tid = threadIdx.x;
  const int wid = tid >> 6, lane = tid & 63;
  const int lr = lane & 15, g = lane >> 4;
  const size_t hbase = (size_t)h * HD_DIM;

  for (int c = tid; c < 512; c += 256) {
    int r = c >> 3, ch = c & 7;
    *(float4*)&Qs[r][ch * 8] =
        *(const float4*)&qi[(size_t)(i0 + r) * D_DIM + hbase + ch * 8];
  }
  float sq4[4];
#pragma unroll
  for (int r = 0; r < 4; ++r) sq4[r] = sq[i0 + wid * 16 + g * 4 + r];
  __syncthreads();

  const int ntiles = i0 / 64 + 1;
  float m_r[4] = {-1e30f, -1e30f, -1e30f, -1e30f};
  float l_r[4] = {0.f, 0.f, 0.f, 0.f};

  // ---------- pass A: running max + denom ----------
  for (int t = 0; t < ntiles; ++t) {
    const int jt = t * 64;
    __syncthreads();
    for (int c = tid; c < 512; c += 256) {
      int r = c >> 3, ch = c & 7;
      *(float4*)&Ks[r][ch * 8] =
          *(const float4*)&ki[(size_t)(jt + r) * D_DIM + hbase + ch * 8];
    }
    __syncthreads();

    bf16x8 aq0 = *(const bf16x8*)&Qs[wid * 16 + lr][g * 8];
    bf16x8 aq1 = *(const bf16x8*)&Qs[wid * 16 + lr][32 + g * 8];
    f32x4 accs[4] = {};
#pragma unroll
    for (int ni = 0; ni < 4; ++ni) {
      bf16x8 b0 = *(const bf16x8*)&Ks[ni * 16 + lr][g * 8];
      bf16x8 b1 = *(const bf16x8*)&Ks[ni * 16 + lr][32 + g * 8];
      accs[ni] = __builtin_amdgcn_mfma_f32_16x16x32_bf16(aq0, b0, accs[ni], 0, 0, 0);
      accs[ni] = __builtin_amdgcn_mfma_f32_16x16x32_bf16(aq1, b1, accs[ni], 0, 0, 0);
    }

    float sv[4][4];
#pragma unroll
    for (int ni = 0; ni < 4; ++ni) {
      const float skc = sk[jt + ni * 16 + lr];
#pragma unroll
      for (int r = 0; r < 4; ++r) sv[ni][r] = accs[ni][r] * sq4[r] * skc;
    }
    if (t == ntiles - 1) {
      const int jcol = jt + lr, irow = i0 + wid * 16 + g * 4;
#pragma unroll
      for (int ni = 0; ni < 4; ++ni)
#pragma unroll
        for (int r = 0; r < 4; ++r)
          if (jcol + ni * 16 > irow + r) sv[ni][r] = -1e30f;
    }
#pragma unroll
    for (int r = 0; r < 4; ++r) {
      float tmax = fmaxf(fmaxf(sv[0][r], sv[1][r]), fmaxf(sv[2][r], sv[3][r]));
      tmax = fmaxf(tmax, __shfl_xor(tmax, 1, 64));
      tmax = fmaxf(tmax, __shfl_xor(tmax, 2, 64));
      tmax = fmaxf(tmax, __shfl_xor(tmax, 4, 64));
      tmax = fmaxf(tmax, __shfl_xor(tmax, 8, 64));
      float mnew = fmaxf(m_r[r], tmax);
      float sum = __expf(sv[0][r] - mnew) + __expf(sv[1][r] - mnew) +
                  __expf(sv[2][r] - mnew) + __expf(sv[3][r] - mnew);
      sum += __shfl_xor(sum, 1, 64);
      sum += __shfl_xor(sum, 2, 64);
      sum += __shfl_xor(sum, 4, 64);
      sum += __shfl_xor(sum, 8, 64);
      l_r[r] = l_r[r] * __expf(m_r[r] - mnew) + sum;
      m_r[r] = mnew;
    }
  }

  float qsc[4], idn[4];
#pragma unroll
  for (int r = 0; r < 4; ++r) {
    float sc = fmaxf((1.0f / l_r[r]) / QMAX, 1e-5f);
    qsc[r] = sc;
    idn[r] = 1.0f / (l_r[r] * sc);
  }

  // ---------- pass B: quantized probs @ V ----------
  f32x4 acco[4] = {};
  for (int t = 0; t < ntiles; ++t) {
    const int jt = t * 64;
    __syncthreads();
    for (int c = tid; c < 512; c += 256) {
      int r = c >> 3, ch = c & 7;
      *(float4*)&Ks[r][ch * 8] =
          *(const float4*)&ki[(size_t)(jt + r) * D_DIM + hbase + ch * 8];
    }
    for (int c = tid; c < 512; c += 256) {
      int jr = c & 63, ch = c >> 6;
      float4 v4 = *(const float4*)&vf[(size_t)(jt + jr) * D_DIM + hbase + ch * 8];
      const u16* vv = (const u16*)&v4;
#pragma unroll
      for (int e = 0; e < 8; ++e) Vt[ch * 8 + e][jr] = vv[e];
    }
    __syncthreads();

    bf16x8 aq0 = *(const bf16x8*)&Qs[wid * 16 + lr][g * 8];
    bf16x8 aq1 = *(const bf16x8*)&Qs[wid * 16 + lr][32 + g * 8];
    f32x4 accs[4] = {};
#pragma unroll
    for (int ni = 0; ni < 4; ++ni) {
      bf16x8 b0 = *(const bf16x8*)&Ks[ni * 16 + lr][g * 8];
      bf16x8 b1 = *(const bf16x8*)&Ks[ni * 16 + lr][32 + g * 8];
      accs[ni] = __builtin_amdgcn_mfma_f32_16x16x32_bf16(aq0, b0, accs[ni], 0, 0, 0);
      accs[ni] = __builtin_amdgcn_mfma_f32_16x16x32_bf16(aq1, b1, accs[ni], 0, 0, 0);
    }

    const bool diag = (t == ntiles - 1);
    const int jcol = jt + lr, irow = i0 + wid * 16 + g * 4;
#pragma unroll
    for (int ni = 0; ni < 4; ++ni) {
      const float skc = sk[jt + ni * 16 + lr];
#pragma unroll
      for (int r = 0; r < 4; ++r) {
        float s = accs[ni][r] * sq4[r] * skc;
        if (diag && (jcol + ni * 16 > irow + r)) s = -1e30f;
        float e = __expf(s - m_r[r]);
        float q8 = fminf(fmaxf(rintf(e * idn[r]), 0.f), QMAX);
        Ps[wid * 16 + g * 4 + r][ni * 16 + lr] = f32i_to_bf16(q8);
      }
    }
    // Ps rows [wid*16, wid*16+16) are wave-local: no barrier needed

    bf16x8 ap0 = *(const bf16x8*)&Ps[wid * 16 + lr][g * 8];
    bf16x8 ap1 = *(const bf16x8*)&Ps[wid * 16 + lr][32 + g * 8];
#pragma unroll
    for (int ni = 0; ni < 4; ++ni) {
      bf16x8 b0 = *(const bf16x8*)&Vt[ni * 16 + lr][g * 8];
      bf16x8 b1 = *(const bf16x8*)&Vt[ni * 16 + lr][32 + g * 8];
      acco[ni] = __builtin_amdgcn_mfma_f32_16x16x32_bf16(ap0, b0, acco[ni], 0, 0, 0);
      acco[ni] = __builtin_amdgcn_mfma_f32_16x16x32_bf16(ap1, b1, acco[ni], 0, 0, 0);
    }
  }

#pragma unroll
  for (int ni = 0; ni < 4; ++ni)
#pragma unroll
    for (int r = 0; r < 4; ++r) {
      const int row = i0 + wid * 16 + g * 4 + r;
      ctx[(size_t)row * D_DIM + hbase + ni * 16 + lr] = acco[ni][r] * qsc[r];
    }
}

extern "C" void kernel_launch(void* const* d_in, const int* in_sizes, int n_in,
                              void* d_out, int out_size, void* d_ws, size_t ws_size,
                              hipStream_t stream) {
  (void)in_sizes; (void)n_in; (void)out_size;
  const float* hs  = (const float*)d_in[0];
  const float* Wq  = (const float*)d_in[2];
  const float* bq  = (const float*)d_in[3];
  const float* Wk  = (const float*)d_in[4];
  const float* bk  = (const float*)d_in[5];
  const float* Wv  = (const float*)d_in[6];
  const float* bv  = (const float*)d_in[7];
  const float* Wo  = (const float*)d_in[8];
  const float* bo  = (const float*)d_in[9];
  const float* g1  = (const float*)d_in[10];
  const float* be1 = (const float*)d_in[11];
  const float* W1  = (const float*)d_in[12];
  const float* bf1 = (const float*)d_in[13];
  const float* W2  = (const float*)d_in[14];
  const float* bf2 = (const float*)d_in[15];
  const float* g2  = (const float*)d_in[16];
  const float* be2 = (const float*)d_in[17];
  float* out = (float*)d_out;

  const size_t SD = (size_t)S_LEN * D_DIM;
  const size_t SF = (size_t)S_LEN * FF_DIM;  // == 4*SD

  float* f = (float*)d_ws;
  float* qb  = f; f += SD;
  float* kb  = f; f += SD;
  float* vb  = f; f += SD;
  float* ctx = f; f += SD;
  float* h2  = f; f += SD;
  float* f1  = qb;  // [S,FF] fp32, alias qb..ctx (lifetimes disjoint)
  float* sx  = f; f += S_LEN;
  float* sxf = f; f += S_LEN;
  float* sqv = f; f += S_LEN;
  float* skv = f; f += S_LEN;
  float* swq = f; f += D_DIM;
  float* swk = f; f += D_DIM;
  float* swv = f; f += D_DIM;
  float* swo = f; f += D_DIM;
  float* sw1 = f; f += FF_DIM;
  float* sw2 = f; f += D_DIM;
  u16* xi  = (u16*)f;           // [S,D] bf16 ints (x1 / ctx / x2, reused)
  u16* f1i = xi + SD;           // [S,FF] (late); early: aliases qi8/ki8/vfb
  u16* qi8 = f1i;
  u16* ki8 = f1i + SD;
  u16* vfb = f1i + 2 * SD;
  u16* wqi = f1i + SF;
  u16* wki = wqi + SD;
  u16* wvi = wki + SD;
  u16* woi = wvi + SD;
  u16* w1i = woi + SD;          // [FF,D]
  u16* w2i = w1i + SF;          // [D,FF]
  size_t need = (size_t)((char*)(w2i + SF) - (char*)d_ws);
  if (ws_size < need) return;

  dim3 blk(256);

  wquant<<<D_DIM, blk, 0, stream>>>(Wq, wqi, swq, D_DIM);
  wquant<<<D_DIM, blk, 0, stream>>>(Wk, wki, swk, D_DIM);
  wquant<<<D_DIM, blk, 0, stream>>>(Wv, wvi, swv, D_DIM);
  wquant<<<D_DIM, blk, 0, stream>>>(Wo, woi, swo, D_DIM);
  wquant<<<FF_DIM, blk, 0, stream>>>(W1, w1i, sw1, D_DIM);
  wquant<<<D_DIM, blk, 0, stream>>>(W2, w2i, sw2, FF_DIM);

  ln_quant_bf16<<<S_LEN, blk, 0, stream>>>(hs, g1, be1, xi, sx);

  dim3 gqkv(3 * D_DIM / 64, S_LEN / 128);
  gemm_qkv<<<gqkv, blk, 0, stream>>>(xi, sx,
                                     wqi, swq, bq, qb,
                                     wki, swk, bk, kb,
                                     wvi, swv, bv, vb);

  act_quant_bf16<<<S_LEN, blk, 0, stream>>>(qb, qi8, sqv, D_DIM, 0.125f, 0);
  act_quant_bf16<<<S_LEN, blk, 0, stream>>>(kb, ki8, skv, D_DIM, 1.0f, 0);
  act_quant_vf<<<S_LEN, blk, 0, stream>>>(vb, vfb, D_DIM);

  attn_fused<<<(S_LEN / 64) * H_NUM, blk, 0, stream>>>(qi8, sqv, ki8, skv, vfb, ctx);

  act_quant_bf16<<<S_LEN, blk, 0, stream>>>(ctx, xi, sx, D_DIM, 1.0f, 0);
  dim3 gdd64(D_DIM / 64, S_LEN / 128);
  gemm_bn64<<<gdd64, blk, 0, stream>>>(xi, sx, woi, swo, bo, hs, h2, D_DIM, D_DIM);

  ln_quant_bf16<<<S_LEN, blk, 0, stream>>>(h2, g2, be2, xi, sx);

  dim3 gff(FF_DIM / 128, S_LEN / 128);
  gemm_mfma<<<gff, blk, 0, stream>>>(xi, sx, w1i, sw1, bf1, nullptr, f1, S_LEN, FF_DIM, D_DIM);
  act_quant_bf16<<<S_LEN, blk, 0, stream>>>(f1, f1i, sxf, FF_DIM, 1.0f, 1);
  gemm_bn64<<<gdd64, blk, 0, stream>>>(f1i, sxf, w2i, sw2, bf2, h2, out, D_DIM, FF_DIM);
}

// Round 5
// 702.351 us; speedup vs baseline: 6.8626x; 1.0239x over previous
//
#include <hip/hip_runtime.h>
#include <hip/hip_bf16.h>
#include <math.h>

#define S_LEN 2048
#define D_DIM 2048
#define H_NUM 32
#define HD_DIM 64
#define FF_DIM 8192
#define QMAX 255.0f

typedef __attribute__((ext_vector_type(4))) float f32x4;
typedef __attribute__((ext_vector_type(8))) __bf16 bf16x8;
typedef unsigned short u16;

__device__ __forceinline__ u16 f32i_to_bf16(float v) {
  // v is an exact integer in [-255,255]: fp32 low 16 bits are zero -> exact bf16
  return (u16)(__float_as_uint(v) >> 16);
}
__device__ __forceinline__ u16 f32_to_bf16_rne(float v) {
  __bf16 b = (__bf16)v;
  return *(u16*)&b;
}

__device__ __forceinline__ float wred_sum(float v) {
#pragma unroll
  for (int o = 1; o < 64; o <<= 1) v += __shfl_xor(v, o, 64);
  return v;
}
__device__ __forceinline__ float wred_min(float v) {
#pragma unroll
  for (int o = 1; o < 64; o <<= 1) v = fminf(v, __shfl_xor(v, o, 64));
  return v;
}
__device__ __forceinline__ float wred_max(float v) {
#pragma unroll
  for (int o = 1; o < 64; o <<= 1) v = fmaxf(v, __shfl_xor(v, o, 64));
  return v;
}

__device__ __forceinline__ void gload_lds16(const void* g, void* l) {
  __builtin_amdgcn_global_load_lds(
      (__attribute__((address_space(1))) void*)(g),
      (__attribute__((address_space(3))) void*)(l), 16, 0, 0);
}

// ---- LayerNorm + per-token quant -> bf16 integer (q-zp) + row scale ----
__global__ __launch_bounds__(256) void ln_quant_bf16(const float* __restrict__ x,
                                                     const float* __restrict__ g,
                                                     const float* __restrict__ bvec,
                                                     u16* __restrict__ out,
                                                     float* __restrict__ srow) {
  __shared__ float red[8];
  const int row = blockIdx.x, tid = threadIdx.x;
  const float4* xr = (const float4*)(x + (size_t)row * D_DIM);
  const float4* g4 = (const float4*)g;
  const float4* b4 = (const float4*)bvec;

  float4 v0 = xr[tid], v1 = xr[tid + 256];
  float s = v0.x + v0.y + v0.z + v0.w + v1.x + v1.y + v1.z + v1.w;
  float ss = v0.x * v0.x + v0.y * v0.y + v0.z * v0.z + v0.w * v0.w +
             v1.x * v1.x + v1.y * v1.y + v1.z * v1.z + v1.w * v1.w;
  s = wred_sum(s); ss = wred_sum(ss);
  if ((tid & 63) == 0) { red[tid >> 6] = s; red[4 + (tid >> 6)] = ss; }
  __syncthreads();
  float mu = (red[0] + red[1] + red[2] + red[3]) / (float)D_DIM;
  float var = (red[4] + red[5] + red[6] + red[7]) / (float)D_DIM - mu * mu;
  float rstd = 1.0f / sqrtf(var + 1e-5f);
  __syncthreads();

  float mn = 0.f, mx = 0.f;
  float4 n0, n1;
  {
    float4 gg = g4[tid], bb = b4[tid];
    n0.x = (v0.x - mu) * rstd * gg.x + bb.x; n0.y = (v0.y - mu) * rstd * gg.y + bb.y;
    n0.z = (v0.z - mu) * rstd * gg.z + bb.z; n0.w = (v0.w - mu) * rstd * gg.w + bb.w;
    gg = g4[tid + 256]; bb = b4[tid + 256];
    n1.x = (v1.x - mu) * rstd * gg.x + bb.x; n1.y = (v1.y - mu) * rstd * gg.y + bb.y;
    n1.z = (v1.z - mu) * rstd * gg.z + bb.z; n1.w = (v1.w - mu) * rstd * gg.w + bb.w;
    mn = fminf(mn, fminf(fminf(n0.x, n0.y), fminf(n0.z, n0.w)));
    mn = fminf(mn, fminf(fminf(n1.x, n1.y), fminf(n1.z, n1.w)));
    mx = fmaxf(mx, fmaxf(fmaxf(n0.x, n0.y), fmaxf(n0.z, n0.w)));
    mx = fmaxf(mx, fmaxf(fmaxf(n1.x, n1.y), fmaxf(n1.z, n1.w)));
  }
  mn = wred_min(mn); mx = wred_max(mx);
  if ((tid & 63) == 0) { red[tid >> 6] = mn; red[4 + (tid >> 6)] = mx; }
  __syncthreads();
  mn = fminf(fminf(red[0], red[1]), fminf(red[2], red[3]));
  mx = fmaxf(fmaxf(red[4], red[5]), fmaxf(red[6], red[7]));
  float scale = fmaxf((mx - mn) / QMAX, 1e-5f);
  float zp = rintf(-mn / scale);
  if (tid == 0) srow[row] = scale;
  ushort4 o0, o1;
  o0.x = f32i_to_bf16(fminf(fmaxf(rintf(n0.x / scale) + zp, 0.f), QMAX) - zp);
  o0.y = f32i_to_bf16(fminf(fmaxf(rintf(n0.y / scale) + zp, 0.f), QMAX) - zp);
  o0.z = f32i_to_bf16(fminf(fmaxf(rintf(n0.z / scale) + zp, 0.f), QMAX) - zp);
  o0.w = f32i_to_bf16(fminf(fmaxf(rintf(n0.w / scale) + zp, 0.f), QMAX) - zp);
  o1.x = f32i_to_bf16(fminf(fmaxf(rintf(n1.x / scale) + zp, 0.f), QMAX) - zp);
  o1.y = f32i_to_bf16(fminf(fmaxf(rintf(n1.y / scale) + zp, 0.f), QMAX) - zp);
  o1.z = f32i_to_bf16(fminf(fmaxf(rintf(n1.z / scale) + zp, 0.f), QMAX) - zp);
  o1.w = f32i_to_bf16(fminf(fmaxf(rintf(n1.w / scale) + zp, 0.f), QMAX) - zp);
  *(ushort4*)&out[(size_t)row * D_DIM + tid * 4] = o0;
  *(ushort4*)&out[(size_t)row * D_DIM + 1024 + tid * 4] = o1;
}

// ---- fp32 row -> quant -> bf16 int + scale (alpha pre-scale, optional relu) ----
__global__ __launch_bounds__(256) void act_quant_bf16(const float* __restrict__ x,
                                                      u16* __restrict__ out,
                                                      float* __restrict__ srow,
                                                      int N, float alpha, int do_relu) {
  __shared__ float red[8];
  const int row = blockIdx.x, tid = threadIdx.x;
  const float4* xr = (const float4*)(x + (size_t)row * N);
  const int N4 = N >> 2;
  float mn = 0.f, mx = 0.f;
  for (int i = tid; i < N4; i += 256) {
    float4 v = xr[i];
    v.x *= alpha; v.y *= alpha; v.z *= alpha; v.w *= alpha;
    if (do_relu) { v.x = fmaxf(v.x, 0.f); v.y = fmaxf(v.y, 0.f); v.z = fmaxf(v.z, 0.f); v.w = fmaxf(v.w, 0.f); }
    mn = fminf(mn, fminf(fminf(v.x, v.y), fminf(v.z, v.w)));
    mx = fmaxf(mx, fmaxf(fmaxf(v.x, v.y), fmaxf(v.z, v.w)));
  }
  mn = wred_min(mn); mx = wred_max(mx);
  if ((tid & 63) == 0) { red[tid >> 6] = mn; red[4 + (tid >> 6)] = mx; }
  __syncthreads();
  mn = fminf(fminf(red[0], red[1]), fminf(red[2], red[3]));
  mx = fmaxf(fmaxf(red[4], red[5]), fmaxf(red[6], red[7]));
  float scale = fmaxf((mx - mn) / QMAX, 1e-5f);
  float zp = rintf(-mn / scale);
  if (tid == 0) srow[row] = scale;
  for (int i = tid; i < N4; i += 256) {
    float4 v = xr[i];
    v.x *= alpha; v.y *= alpha; v.z *= alpha; v.w *= alpha;
    if (do_relu) { v.x = fmaxf(v.x, 0.f); v.y = fmaxf(v.y, 0.f); v.z = fmaxf(v.z, 0.f); v.w = fmaxf(v.w, 0.f); }
    ushort4 o;
    o.x = f32i_to_bf16(fminf(fmaxf(rintf(v.x / scale) + zp, 0.f), QMAX) - zp);
    o.y = f32i_to_bf16(fminf(fmaxf(rintf(v.y / scale) + zp, 0.f), QMAX) - zp);
    o.z = f32i_to_bf16(fminf(fmaxf(rintf(v.z / scale) + zp, 0.f), QMAX) - zp);
    o.w = f32i_to_bf16(fminf(fmaxf(rintf(v.w / scale) + zp, 0.f), QMAX) - zp);
    *(ushort4*)&out[(size_t)row * N + i * 4] = o;
  }
}

// ---- fp32 row -> fake quant -> bf16 VALUES (attention V operand) ----
__global__ __launch_bounds__(256) void act_quant_vf(const float* __restrict__ x,
                                                    u16* __restrict__ out, int N) {
  __shared__ float red[8];
  const int row = blockIdx.x, tid = threadIdx.x;
  const float4* xr = (const float4*)(x + (size_t)row * N);
  const int N4 = N >> 2;
  float mn = 0.f, mx = 0.f;
  for (int i = tid; i < N4; i += 256) {
    float4 v = xr[i];
    mn = fminf(mn, fminf(fminf(v.x, v.y), fminf(v.z, v.w)));
    mx = fmaxf(mx, fmaxf(fmaxf(v.x, v.y), fmaxf(v.z, v.w)));
  }
  mn = wred_min(mn); mx = wred_max(mx);
  if ((tid & 63) == 0) { red[tid >> 6] = mn; red[4 + (tid >> 6)] = mx; }
  __syncthreads();
  mn = fminf(fminf(red[0], red[1]), fminf(red[2], red[3]));
  mx = fmaxf(fmaxf(red[4], red[5]), fmaxf(red[6], red[7]));
  float scale = fmaxf((mx - mn) / QMAX, 1e-5f);
  float zp = rintf(-mn / scale);
  for (int i = tid; i < N4; i += 256) {
    float4 v = xr[i];
    ushort4 o;
    o.x = f32_to_bf16_rne((fminf(fmaxf(rintf(v.x / scale) + zp, 0.f), QMAX) - zp) * scale);
    o.y = f32_to_bf16_rne((fminf(fmaxf(rintf(v.y / scale) + zp, 0.f), QMAX) - zp) * scale);
    o.z = f32_to_bf16_rne((fminf(fmaxf(rintf(v.z / scale) + zp, 0.f), QMAX) - zp) * scale);
    o.w = f32_to_bf16_rne((fminf(fmaxf(rintf(v.w / scale) + zp, 0.f), QMAX) - zp) * scale);
    *(ushort4*)&out[(size_t)row * N + i * 4] = o;
  }
}

// ---- weight row quant -> bf16 int + per-row scale ----
__global__ __launch_bounds__(256) void wquant(const float* __restrict__ W,
                                              u16* __restrict__ Wi,
                                              float* __restrict__ sc, int K) {
  __shared__ float red[8];
  const int row = blockIdx.x, tid = threadIdx.x;
  const float4* wr = (const float4*)(W + (size_t)row * K);
  const int K4 = K >> 2;
  float mn = 0.f, mx = 0.f;
  for (int i = tid; i < K4; i += 256) {
    float4 v = wr[i];
    mn = fminf(mn, fminf(fminf(v.x, v.y), fminf(v.z, v.w)));
    mx = fmaxf(mx, fmaxf(fmaxf(v.x, v.y), fmaxf(v.z, v.w)));
  }
  mn = wred_min(mn); mx = wred_max(mx);
  if ((tid & 63) == 0) { red[tid >> 6] = mn; red[4 + (tid >> 6)] = mx; }
  __syncthreads();
  mn = fminf(fminf(red[0], red[1]), fminf(red[2], red[3]));
  mx = fmaxf(fmaxf(red[4], red[5]), fmaxf(red[6], red[7]));
  float scale = fmaxf((mx - mn) / QMAX, 1e-5f);
  float zp = rintf(-mn / scale);
  if (tid == 0) sc[row] = scale;
  for (int i = tid; i < K4; i += 256) {
    float4 v = wr[i];
    ushort4 o;
    o.x = f32i_to_bf16(fminf(fmaxf(rintf(v.x / scale) + zp, 0.f), QMAX) - zp);
    o.y = f32i_to_bf16(fminf(fmaxf(rintf(v.y / scale) + zp, 0.f), QMAX) - zp);
    o.z = f32i_to_bf16(fminf(fmaxf(rintf(v.z / scale) + zp, 0.f), QMAX) - zp);
    o.w = f32i_to_bf16(fminf(fmaxf(rintf(v.w / scale) + zp, 0.f), QMAX) - zp);
    *(ushort4*)&Wi[(size_t)row * K + i * 4] = o;
  }
}

// ---- shared 128x128x32 MFMA accumulation body (m97 structure) ----
__device__ __forceinline__ void gemm128_acc(
    const u16* __restrict__ A, const u16* __restrict__ B,
    int K, int bm, int bn, int k_begin, int k_end,
    u16* As, u16* Bs, f32x4 (&acc)[4][4]) {
  const int tid = threadIdx.x;
  const int wid = tid >> 6, lane = tid & 63;
  const int wr = wid >> 1, wc = wid & 1;
  const int lr = lane & 15, lk = lane >> 4;

  const int r0 = tid >> 2, c0 = (tid & 3) * 8;
  const int r1 = (256 + tid) >> 2;
  const size_t ldsb0 = (size_t)(wid * 64) * 8;
  const size_t ldsb1 = (size_t)(256 + wid * 64) * 8;

  for (int k0 = k_begin; k0 < k_end; k0 += 32) {
    gload_lds16(A + (size_t)(bm + r0) * K + k0 + c0, As + ldsb0);
    gload_lds16(A + (size_t)(bm + r1) * K + k0 + c0, As + ldsb1);
    gload_lds16(B + (size_t)(bn + r0) * K + k0 + c0, Bs + ldsb0);
    gload_lds16(B + (size_t)(bn + r1) * K + k0 + c0, Bs + ldsb1);
    __syncthreads();

    bf16x8 af[4], bf[4];
#pragma unroll
    for (int mi = 0; mi < 4; ++mi)
      af[mi] = *(const bf16x8*)&As[(size_t)(wr * 64 + mi * 16 + lr) * 32 + lk * 8];
#pragma unroll
    for (int ni = 0; ni < 4; ++ni)
      bf[ni] = *(const bf16x8*)&Bs[(size_t)(wc * 64 + ni * 16 + lr) * 32 + lk * 8];
#pragma unroll
    for (int mi = 0; mi < 4; ++mi)
#pragma unroll
      for (int ni = 0; ni < 4; ++ni)
        acc[mi][ni] = __builtin_amdgcn_mfma_f32_16x16x32_bf16(af[mi], bf[ni], acc[mi][ni], 0, 0, 0);
    __syncthreads();
  }
}

// ---- full GEMM: C = sa*sb*(A@B^T) + bias (+res) ----
__global__ __launch_bounds__(256) void gemm_mfma(
    const u16* __restrict__ A, const float* __restrict__ sa,
    const u16* __restrict__ B, const float* __restrict__ sb,
    const float* __restrict__ bias, const float* __restrict__ res,
    float* __restrict__ C, int N, int K) {
  __shared__ __align__(16) u16 As[128 * 32];
  __shared__ __align__(16) u16 Bs[128 * 32];
  const int bm = blockIdx.y * 128, bn = blockIdx.x * 128;
  f32x4 acc[4][4] = {};
  gemm128_acc(A, B, K, bm, bn, 0, K, As, Bs, acc);

  const int tid = threadIdx.x;
  const int wid = tid >> 6, lane = tid & 63;
  const int wr = wid >> 1, wc = wid & 1;
  const int lr = lane & 15, lk = lane >> 4;
  const int col0 = bn + wc * 64 + lr;
  const int rbase = bm + wr * 64 + lk * 4;
#pragma unroll
  for (int ni = 0; ni < 4; ++ni) {
    const int col = col0 + ni * 16;
    const float sbc = sb[col];
    const float bc = bias[col];
#pragma unroll
    for (int mi = 0; mi < 4; ++mi)
#pragma unroll
      for (int r = 0; r < 4; ++r) {
        const int row = rbase + mi * 16 + r;
        float v = acc[mi][ni][r] * sa[row] * sbc + bc;
        if (res) v += res[(size_t)row * N + col];
        C[(size_t)row * N + col] = v;
      }
  }
}

// ---- fused QKV (three weights share A), 128^2 tiles ----
__global__ __launch_bounds__(256) void gemm_qkv128(
    const u16* __restrict__ A, const float* __restrict__ sa,
    const u16* __restrict__ Bq, const float* __restrict__ sbq, const float* __restrict__ biasq, float* __restrict__ Cq,
    const u16* __restrict__ Bk, const float* __restrict__ sbk, const float* __restrict__ biask, float* __restrict__ Ck,
    const u16* __restrict__ Bv, const float* __restrict__ sbv, const float* __restrict__ biasv, float* __restrict__ Cv) {
  __shared__ __align__(16) u16 As[128 * 32];
  __shared__ __align__(16) u16 Bs[128 * 32];
  const int which = blockIdx.x >> 4;          // D/128 = 16 col-tiles per weight
  const int bn = (blockIdx.x & 15) * 128;
  const int bm = blockIdx.y * 128;
  const u16* B = (which == 0) ? Bq : (which == 1) ? Bk : Bv;
  const float* sb = (which == 0) ? sbq : (which == 1) ? sbk : sbv;
  const float* bias = (which == 0) ? biasq : (which == 1) ? biask : biasv;
  float* C = (which == 0) ? Cq : (which == 1) ? Ck : Cv;

  f32x4 acc[4][4] = {};
  gemm128_acc(A, B, D_DIM, bm, bn, 0, D_DIM, As, Bs, acc);

  const int tid = threadIdx.x;
  const int wid = tid >> 6, lane = tid & 63;
  const int wr = wid >> 1, wc = wid & 1;
  const int lr = lane & 15, lk = lane >> 4;
  const int col0 = bn + wc * 64 + lr;
  const int rbase = bm + wr * 64 + lk * 4;
#pragma unroll
  for (int ni = 0; ni < 4; ++ni) {
    const int col = col0 + ni * 16;
    const float sbc = sb[col];
    const float bc = bias[col];
#pragma unroll
    for (int mi = 0; mi < 4; ++mi)
#pragma unroll
      for (int r = 0; r < 4; ++r) {
        const int row = rbase + mi * 16 + r;
        C[(size_t)row * D_DIM + col] = acc[mi][ni][r] * sa[row] * sbc + bc;
      }
  }
}

// ---- split-K partial GEMM: part[z] = sa*sb*(A@B^T) over K-chunk z ----
__global__ __launch_bounds__(256) void gemm_splitk(
    const u16* __restrict__ A, const float* __restrict__ sa,
    const u16* __restrict__ B, const float* __restrict__ sb,
    float* __restrict__ part, int N, int K, int kchunk) {
  __shared__ __align__(16) u16 As[128 * 32];
  __shared__ __align__(16) u16 Bs[128 * 32];
  const int bm = blockIdx.y * 128, bn = blockIdx.x * 128;
  const int ks = blockIdx.z;
  f32x4 acc[4][4] = {};
  gemm128_acc(A, B, K, bm, bn, ks * kchunk, (ks + 1) * kchunk, As, Bs, acc);

  float* dst = part + (size_t)ks * S_LEN * N;
  const int tid = threadIdx.x;
  const int wid = tid >> 6, lane = tid & 63;
  const int wr = wid >> 1, wc = wid & 1;
  const int lr = lane & 15, lk = lane >> 4;
  const int col0 = bn + wc * 64 + lr;
  const int rbase = bm + wr * 64 + lk * 4;
#pragma unroll
  for (int ni = 0; ni < 4; ++ni) {
    const int col = col0 + ni * 16;
    const float sbc = sb[col];
#pragma unroll
    for (int mi = 0; mi < 4; ++mi)
#pragma unroll
      for (int r = 0; r < 4; ++r) {
        const int row = rbase + mi * 16 + r;
        dst[(size_t)row * N + col] = acc[mi][ni][r] * sa[row] * sbc;
      }
  }
}

// ---- split-K reduce: out = sum(part) + bias (+res) ----
__global__ __launch_bounds__(256) void splitk_reduce(
    const float* __restrict__ part, int nsplit,
    const float* __restrict__ bias, const float* __restrict__ res,
    float* __restrict__ out, int N) {
  const size_t stride4 = (size_t)S_LEN * N / 4;
  const int n4 = N >> 2;
  for (size_t i = (size_t)blockIdx.x * 256 + threadIdx.x; i < stride4;
       i += (size_t)gridDim.x * 256) {
    float4 s = ((const float4*)part)[i];
    for (int k = 1; k < nsplit; ++k) {
      float4 p = ((const float4*)part)[i + (size_t)k * stride4];
      s.x += p.x; s.y += p.y; s.z += p.z; s.w += p.w;
    }
    float4 b4 = ((const float4*)bias)[i % n4];
    s.x += b4.x; s.y += b4.y; s.z += b4.z; s.w += b4.w;
    if (res) {
      float4 r = ((const float4*)res)[i];
      s.x += r.x; s.y += r.y; s.z += r.z; s.w += r.w;
    }
    ((float4*)out)[i] = s;
  }
}

// ---- fused causal attention with quantized probs, MFMA both passes ----
__global__ __launch_bounds__(256) void attn_fused(
    const u16* __restrict__ qi, const float* __restrict__ sq,
    const u16* __restrict__ ki, const float* __restrict__ sk,
    const u16* __restrict__ vf, float* __restrict__ ctx) {
  __shared__ __align__(16) u16 Qs[64][72];
  __shared__ __align__(16) u16 Ks[64][72];
  __shared__ __align__(16) u16 Ps[64][72];
  __shared__ __align__(16) u16 Vt[64][72];
  const int bid = blockIdx.x;
  const int ti = (S_LEN / 64 - 1) - (bid >> 5);  // heavy tiles first
  const int h = bid & (H_NUM - 1);
  const int i0 = ti * 64;
  const int tid = threadIdx.x;
  const int wid = tid >> 6, lane = tid & 63;
  const int lr = lane & 15, g = lane >> 4;
  const size_t hbase = (size_t)h * HD_DIM;

  for (int c = tid; c < 512; c += 256) {
    int r = c >> 3, ch = c & 7;
    *(float4*)&Qs[r][ch * 8] =
        *(const float4*)&qi[(size_t)(i0 + r) * D_DIM + hbase + ch * 8];
  }
  float sq4[4];
#pragma unroll
  for (int r = 0; r < 4; ++r) sq4[r] = sq[i0 + wid * 16 + g * 4 + r];
  __syncthreads();

  const int ntiles = i0 / 64 + 1;
  float m_r[4] = {-1e30f, -1e30f, -1e30f, -1e30f};
  float l_r[4] = {0.f, 0.f, 0.f, 0.f};

  for (int t = 0; t < ntiles; ++t) {
    const int jt = t * 64;
    __syncthreads();
    for (int c = tid; c < 512; c += 256) {
      int r = c >> 3, ch = c & 7;
      *(float4*)&Ks[r][ch * 8] =
          *(const float4*)&ki[(size_t)(jt + r) * D_DIM + hbase + ch * 8];
    }
    __syncthreads();

    bf16x8 aq0 = *(const bf16x8*)&Qs[wid * 16 + lr][g * 8];
    bf16x8 aq1 = *(const bf16x8*)&Qs[wid * 16 + lr][32 + g * 8];
    f32x4 accs[4] = {};
#pragma unroll
    for (int ni = 0; ni < 4; ++ni) {
      bf16x8 b0 = *(const bf16x8*)&Ks[ni * 16 + lr][g * 8];
      bf16x8 b1 = *(const bf16x8*)&Ks[ni * 16 + lr][32 + g * 8];
      accs[ni] = __builtin_amdgcn_mfma_f32_16x16x32_bf16(aq0, b0, accs[ni], 0, 0, 0);
      accs[ni] = __builtin_amdgcn_mfma_f32_16x16x32_bf16(aq1, b1, accs[ni], 0, 0, 0);
    }

    float sv[4][4];
#pragma unroll
    for (int ni = 0; ni < 4; ++ni) {
      const float skc = sk[jt + ni * 16 + lr];
#pragma unroll
      for (int r = 0; r < 4; ++r) sv[ni][r] = accs[ni][r] * sq4[r] * skc;
    }
    if (t == ntiles - 1) {
      const int jcol = jt + lr, irow = i0 + wid * 16 + g * 4;
#pragma unroll
      for (int ni = 0; ni < 4; ++ni)
#pragma unroll
        for (int r = 0; r < 4; ++r)
          if (jcol + ni * 16 > irow + r) sv[ni][r] = -1e30f;
    }
#pragma unroll
    for (int r = 0; r < 4; ++r) {
      float tmax = fmaxf(fmaxf(sv[0][r], sv[1][r]), fmaxf(sv[2][r], sv[3][r]));
      tmax = fmaxf(tmax, __shfl_xor(tmax, 1, 64));
      tmax = fmaxf(tmax, __shfl_xor(tmax, 2, 64));
      tmax = fmaxf(tmax, __shfl_xor(tmax, 4, 64));
      tmax = fmaxf(tmax, __shfl_xor(tmax, 8, 64));
      float mnew = fmaxf(m_r[r], tmax);
      float sum = __expf(sv[0][r] - mnew) + __expf(sv[1][r] - mnew) +
                  __expf(sv[2][r] - mnew) + __expf(sv[3][r] - mnew);
      sum += __shfl_xor(sum, 1, 64);
      sum += __shfl_xor(sum, 2, 64);
      sum += __shfl_xor(sum, 4, 64);
      sum += __shfl_xor(sum, 8, 64);
      l_r[r] = l_r[r] * __expf(m_r[r] - mnew) + sum;
      m_r[r] = mnew;
    }
  }

  float qsc[4], idn[4];
#pragma unroll
  for (int r = 0; r < 4; ++r) {
    float sc = fmaxf((1.0f / l_r[r]) / QMAX, 1e-5f);
    qsc[r] = sc;
    idn[r] = 1.0f / (l_r[r] * sc);
  }

  f32x4 acco[4] = {};
  for (int t = 0; t < ntiles; ++t) {
    const int jt = t * 64;
    __syncthreads();
    for (int c = tid; c < 512; c += 256) {
      int r = c >> 3, ch = c & 7;
      *(float4*)&Ks[r][ch * 8] =
          *(const float4*)&ki[(size_t)(jt + r) * D_DIM + hbase + ch * 8];
    }
    for (int c = tid; c < 512; c += 256) {
      int jr = c & 63, ch = c >> 6;
      float4 v4 = *(const float4*)&vf[(size_t)(jt + jr) * D_DIM + hbase + ch * 8];
      const u16* vv = (const u16*)&v4;
#pragma unroll
      for (int e = 0; e < 8; ++e) Vt[ch * 8 + e][jr] = vv[e];
    }
    __syncthreads();

    bf16x8 aq0 = *(const bf16x8*)&Qs[wid * 16 + lr][g * 8];
    bf16x8 aq1 = *(const bf16x8*)&Qs[wid * 16 + lr][32 + g * 8];
    f32x4 accs[4] = {};
#pragma unroll
    for (int ni = 0; ni < 4; ++ni) {
      bf16x8 b0 = *(const bf16x8*)&Ks[ni * 16 + lr][g * 8];
      bf16x8 b1 = *(const bf16x8*)&Ks[ni * 16 + lr][32 + g * 8];
      accs[ni] = __builtin_amdgcn_mfma_f32_16x16x32_bf16(aq0, b0, accs[ni], 0, 0, 0);
      accs[ni] = __builtin_amdgcn_mfma_f32_16x16x32_bf16(aq1, b1, accs[ni], 0, 0, 0);
    }

    const bool diag = (t == ntiles - 1);
    const int jcol = jt + lr, irow = i0 + wid * 16 + g * 4;
#pragma unroll
    for (int ni = 0; ni < 4; ++ni) {
      const float skc = sk[jt + ni * 16 + lr];
#pragma unroll
      for (int r = 0; r < 4; ++r) {
        float s = accs[ni][r] * sq4[r] * skc;
        if (diag && (jcol + ni * 16 > irow + r)) s = -1e30f;
        float e = __expf(s - m_r[r]);
        float q8 = fminf(fmaxf(rintf(e * idn[r]), 0.f), QMAX);
        Ps[wid * 16 + g * 4 + r][ni * 16 + lr] = f32i_to_bf16(q8);
      }
    }
    // Ps rows for this wave are wave-local: no barrier needed

    bf16x8 ap0 = *(const bf16x8*)&Ps[wid * 16 + lr][g * 8];
    bf16x8 ap1 = *(const bf16x8*)&Ps[wid * 16 + lr][32 + g * 8];
#pragma unroll
    for (int ni = 0; ni < 4; ++ni) {
      bf16x8 b0 = *(const bf16x8*)&Vt[ni * 16 + lr][g * 8];
      bf16x8 b1 = *(const bf16x8*)&Vt[ni * 16 + lr][32 + g * 8];
      acco[ni] = __builtin_amdgcn_mfma_f32_16x16x32_bf16(ap0, b0, acco[ni], 0, 0, 0);
      acco[ni] = __builtin_amdgcn_mfma_f32_16x16x32_bf16(ap1, b1, acco[ni], 0, 0, 0);
    }
  }

#pragma unroll
  for (int ni = 0; ni < 4; ++ni)
#pragma unroll
    for (int r = 0; r < 4; ++r) {
      const int row = i0 + wid * 16 + g * 4 + r;
      ctx[(size_t)row * D_DIM + hbase + ni * 16 + lr] = acco[ni][r] * qsc[r];
    }
}

extern "C" void kernel_launch(void* const* d_in, const int* in_sizes, int n_in,
                              void* d_out, int out_size, void* d_ws, size_t ws_size,
                              hipStream_t stream) {
  (void)in_sizes; (void)n_in; (void)out_size;
  const float* hs  = (const float*)d_in[0];
  const float* Wq  = (const float*)d_in[2];
  const float* bq  = (const float*)d_in[3];
  const float* Wk  = (const float*)d_in[4];
  const float* bk  = (const float*)d_in[5];
  const float* Wv  = (const float*)d_in[6];
  const float* bv  = (const float*)d_in[7];
  const float* Wo  = (const float*)d_in[8];
  const float* bo  = (const float*)d_in[9];
  const float* g1  = (const float*)d_in[10];
  const float* be1 = (const float*)d_in[11];
  const float* W1  = (const float*)d_in[12];
  const float* bf1 = (const float*)d_in[13];
  const float* W2  = (const float*)d_in[14];
  const float* bf2 = (const float*)d_in[15];
  const float* g2  = (const float*)d_in[16];
  const float* be2 = (const float*)d_in[17];
  float* out = (float*)d_out;

  const size_t SD = (size_t)S_LEN * D_DIM;
  const size_t SF = (size_t)S_LEN * FF_DIM;  // == 4*SD

  float* f = (float*)d_ws;
  float* qb  = f; f += SD;
  float* kb  = f; f += SD;
  float* vb  = f; f += SD;
  float* ctx = f; f += SD;
  float* h2  = f; f += SD;
  float* f1  = qb;      // [S,FF] fp32 W1 output, aliases qb..ctx (disjoint lifetime)
  float* pwo = qb;      // Wo split-K partials (2*SD), alias dead qb/kb
  float* pw2 = qb;      // W2 split-K partials (4*SD), alias dead f1 region
  float* sx  = f; f += S_LEN;
  float* sxf = f; f += S_LEN;
  float* sqv = f; f += S_LEN;
  float* skv = f; f += S_LEN;
  float* swq = f; f += D_DIM;
  float* swk = f; f += D_DIM;
  float* swv = f; f += D_DIM;
  float* swo = f; f += D_DIM;
  float* sw1 = f; f += FF_DIM;
  float* sw2 = f; f += D_DIM;
  u16* xi  = (u16*)f;           // [S,D] bf16 ints (x1 / ctx / x2, reused)
  u16* f1i = xi + SD;           // [S,FF] (late); early: aliases qi8/ki8/vfb
  u16* qi8 = f1i;
  u16* ki8 = f1i + SD;
  u16* vfb = f1i + 2 * SD;
  u16* wqi = f1i + SF;
  u16* wki = wqi + SD;
  u16* wvi = wki + SD;
  u16* woi = wvi + SD;
  u16* w1i = woi + SD;          // [FF,D]
  u16* w2i = w1i + SF;          // [D,FF]
  size_t need = (size_t)((char*)(w2i + SF) - (char*)d_ws);
  if (ws_size < need) return;

  dim3 blk(256);

  wquant<<<D_DIM, blk, 0, stream>>>(Wq, wqi, swq, D_DIM);
  wquant<<<D_DIM, blk, 0, stream>>>(Wk, wki, swk, D_DIM);
  wquant<<<D_DIM, blk, 0, stream>>>(Wv, wvi, swv, D_DIM);
  wquant<<<D_DIM, blk, 0, stream>>>(Wo, woi, swo, D_DIM);
  wquant<<<FF_DIM, blk, 0, stream>>>(W1, w1i, sw1, D_DIM);
  wquant<<<D_DIM, blk, 0, stream>>>(W2, w2i, sw2, FF_DIM);

  ln_quant_bf16<<<S_LEN, blk, 0, stream>>>(hs, g1, be1, xi, sx);

  // fused QKV, 128^2 tiles: grid 48 x 16 = 768 blocks
  dim3 gqkv(3 * D_DIM / 128, S_LEN / 128);
  gemm_qkv128<<<gqkv, blk, 0, stream>>>(xi, sx,
                                        wqi, swq, bq, qb,
                                        wki, swk, bk, kb,
                                        wvi, swv, bv, vb);

  act_quant_bf16<<<S_LEN, blk, 0, stream>>>(qb, qi8, sqv, D_DIM, 0.125f, 0);
  act_quant_bf16<<<S_LEN, blk, 0, stream>>>(kb, ki8, skv, D_DIM, 1.0f, 0);
  act_quant_vf<<<S_LEN, blk, 0, stream>>>(vb, vfb, D_DIM);

  attn_fused<<<(S_LEN / 64) * H_NUM, blk, 0, stream>>>(qi8, sqv, ki8, skv, vfb, ctx);

  act_quant_bf16<<<S_LEN, blk, 0, stream>>>(ctx, xi, sx, D_DIM, 1.0f, 0);

  // Wo: split-K=2 (qb/kb dead -> partials), reduce adds bias + residual(hs)
  dim3 gwo(D_DIM / 128, S_LEN / 128, 2);
  gemm_splitk<<<gwo, blk, 0, stream>>>(xi, sx, woi, swo, pwo, D_DIM, D_DIM, D_DIM / 2);
  splitk_reduce<<<2048, blk, 0, stream>>>(pwo, 2, bo, hs, h2, D_DIM);

  ln_quant_bf16<<<S_LEN, blk, 0, stream>>>(h2, g2, be2, xi, sx);

  dim3 gff(FF_DIM / 128, S_LEN / 128);
  gemm_mfma<<<gff, blk, 0, stream>>>(xi, sx, w1i, sw1, bf1, nullptr, f1, FF_DIM, D_DIM);
  act_quant_bf16<<<S_LEN, blk, 0, stream>>>(f1, f1i, sxf, FF_DIM, 1.0f, 1);

  // W2: split-K=4 (f1 fp32 dead -> partials), reduce adds bias + residual(h2)
  dim3 gw2(D_DIM / 128, S_LEN / 128, 4);
  gemm_splitk<<<gw2, blk, 0, stream>>>(f1i, sxf, w2i, sw2, pw2, D_DIM, FF_DIM, FF_DIM / 4);
  splitk_reduce<<<2048, blk, 0, stream>>>(pw2, 4, bf2, h2, out, D_DIM);
}

// Round 6
// 609.493 us; speedup vs baseline: 7.9081x; 1.1524x over previous
//
#include <hip/hip_runtime.h>
#include <hip/hip_bf16.h>
#include <math.h>

#define S_LEN 2048
#define D_DIM 2048
#define H_NUM 32
#define HD_DIM 64
#define FF_DIM 8192
#define QMAX 255.0f

typedef __attribute__((ext_vector_type(4))) float f32x4;
typedef __attribute__((ext_vector_type(8))) __bf16 bf16x8;
typedef unsigned short u16;

__device__ __forceinline__ u16 f32i_to_bf16(float v) {
  // v is an exact integer in [-255,255]: fp32 low 16 bits are zero -> exact bf16
  return (u16)(__float_as_uint(v) >> 16);
}
__device__ __forceinline__ u16 f32_to_bf16_rne(float v) {
  __bf16 b = (__bf16)v;
  return *(u16*)&b;
}
__device__ __forceinline__ float bf16_to_f32(u16 u) {
  return __uint_as_float((unsigned int)u << 16);
}

__device__ __forceinline__ float wred_sum(float v) {
#pragma unroll
  for (int o = 1; o < 64; o <<= 1) v += __shfl_xor(v, o, 64);
  return v;
}
__device__ __forceinline__ float wred_min(float v) {
#pragma unroll
  for (int o = 1; o < 64; o <<= 1) v = fminf(v, __shfl_xor(v, o, 64));
  return v;
}
__device__ __forceinline__ float wred_max(float v) {
#pragma unroll
  for (int o = 1; o < 64; o <<= 1) v = fmaxf(v, __shfl_xor(v, o, 64));
  return v;
}

__device__ __forceinline__ void gload_lds16(const void* g, void* l) {
  __builtin_amdgcn_global_load_lds(
      (__attribute__((address_space(1))) void*)(g),
      (__attribute__((address_space(3))) void*)(l), 16, 0, 0);
}

// bijective XCD-aware swizzle of the 2D grid (requires (gx*gy)%8==0)
__device__ __forceinline__ void xcd_swz(int& bx, int& by) {
  const int gx = gridDim.x;
  const int nwg = gx * gridDim.y;
  const int orig = blockIdx.x + gx * blockIdx.y;
  const int swz = (orig & 7) * (nwg >> 3) + (orig >> 3);
  bx = swz % gx;
  by = swz / gx;
}

// ---- LayerNorm + per-token quant -> bf16 integer (q-zp) + row scale ----
__global__ __launch_bounds__(256) void ln_quant_bf16(const float* __restrict__ x,
                                                     const float* __restrict__ g,
                                                     const float* __restrict__ bvec,
                                                     u16* __restrict__ out,
                                                     float* __restrict__ srow) {
  __shared__ float red[8];
  const int row = blockIdx.x, tid = threadIdx.x;
  const float4* xr = (const float4*)(x + (size_t)row * D_DIM);
  const float4* g4 = (const float4*)g;
  const float4* b4 = (const float4*)bvec;

  float4 v0 = xr[tid], v1 = xr[tid + 256];
  float s = v0.x + v0.y + v0.z + v0.w + v1.x + v1.y + v1.z + v1.w;
  float ss = v0.x * v0.x + v0.y * v0.y + v0.z * v0.z + v0.w * v0.w +
             v1.x * v1.x + v1.y * v1.y + v1.z * v1.z + v1.w * v1.w;
  s = wred_sum(s); ss = wred_sum(ss);
  if ((tid & 63) == 0) { red[tid >> 6] = s; red[4 + (tid >> 6)] = ss; }
  __syncthreads();
  float mu = (red[0] + red[1] + red[2] + red[3]) / (float)D_DIM;
  float var = (red[4] + red[5] + red[6] + red[7]) / (float)D_DIM - mu * mu;
  float rstd = 1.0f / sqrtf(var + 1e-5f);
  __syncthreads();

  float mn = 0.f, mx = 0.f;
  float4 n0, n1;
  {
    float4 gg = g4[tid], bb = b4[tid];
    n0.x = (v0.x - mu) * rstd * gg.x + bb.x; n0.y = (v0.y - mu) * rstd * gg.y + bb.y;
    n0.z = (v0.z - mu) * rstd * gg.z + bb.z; n0.w = (v0.w - mu) * rstd * gg.w + bb.w;
    gg = g4[tid + 256]; bb = b4[tid + 256];
    n1.x = (v1.x - mu) * rstd * gg.x + bb.x; n1.y = (v1.y - mu) * rstd * gg.y + bb.y;
    n1.z = (v1.z - mu) * rstd * gg.z + bb.z; n1.w = (v1.w - mu) * rstd * gg.w + bb.w;
    mn = fminf(mn, fminf(fminf(n0.x, n0.y), fminf(n0.z, n0.w)));
    mn = fminf(mn, fminf(fminf(n1.x, n1.y), fminf(n1.z, n1.w)));
    mx = fmaxf(mx, fmaxf(fmaxf(n0.x, n0.y), fmaxf(n0.z, n0.w)));
    mx = fmaxf(mx, fmaxf(fmaxf(n1.x, n1.y), fmaxf(n1.z, n1.w)));
  }
  mn = wred_min(mn); mx = wred_max(mx);
  if ((tid & 63) == 0) { red[tid >> 6] = mn; red[4 + (tid >> 6)] = mx; }
  __syncthreads();
  mn = fminf(fminf(red[0], red[1]), fminf(red[2], red[3]));
  mx = fmaxf(fmaxf(red[4], red[5]), fmaxf(red[6], red[7]));
  float scale = fmaxf((mx - mn) / QMAX, 1e-5f);
  float zp = rintf(-mn / scale);
  if (tid == 0) srow[row] = scale;
  ushort4 o0, o1;
  o0.x = f32i_to_bf16(fminf(fmaxf(rintf(n0.x / scale) + zp, 0.f), QMAX) - zp);
  o0.y = f32i_to_bf16(fminf(fmaxf(rintf(n0.y / scale) + zp, 0.f), QMAX) - zp);
  o0.z = f32i_to_bf16(fminf(fmaxf(rintf(n0.z / scale) + zp, 0.f), QMAX) - zp);
  o0.w = f32i_to_bf16(fminf(fmaxf(rintf(n0.w / scale) + zp, 0.f), QMAX) - zp);
  o1.x = f32i_to_bf16(fminf(fmaxf(rintf(n1.x / scale) + zp, 0.f), QMAX) - zp);
  o1.y = f32i_to_bf16(fminf(fmaxf(rintf(n1.y / scale) + zp, 0.f), QMAX) - zp);
  o1.z = f32i_to_bf16(fminf(fmaxf(rintf(n1.z / scale) + zp, 0.f), QMAX) - zp);
  o1.w = f32i_to_bf16(fminf(fmaxf(rintf(n1.w / scale) + zp, 0.f), QMAX) - zp);
  *(ushort4*)&out[(size_t)row * D_DIM + tid * 4] = o0;
  *(ushort4*)&out[(size_t)row * D_DIM + 1024 + tid * 4] = o1;
}

// ---- fp32 row -> quant -> bf16 int + scale (for attention ctx) ----
__global__ __launch_bounds__(256) void act_quant_bf16(const float* __restrict__ x,
                                                      u16* __restrict__ out,
                                                      float* __restrict__ srow,
                                                      int N) {
  __shared__ float red[8];
  const int row = blockIdx.x, tid = threadIdx.x;
  const float4* xr = (const float4*)(x + (size_t)row * N);
  const int N4 = N >> 2;
  float mn = 0.f, mx = 0.f;
  for (int i = tid; i < N4; i += 256) {
    float4 v = xr[i];
    mn = fminf(mn, fminf(fminf(v.x, v.y), fminf(v.z, v.w)));
    mx = fmaxf(mx, fmaxf(fmaxf(v.x, v.y), fmaxf(v.z, v.w)));
  }
  mn = wred_min(mn); mx = wred_max(mx);
  if ((tid & 63) == 0) { red[tid >> 6] = mn; red[4 + (tid >> 6)] = mx; }
  __syncthreads();
  mn = fminf(fminf(red[0], red[1]), fminf(red[2], red[3]));
  mx = fmaxf(fmaxf(red[4], red[5]), fmaxf(red[6], red[7]));
  float scale = fmaxf((mx - mn) / QMAX, 1e-5f);
  float zp = rintf(-mn / scale);
  if (tid == 0) srow[row] = scale;
  for (int i = tid; i < N4; i += 256) {
    float4 v = xr[i];
    ushort4 o;
    o.x = f32i_to_bf16(fminf(fmaxf(rintf(v.x / scale) + zp, 0.f), QMAX) - zp);
    o.y = f32i_to_bf16(fminf(fmaxf(rintf(v.y / scale) + zp, 0.f), QMAX) - zp);
    o.z = f32i_to_bf16(fminf(fmaxf(rintf(v.z / scale) + zp, 0.f), QMAX) - zp);
    o.w = f32i_to_bf16(fminf(fmaxf(rintf(v.w / scale) + zp, 0.f), QMAX) - zp);
    *(ushort4*)&out[(size_t)row * N + i * 4] = o;
  }
}

// ---- weight row quant -> bf16 int + per-row scale ----
__global__ __launch_bounds__(256) void wquant(const float* __restrict__ W,
                                              u16* __restrict__ Wi,
                                              float* __restrict__ sc, int K) {
  __shared__ float red[8];
  const int row = blockIdx.x, tid = threadIdx.x;
  const float4* wr = (const float4*)(W + (size_t)row * K);
  const int K4 = K >> 2;
  float mn = 0.f, mx = 0.f;
  for (int i = tid; i < K4; i += 256) {
    float4 v = wr[i];
    mn = fminf(mn, fminf(fminf(v.x, v.y), fminf(v.z, v.w)));
    mx = fmaxf(mx, fmaxf(fmaxf(v.x, v.y), fmaxf(v.z, v.w)));
  }
  mn = wred_min(mn); mx = wred_max(mx);
  if ((tid & 63) == 0) { red[tid >> 6] = mn; red[4 + (tid >> 6)] = mx; }
  __syncthreads();
  mn = fminf(fminf(red[0], red[1]), fminf(red[2], red[3]));
  mx = fmaxf(fmaxf(red[4], red[5]), fmaxf(red[6], red[7]));
  float scale = fmaxf((mx - mn) / QMAX, 1e-5f);
  float zp = rintf(-mn / scale);
  if (tid == 0) sc[row] = scale;
  for (int i = tid; i < K4; i += 256) {
    float4 v = wr[i];
    ushort4 o;
    o.x = f32i_to_bf16(fminf(fmaxf(rintf(v.x / scale) + zp, 0.f), QMAX) - zp);
    o.y = f32i_to_bf16(fminf(fmaxf(rintf(v.y / scale) + zp, 0.f), QMAX) - zp);
    o.z = f32i_to_bf16(fminf(fmaxf(rintf(v.z / scale) + zp, 0.f), QMAX) - zp);
    o.w = f32i_to_bf16(fminf(fmaxf(rintf(v.w / scale) + zp, 0.f), QMAX) - zp);
    *(ushort4*)&Wi[(size_t)row * K + i * 4] = o;
  }
}

// ---- requant: bf16 values + per-tile min/max -> bf16 ints (or fake-quant values) ----
// tmn==nullptr means xmin = 0 (relu rows). value_mode: out = (q-zp)*scale bf16.
__global__ __launch_bounds__(256) void requant(const u16* __restrict__ vals,
                                               const float* __restrict__ tmn,
                                               const float* __restrict__ tmx,
                                               int NT, u16* __restrict__ out,
                                               float* __restrict__ srow,
                                               int N, int value_mode) {
  __shared__ float red[8];
  const int row = blockIdx.x, tid = threadIdx.x;
  float mn = 0.f, mx = 0.f;
  if (tid < NT) {
    mn = tmn ? tmn[(size_t)row * NT + tid] : 0.f;
    mx = tmx[(size_t)row * NT + tid];
  }
  mn = wred_min(mn); mx = wred_max(mx);
  if ((tid & 63) == 0) { red[tid >> 6] = mn; red[4 + (tid >> 6)] = mx; }
  __syncthreads();
  mn = fminf(fminf(red[0], red[1]), fminf(red[2], red[3]));
  mx = fmaxf(fmaxf(red[4], red[5]), fmaxf(red[6], red[7]));
  mn = fminf(mn, 0.f); mx = fmaxf(mx, 0.f);
  float scale = fmaxf((mx - mn) / QMAX, 1e-5f);
  float zp = rintf(-mn / scale);
  if (srow && tid == 0) srow[row] = scale;
  const ushort4* vr = (const ushort4*)(vals + (size_t)row * N);
  ushort4* orow = (ushort4*)(out + (size_t)row * N);
  const int N4 = N >> 2;
  for (int i = tid; i < N4; i += 256) {
    ushort4 u = vr[i];
    float q0 = fminf(fmaxf(rintf(bf16_to_f32(u.x) / scale) + zp, 0.f), QMAX) - zp;
    float q1 = fminf(fmaxf(rintf(bf16_to_f32(u.y) / scale) + zp, 0.f), QMAX) - zp;
    float q2 = fminf(fmaxf(rintf(bf16_to_f32(u.z) / scale) + zp, 0.f), QMAX) - zp;
    float q3 = fminf(fmaxf(rintf(bf16_to_f32(u.w) / scale) + zp, 0.f), QMAX) - zp;
    ushort4 o;
    if (value_mode) {
      o.x = f32_to_bf16_rne(q0 * scale); o.y = f32_to_bf16_rne(q1 * scale);
      o.z = f32_to_bf16_rne(q2 * scale); o.w = f32_to_bf16_rne(q3 * scale);
    } else {
      o.x = f32i_to_bf16(q0); o.y = f32i_to_bf16(q1);
      o.z = f32i_to_bf16(q2); o.w = f32i_to_bf16(q3);
    }
    orow[i] = o;
  }
}

// ---- double-buffered 128x128x32 MFMA accumulation body ----
__device__ __forceinline__ void gemm128_acc_db(
    const u16* __restrict__ A, const u16* __restrict__ B,
    int K, int bm, int bn, int k_begin, int k_end,
    u16* As0, u16* Bs0, u16* As1, u16* Bs1, f32x4 (&acc)[4][4]) {
  const int tid = threadIdx.x;
  const int wid = tid >> 6, lane = tid & 63;
  const int wr = wid >> 1, wc = wid & 1;
  const int lr = lane & 15, lk = lane >> 4;
  const int r0 = tid >> 2, c0 = (tid & 3) * 8;
  const int r1 = 64 + (tid >> 2);
  const size_t ldsb0 = (size_t)(wid * 64) * 8;
  const size_t ldsb1 = (size_t)(256 + wid * 64) * 8;

  const u16* Ag0 = A + (size_t)(bm + r0) * K + c0;
  const u16* Ag1 = A + (size_t)(bm + r1) * K + c0;
  const u16* Bg0 = B + (size_t)(bn + r0) * K + c0;
  const u16* Bg1 = B + (size_t)(bn + r1) * K + c0;

  // prologue: stage first K-tile into buffer 0
  gload_lds16(Ag0 + k_begin, As0 + ldsb0);
  gload_lds16(Ag1 + k_begin, As0 + ldsb1);
  gload_lds16(Bg0 + k_begin, Bs0 + ldsb0);
  gload_lds16(Bg1 + k_begin, Bs0 + ldsb1);
  __syncthreads();  // vmcnt drained -> buf0 ready

  int cur = 0;
  for (int k0 = k_begin; k0 < k_end; k0 += 32) {
    const u16* Ac = cur ? As1 : As0;
    const u16* Bc = cur ? Bs1 : Bs0;
    bf16x8 af[4], bf[4];
#pragma unroll
    for (int mi = 0; mi < 4; ++mi)
      af[mi] = *(const bf16x8*)&Ac[(size_t)(wr * 64 + mi * 16 + lr) * 32 + lk * 8];
#pragma unroll
    for (int ni = 0; ni < 4; ++ni)
      bf[ni] = *(const bf16x8*)&Bc[(size_t)(wc * 64 + ni * 16 + lr) * 32 + lk * 8];
    // issue next tile into the other buffer; flies under the MFMAs
    if (k0 + 32 < k_end) {
      u16* An = cur ? As0 : As1;
      u16* Bn = cur ? Bs0 : Bs1;
      gload_lds16(Ag0 + k0 + 32, An + ldsb0);
      gload_lds16(Ag1 + k0 + 32, An + ldsb1);
      gload_lds16(Bg0 + k0 + 32, Bn + ldsb0);
      gload_lds16(Bg1 + k0 + 32, Bn + ldsb1);
    }
#pragma unroll
    for (int mi = 0; mi < 4; ++mi)
#pragma unroll
      for (int ni = 0; ni < 4; ++ni)
        acc[mi][ni] = __builtin_amdgcn_mfma_f32_16x16x32_bf16(af[mi], bf[ni], acc[mi][ni], 0, 0, 0);
    __syncthreads();  // drains next-tile loads + all reads of current buffer
    cur ^= 1;
  }
}

// ---- fused QKV: C = (acc*sa*sb + bias) [*0.125 for q] -> bf16 values + tile min/max ----
__global__ __launch_bounds__(256) void gemm_qkv128(
    const u16* __restrict__ A, const float* __restrict__ sa,
    const u16* __restrict__ Bq, const float* __restrict__ sbq, const float* __restrict__ biasq,
    u16* __restrict__ Cq, float* __restrict__ tqmn, float* __restrict__ tqmx,
    const u16* __restrict__ Bk, const float* __restrict__ sbk, const float* __restrict__ biask,
    u16* __restrict__ Ck, float* __restrict__ tkmn, float* __restrict__ tkmx,
    const u16* __restrict__ Bv, const float* __restrict__ sbv, const float* __restrict__ biasv,
    u16* __restrict__ Cv, float* __restrict__ tvmn, float* __restrict__ tvmx) {
  __shared__ __align__(16) u16 As0[128 * 32], Bs0[128 * 32];
  __shared__ __align__(16) u16 As1[128 * 32], Bs1[128 * 32];
  int bx, by; xcd_swz(bx, by);
  const int which = bx >> 4;          // 16 col-tiles per weight
  const int bn = (bx & 15) * 128;
  const int bm = by * 128;
  const u16* B = (which == 0) ? Bq : (which == 1) ? Bk : Bv;
  const float* sb = (which == 0) ? sbq : (which == 1) ? sbk : sbv;
  const float* bias = (which == 0) ? biasq : (which == 1) ? biask : biasv;
  u16* C = (which == 0) ? Cq : (which == 1) ? Ck : Cv;
  float* tmn = (which == 0) ? tqmn : (which == 1) ? tkmn : tvmn;
  float* tmx = (which == 0) ? tqmx : (which == 1) ? tkmx : tvmx;
  const float alpha = (which == 0) ? 0.125f : 1.0f;

  f32x4 acc[4][4] = {};
  gemm128_acc_db(A, B, D_DIM, bm, bn, 0, D_DIM, As0, Bs0, As1, Bs1, acc);

  const int tid = threadIdx.x;
  const int wid = tid >> 6, lane = tid & 63;
  const int wr = wid >> 1, wc = wid & 1;
  const int lr = lane & 15, lk = lane >> 4;
  const int col0 = bn + wc * 64 + lr;
  const int rbase = bm + wr * 64 + lk * 4;
  const int tci = (bn >> 6) + wc;     // 64-col tile index, NT = 32
  float sbc[4], bc[4];
#pragma unroll
  for (int ni = 0; ni < 4; ++ni) { sbc[ni] = sb[col0 + ni * 16]; bc[ni] = bias[col0 + ni * 16]; }
#pragma unroll
  for (int mi = 0; mi < 4; ++mi) {
#pragma unroll
    for (int r = 0; r < 4; ++r) {
      const int row = rbase + mi * 16 + r;
      const float sar = sa[row];
      float v[4];
#pragma unroll
      for (int ni = 0; ni < 4; ++ni)
        v[ni] = (acc[mi][ni][r] * sar * sbc[ni] + bc[ni]) * alpha;
#pragma unroll
      for (int ni = 0; ni < 4; ++ni)
        C[(size_t)row * D_DIM + col0 + ni * 16] = f32_to_bf16_rne(v[ni]);
      float mnv = fminf(fminf(v[0], v[1]), fminf(v[2], v[3]));
      float mxv = fmaxf(fmaxf(v[0], v[1]), fmaxf(v[2], v[3]));
      mnv = fminf(mnv, __shfl_xor(mnv, 1, 64)); mxv = fmaxf(mxv, __shfl_xor(mxv, 1, 64));
      mnv = fminf(mnv, __shfl_xor(mnv, 2, 64)); mxv = fmaxf(mxv, __shfl_xor(mxv, 2, 64));
      mnv = fminf(mnv, __shfl_xor(mnv, 4, 64)); mxv = fmaxf(mxv, __shfl_xor(mxv, 4, 64));
      mnv = fminf(mnv, __shfl_xor(mnv, 8, 64)); mxv = fmaxf(mxv, __shfl_xor(mxv, 8, 64));
      if (lr == 0) {
        tmn[(size_t)row * 32 + tci] = mnv;
        tmx[(size_t)row * 32 + tci] = mxv;
      }
    }
  }
}

// ---- W1: C = relu(acc*sa*sb + bias) -> bf16 values + tile row-max ----
__global__ __launch_bounds__(256) void gemm_w1(
    const u16* __restrict__ A, const float* __restrict__ sa,
    const u16* __restrict__ B, const float* __restrict__ sb,
    const float* __restrict__ bias,
    u16* __restrict__ C, float* __restrict__ tmx) {
  __shared__ __align__(16) u16 As0[128 * 32], Bs0[128 * 32];
  __shared__ __align__(16) u16 As1[128 * 32], Bs1[128 * 32];
  int bx, by; xcd_swz(bx, by);
  const int bn = bx * 128, bm = by * 128;

  f32x4 acc[4][4] = {};
  gemm128_acc_db(A, B, D_DIM, bm, bn, 0, D_DIM, As0, Bs0, As1, Bs1, acc);

  const int tid = threadIdx.x;
  const int wid = tid >> 6, lane = tid & 63;
  const int wr = wid >> 1, wc = wid & 1;
  const int lr = lane & 15, lk = lane >> 4;
  const int col0 = bn + wc * 64 + lr;
  const int rbase = bm + wr * 64 + lk * 4;
  const int tci = (bn >> 6) + wc;     // NT = 128
  float sbc[4], bc[4];
#pragma unroll
  for (int ni = 0; ni < 4; ++ni) { sbc[ni] = sb[col0 + ni * 16]; bc[ni] = bias[col0 + ni * 16]; }
#pragma unroll
  for (int mi = 0; mi < 4; ++mi) {
#pragma unroll
    for (int r = 0; r < 4; ++r) {
      const int row = rbase + mi * 16 + r;
      const float sar = sa[row];
      float v[4];
#pragma unroll
      for (int ni = 0; ni < 4; ++ni)
        v[ni] = fmaxf(acc[mi][ni][r] * sar * sbc[ni] + bc[ni], 0.f);
#pragma unroll
      for (int ni = 0; ni < 4; ++ni)
        C[(size_t)row * FF_DIM + col0 + ni * 16] = f32_to_bf16_rne(v[ni]);
      float mxv = fmaxf(fmaxf(v[0], v[1]), fmaxf(v[2], v[3]));
      mxv = fmaxf(mxv, __shfl_xor(mxv, 1, 64));
      mxv = fmaxf(mxv, __shfl_xor(mxv, 2, 64));
      mxv = fmaxf(mxv, __shfl_xor(mxv, 4, 64));
      mxv = fmaxf(mxv, __shfl_xor(mxv, 8, 64));
      if (lr == 0) tmx[(size_t)row * 128 + tci] = mxv;
    }
  }
}

// ---- split-K partial GEMM: part[z] = sa*sb*(A@B^T) over K-chunk z ----
__global__ __launch_bounds__(256) void gemm_splitk(
    const u16* __restrict__ A, const float* __restrict__ sa,
    const u16* __restrict__ B, const float* __restrict__ sb,
    float* __restrict__ part, int N, int K, int kchunk) {
  __shared__ __align__(16) u16 As0[128 * 32], Bs0[128 * 32];
  __shared__ __align__(16) u16 As1[128 * 32], Bs1[128 * 32];
  int bx, by; xcd_swz(bx, by);
  const int bm = by * 128, bn = bx * 128;
  const int ks = blockIdx.z;
  f32x4 acc[4][4] = {};
  gemm128_acc_db(A, B, K, bm, bn, ks * kchunk, (ks + 1) * kchunk, As0, Bs0, As1, Bs1, acc);

  float* dst = part + (size_t)ks * S_LEN * N;
  const int tid = threadIdx.x;
  const int wid = tid >> 6, lane = tid & 63;
  const int wr = wid >> 1, wc = wid & 1;
  const int lr = lane & 15, lk = lane >> 4;
  const int col0 = bn + wc * 64 + lr;
  const int rbase = bm + wr * 64 + lk * 4;
#pragma unroll
  for (int ni = 0; ni < 4; ++ni) {
    const int col = col0 + ni * 16;
    const float sbc = sb[col];
#pragma unroll
    for (int mi = 0; mi < 4; ++mi)
#pragma unroll
      for (int r = 0; r < 4; ++r) {
        const int row = rbase + mi * 16 + r;
        dst[(size_t)row * N + col] = acc[mi][ni][r] * sa[row] * sbc;
      }
  }
}

// ---- split-K reduce: out = sum(part) + bias (+res) ----
__global__ __launch_bounds__(256) void splitk_reduce(
    const float* __restrict__ part, int nsplit,
    const float* __restrict__ bias, const float* __restrict__ res,
    float* __restrict__ out, int N) {
  const size_t stride4 = (size_t)S_LEN * N / 4;
  const int n4 = N >> 2;
  for (size_t i = (size_t)blockIdx.x * 256 + threadIdx.x; i < stride4;
       i += (size_t)gridDim.x * 256) {
    float4 s = ((const float4*)part)[i];
    for (int k = 1; k < nsplit; ++k) {
      float4 p = ((const float4*)part)[i + (size_t)k * stride4];
      s.x += p.x; s.y += p.y; s.z += p.z; s.w += p.w;
    }
    float4 b4 = ((const float4*)bias)[i % n4];
    s.x += b4.x; s.y += b4.y; s.z += b4.z; s.w += b4.w;
    if (res) {
      float4 r = ((const float4*)res)[i];
      s.x += r.x; s.y += r.y; s.z += r.z; s.w += r.w;
    }
    ((float4*)out)[i] = s;
  }
}

// ---- fused causal attention with quantized probs, MFMA both passes ----
__global__ __launch_bounds__(256) void attn_fused(
    const u16* __restrict__ qi, const float* __restrict__ sq,
    const u16* __restrict__ ki, const float* __restrict__ sk,
    const u16* __restrict__ vf, float* __restrict__ ctx) {
  __shared__ __align__(16) u16 Qs[64][72];
  __shared__ __align__(16) u16 Ks[64][72];
  __shared__ __align__(16) u16 Ps[64][72];
  __shared__ __align__(16) u16 Vt[64][72];
  const int bid = blockIdx.x;
  const int ti = (S_LEN / 64 - 1) - (bid >> 5);  // heavy tiles first
  const int h = bid & (H_NUM - 1);
  const int i0 = ti * 64;
  const int tid = threadIdx.x;
  const int wid = tid >> 6, lane = tid & 63;
  const int lr = lane & 15, g = lane >> 4;
  const size_t hbase = (size_t)h * HD_DIM;

  const int r_a = tid >> 3, ch_a = tid & 7;  // K staging: rows 0..31 / 32..63
  const int r_b = 32 + r_a;
  const int jr_v = tid & 63, ch_v = tid >> 6; // V staging: ch_v and 4+ch_v

  for (int c = tid; c < 512; c += 256) {
    int r = c >> 3, ch = c & 7;
    *(float4*)&Qs[r][ch * 8] =
        *(const float4*)&qi[(size_t)(i0 + r) * D_DIM + hbase + ch * 8];
  }
  float sq4[4];
#pragma unroll
  for (int r = 0; r < 4; ++r) sq4[r] = sq[i0 + wid * 16 + g * 4 + r];
  __syncthreads();

  const int ntiles = i0 / 64 + 1;
  float m_r[4] = {-1e30f, -1e30f, -1e30f, -1e30f};
  float l_r[4] = {0.f, 0.f, 0.f, 0.f};

  // ---------- pass A: running max + denom (K prefetched into regs) ----------
  float4 ka0 = *(const float4*)&ki[(size_t)r_a * D_DIM + hbase + ch_a * 8];
  float4 ka1 = *(const float4*)&ki[(size_t)r_b * D_DIM + hbase + ch_a * 8];
  for (int t = 0; t < ntiles; ++t) {
    __syncthreads();  // all reads of Ks done
    *(float4*)&Ks[r_a][ch_a * 8] = ka0;
    *(float4*)&Ks[r_b][ch_a * 8] = ka1;
    __syncthreads();  // Ks ready
    if (t + 1 < ntiles) {
      const int jn = (t + 1) * 64;
      ka0 = *(const float4*)&ki[(size_t)(jn + r_a) * D_DIM + hbase + ch_a * 8];
      ka1 = *(const float4*)&ki[(size_t)(jn + r_b) * D_DIM + hbase + ch_a * 8];
    }

    bf16x8 aq0 = *(const bf16x8*)&Qs[wid * 16 + lr][g * 8];
    bf16x8 aq1 = *(const bf16x8*)&Qs[wid * 16 + lr][32 + g * 8];
    f32x4 accs[4] = {};
#pragma unroll
    for (int ni = 0; ni < 4; ++ni) {
      bf16x8 b0 = *(const bf16x8*)&Ks[ni * 16 + lr][g * 8];
      bf16x8 b1 = *(const bf16x8*)&Ks[ni * 16 + lr][32 + g * 8];
      accs[ni] = __builtin_amdgcn_mfma_f32_16x16x32_bf16(aq0, b0, accs[ni], 0, 0, 0);
      accs[ni] = __builtin_amdgcn_mfma_f32_16x16x32_bf16(aq1, b1, accs[ni], 0, 0, 0);
    }

    const int jt = t * 64;
    float sv[4][4];
#pragma unroll
    for (int ni = 0; ni < 4; ++ni) {
      const float skc = sk[jt + ni * 16 + lr];
#pragma unroll
      for (int r = 0; r < 4; ++r) sv[ni][r] = accs[ni][r] * sq4[r] * skc;
    }
    if (t == ntiles - 1) {
      const int jcol = jt + lr, irow = i0 + wid * 16 + g * 4;
#pragma unroll
      for (int ni = 0; ni < 4; ++ni)
#pragma unroll
        for (int r = 0; r < 4; ++r)
          if (jcol + ni * 16 > irow + r) sv[ni][r] = -1e30f;
    }
#pragma unroll
    for (int r = 0; r < 4; ++r) {
      float tmax = fmaxf(fmaxf(sv[0][r], sv[1][r]), fmaxf(sv[2][r], sv[3][r]));
      tmax = fmaxf(tmax, __shfl_xor(tmax, 1, 64));
      tmax = fmaxf(tmax, __shfl_xor(tmax, 2, 64));
      tmax = fmaxf(tmax, __shfl_xor(tmax, 4, 64));
      tmax = fmaxf(tmax, __shfl_xor(tmax, 8, 64));
      float mnew = fmaxf(m_r[r], tmax);
      float sum = __expf(sv[0][r] - mnew) + __expf(sv[1][r] - mnew) +
                  __expf(sv[2][r] - mnew) + __expf(sv[3][r] - mnew);
      sum += __shfl_xor(sum, 1, 64);
      sum += __shfl_xor(sum, 2, 64);
      sum += __shfl_xor(sum, 4, 64);
      sum += __shfl_xor(sum, 8, 64);
      l_r[r] = l_r[r] * __expf(m_r[r] - mnew) + sum;
      m_r[r] = mnew;
    }
  }

  float qsc[4], idn[4];
#pragma unroll
  for (int r = 0; r < 4; ++r) {
    float sc = fmaxf((1.0f / l_r[r]) / QMAX, 1e-5f);
    qsc[r] = sc;
    idn[r] = 1.0f / (l_r[r] * sc);
  }

  // ---------- pass B: quantized probs @ V (K and V prefetched) ----------
  f32x4 acco[4] = {};
  float4 kb0 = *(const float4*)&ki[(size_t)r_a * D_DIM + hbase + ch_a * 8];
  float4 kb1 = *(const float4*)&ki[(size_t)r_b * D_DIM + hbase + ch_a * 8];
  float4 vb0 = *(const float4*)&vf[(size_t)jr_v * D_DIM + hbase + ch_v * 8];
  float4 vb1 = *(const float4*)&vf[(size_t)jr_v * D_DIM + hbase + (4 + ch_v) * 8];
  for (int t = 0; t < ntiles; ++t) {
    __syncthreads();
    *(float4*)&Ks[r_a][ch_a * 8] = kb0;
    *(float4*)&Ks[r_b][ch_a * 8] = kb1;
    {
      const u16* v0 = (const u16*)&vb0;
      const u16* v1 = (const u16*)&vb1;
#pragma unroll
      for (int e = 0; e < 8; ++e) Vt[ch_v * 8 + e][jr_v] = v0[e];
#pragma unroll
      for (int e = 0; e < 8; ++e) Vt[(4 + ch_v) * 8 + e][jr_v] = v1[e];
    }
    __syncthreads();
    if (t + 1 < ntiles) {
      const int jn = (t + 1) * 64;
      kb0 = *(const float4*)&ki[(size_t)(jn + r_a) * D_DIM + hbase + ch_a * 8];
      kb1 = *(const float4*)&ki[(size_t)(jn + r_b) * D_DIM + hbase + ch_a * 8];
      vb0 = *(const float4*)&vf[(size_t)(jn + jr_v) * D_DIM + hbase + ch_v * 8];
      vb1 = *(const float4*)&vf[(size_t)(jn + jr_v) * D_DIM + hbase + (4 + ch_v) * 8];
    }

    bf16x8 aq0 = *(const bf16x8*)&Qs[wid * 16 + lr][g * 8];
    bf16x8 aq1 = *(const bf16x8*)&Qs[wid * 16 + lr][32 + g * 8];
    f32x4 accs[4] = {};
#pragma unroll
    for (int ni = 0; ni < 4; ++ni) {
      bf16x8 b0 = *(const bf16x8*)&Ks[ni * 16 + lr][g * 8];
      bf16x8 b1 = *(const bf16x8*)&Ks[ni * 16 + lr][32 + g * 8];
      accs[ni] = __builtin_amdgcn_mfma_f32_16x16x32_bf16(aq0, b0, accs[ni], 0, 0, 0);
      accs[ni] = __builtin_amdgcn_mfma_f32_16x16x32_bf16(aq1, b1, accs[ni], 0, 0, 0);
    }

    const int jt = t * 64;
    const bool diag = (t == ntiles - 1);
    const int jcol = jt + lr, irow = i0 + wid * 16 + g * 4;
#pragma unroll
    for (int ni = 0; ni < 4; ++ni) {
      const float skc = sk[jt + ni * 16 + lr];
#pragma unroll
      for (int r = 0; r < 4; ++r) {
        float s = accs[ni][r] * sq4[r] * skc;
        if (diag && (jcol + ni * 16 > irow + r)) s = -1e30f;
        float e = __expf(s - m_r[r]);
        float q8 = fminf(fmaxf(rintf(e * idn[r]), 0.f), QMAX);
        Ps[wid * 16 + g * 4 + r][ni * 16 + lr] = f32i_to_bf16(q8);
      }
    }
    // Ps rows for this wave are wave-local: no barrier needed

    bf16x8 ap0 = *(const bf16x8*)&Ps[wid * 16 + lr][g * 8];
    bf16x8 ap1 = *(const bf16x8*)&Ps[wid * 16 + lr][32 + g * 8];
#pragma unroll
    for (int ni = 0; ni < 4; ++ni) {
      bf16x8 b0 = *(const bf16x8*)&Vt[ni * 16 + lr][g * 8];
      bf16x8 b1 = *(const bf16x8*)&Vt[ni * 16 + lr][32 + g * 8];
      acco[ni] = __builtin_amdgcn_mfma_f32_16x16x32_bf16(ap0, b0, acco[ni], 0, 0, 0);
      acco[ni] = __builtin_amdgcn_mfma_f32_16x16x32_bf16(ap1, b1, acco[ni], 0, 0, 0);
    }
  }

#pragma unroll
  for (int ni = 0; ni < 4; ++ni)
#pragma unroll
    for (int r = 0; r < 4; ++r) {
      const int row = i0 + wid * 16 + g * 4 + r;
      ctx[(size_t)row * D_DIM + hbase + ni * 16 + lr] = acco[ni][r] * qsc[r];
    }
}

extern "C" void kernel_launch(void* const* d_in, const int* in_sizes, int n_in,
                              void* d_out, int out_size, void* d_ws, size_t ws_size,
                              hipStream_t stream) {
  (void)in_sizes; (void)n_in; (void)out_size;
  const float* hs  = (const float*)d_in[0];
  const float* Wq  = (const float*)d_in[2];
  const float* bq  = (const float*)d_in[3];
  const float* Wk  = (const float*)d_in[4];
  const float* bk  = (const float*)d_in[5];
  const float* Wv  = (const float*)d_in[6];
  const float* bv  = (const float*)d_in[7];
  const float* Wo  = (const float*)d_in[8];
  const float* bo  = (const float*)d_in[9];
  const float* g1  = (const float*)d_in[10];
  const float* be1 = (const float*)d_in[11];
  const float* W1  = (const float*)d_in[12];
  const float* bf1 = (const float*)d_in[13];
  const float* W2  = (const float*)d_in[14];
  const float* bf2 = (const float*)d_in[15];
  const float* g2  = (const float*)d_in[16];
  const float* be2 = (const float*)d_in[17];
  float* out = (float*)d_out;

  const size_t SD = (size_t)S_LEN * D_DIM;
  const size_t SF = (size_t)S_LEN * FF_DIM;

  char* p = (char*)d_ws;
  auto alloc = [&](size_t bytes) { char* r = p; p += (bytes + 255) & ~(size_t)255; return r; };

  float* h2   = (float*)alloc(SD * 4);
  float* sx   = (float*)alloc(S_LEN * 4);
  float* sxf  = (float*)alloc(S_LEN * 4);
  float* sqv  = (float*)alloc(S_LEN * 4);
  float* skv  = (float*)alloc(S_LEN * 4);
  float* swq  = (float*)alloc(D_DIM * 4);
  float* swk  = (float*)alloc(D_DIM * 4);
  float* swv  = (float*)alloc(D_DIM * 4);
  float* swo  = (float*)alloc(D_DIM * 4);
  float* sw1  = (float*)alloc(FF_DIM * 4);
  float* sw2  = (float*)alloc(D_DIM * 4);
  float* tqmn = (float*)alloc(S_LEN * 32 * 4);
  float* tqmx = (float*)alloc(S_LEN * 32 * 4);
  float* tkmn = (float*)alloc(S_LEN * 32 * 4);
  float* tkmx = (float*)alloc(S_LEN * 32 * 4);
  float* tvmn = (float*)alloc(S_LEN * 32 * 4);
  float* tvmx = (float*)alloc(S_LEN * 32 * 4);
  float* tf1x = (float*)alloc(S_LEN * 128 * 4);
  u16* xi  = (u16*)alloc(SD * 2);
  u16* wqi = (u16*)alloc(SD * 2);
  u16* wki = (u16*)alloc(SD * 2);
  u16* wvi = (u16*)alloc(SD * 2);
  u16* woi = (u16*)alloc(SD * 2);
  u16* w1i = (u16*)alloc(SF * 2);
  u16* w2i = (u16*)alloc(SF * 2);
  char* arena = alloc(8 * SD * 2);   // 8 SD-u16 units, phase-aliased
  // phase QKV/attn:
  u16* qv   = (u16*)arena;           // units 0-1
  u16* kv   = qv + SD;               // 1-2
  u16* vv   = kv + SD;               // 2-3
  u16* qi8  = vv + SD;               // 3-4
  u16* ki8  = qi8 + SD;              // 4-5
  u16* vfb  = ki8 + SD;              // 5-6
  float* ctxb = (float*)(vfb + SD);  // 6-8 (fp32 SD)
  // phase Wo:
  float* pwo = (float*)arena;        // 0-4 (2*SD fp32)
  // phase FFN:
  u16* f1v = (u16*)arena;            // 0-4 (SF u16)
  u16* f1i = (u16*)(arena + 4 * SD * 2); // 4-8 (SF u16)
  float* pw2 = (float*)arena;        // 0-4 (2*SD fp32), f1v dead by then
  size_t need = (size_t)(p - (char*)d_ws);
  if (ws_size < need) return;  // fail loudly rather than corrupt

  dim3 blk(256);

  wquant<<<D_DIM, blk, 0, stream>>>(Wq, wqi, swq, D_DIM);
  wquant<<<D_DIM, blk, 0, stream>>>(Wk, wki, swk, D_DIM);
  wquant<<<D_DIM, blk, 0, stream>>>(Wv, wvi, swv, D_DIM);
  wquant<<<D_DIM, blk, 0, stream>>>(Wo, woi, swo, D_DIM);
  wquant<<<FF_DIM, blk, 0, stream>>>(W1, w1i, sw1, D_DIM);
  wquant<<<D_DIM, blk, 0, stream>>>(W2, w2i, sw2, FF_DIM);

  ln_quant_bf16<<<S_LEN, blk, 0, stream>>>(hs, g1, be1, xi, sx);

  dim3 gqkv(3 * D_DIM / 128, S_LEN / 128);   // 48 x 16 = 768 blocks
  gemm_qkv128<<<gqkv, blk, 0, stream>>>(xi, sx,
                                        wqi, swq, bq, qv, tqmn, tqmx,
                                        wki, swk, bk, kv, tkmn, tkmx,
                                        wvi, swv, bv, vv, tvmn, tvmx);

  requant<<<S_LEN, blk, 0, stream>>>(qv, tqmn, tqmx, 32, qi8, sqv, D_DIM, 0);
  requant<<<S_LEN, blk, 0, stream>>>(kv, tkmn, tkmx, 32, ki8, skv, D_DIM, 0);
  requant<<<S_LEN, blk, 0, stream>>>(vv, tvmn, tvmx, 32, vfb, nullptr, D_DIM, 1);

  attn_fused<<<(S_LEN / 64) * H_NUM, blk, 0, stream>>>(qi8, sqv, ki8, skv, vfb, ctxb);

  act_quant_bf16<<<S_LEN, blk, 0, stream>>>(ctxb, xi, sx, D_DIM);

  // Wo: split-K=2, reduce adds bias + residual(hs)
  dim3 gwo(D_DIM / 128, S_LEN / 128, 2);
  gemm_splitk<<<gwo, blk, 0, stream>>>(xi, sx, woi, swo, pwo, D_DIM, D_DIM, D_DIM / 2);
  splitk_reduce<<<2048, blk, 0, stream>>>(pwo, 2, bo, hs, h2, D_DIM);

  ln_quant_bf16<<<S_LEN, blk, 0, stream>>>(h2, g2, be2, xi, sx);

  dim3 gff(FF_DIM / 128, S_LEN / 128);       // 64 x 16 = 1024 blocks
  gemm_w1<<<gff, blk, 0, stream>>>(xi, sx, w1i, sw1, bf1, f1v, tf1x);
  requant<<<S_LEN, blk, 0, stream>>>(f1v, nullptr, tf1x, 128, f1i, sxf, FF_DIM, 0);

  // W2: split-K=2, reduce adds bias + residual(h2)
  dim3 gw2(D_DIM / 128, S_LEN / 128, 2);
  gemm_splitk<<<gw2, blk, 0, stream>>>(f1i, sxf, w2i, sw2, pw2, D_DIM, FF_DIM, FF_DIM / 2);
  splitk_reduce<<<2048, blk, 0, stream>>>(pw2, 2, bf2, h2, out, D_DIM);
}

// Round 7
// 575.349 us; speedup vs baseline: 8.3774x; 1.0593x over previous
//
#include <hip/hip_runtime.h>
#include <hip/hip_bf16.h>
#include <math.h>

#define S_LEN 2048
#define D_DIM 2048
#define H_NUM 32
#define HD_DIM 64
#define FF_DIM 8192
#define QMAX 255.0f

typedef __attribute__((ext_vector_type(4))) float f32x4;
typedef __attribute__((ext_vector_type(8))) __bf16 bf16x8;
typedef unsigned short u16;

__device__ __forceinline__ u16 f32i_to_bf16(float v) {
  // v is an exact integer in [-255,255]: fp32 low 16 bits are zero -> exact bf16
  return (u16)(__float_as_uint(v) >> 16);
}
__device__ __forceinline__ u16 f32_to_bf16_rne(float v) {
  __bf16 b = (__bf16)v;
  return *(u16*)&b;
}
__device__ __forceinline__ float bf16_to_f32(u16 u) {
  return __uint_as_float((unsigned int)u << 16);
}

__device__ __forceinline__ float wred_sum(float v) {
#pragma unroll
  for (int o = 1; o < 64; o <<= 1) v += __shfl_xor(v, o, 64);
  return v;
}
__device__ __forceinline__ float wred_min(float v) {
#pragma unroll
  for (int o = 1; o < 64; o <<= 1) v = fminf(v, __shfl_xor(v, o, 64));
  return v;
}
__device__ __forceinline__ float wred_max(float v) {
#pragma unroll
  for (int o = 1; o < 64; o <<= 1) v = fmaxf(v, __shfl_xor(v, o, 64));
  return v;
}

__device__ __forceinline__ void gload_lds16(const void* g, void* l) {
  __builtin_amdgcn_global_load_lds(
      (__attribute__((address_space(1))) void*)(g),
      (__attribute__((address_space(3))) void*)(l), 16, 0, 0);
}

// bijective XCD-aware swizzle of the 2D grid (requires (gx*gy)%8==0)
__device__ __forceinline__ void xcd_swz(int& bx, int& by) {
  const int gx = gridDim.x;
  const int nwg = gx * gridDim.y;
  const int orig = blockIdx.x + gx * blockIdx.y;
  const int swz = (orig & 7) * (nwg >> 3) + (orig >> 3);
  bx = swz % gx;
  by = swz / gx;
}

// ---- LayerNorm + per-token quant -> bf16 integer (q-zp) + row scale ----
__global__ __launch_bounds__(256) void ln_quant_bf16(const float* __restrict__ x,
                                                     const float* __restrict__ g,
                                                     const float* __restrict__ bvec,
                                                     u16* __restrict__ out,
                                                     float* __restrict__ srow) {
  __shared__ float red[8];
  const int row = blockIdx.x, tid = threadIdx.x;
  const float4* xr = (const float4*)(x + (size_t)row * D_DIM);
  const float4* g4 = (const float4*)g;
  const float4* b4 = (const float4*)bvec;

  float4 v0 = xr[tid], v1 = xr[tid + 256];
  float s = v0.x + v0.y + v0.z + v0.w + v1.x + v1.y + v1.z + v1.w;
  float ss = v0.x * v0.x + v0.y * v0.y + v0.z * v0.z + v0.w * v0.w +
             v1.x * v1.x + v1.y * v1.y + v1.z * v1.z + v1.w * v1.w;
  s = wred_sum(s); ss = wred_sum(ss);
  if ((tid & 63) == 0) { red[tid >> 6] = s; red[4 + (tid >> 6)] = ss; }
  __syncthreads();
  float mu = (red[0] + red[1] + red[2] + red[3]) / (float)D_DIM;
  float var = (red[4] + red[5] + red[6] + red[7]) / (float)D_DIM - mu * mu;
  float rstd = 1.0f / sqrtf(var + 1e-5f);
  __syncthreads();

  float mn = 0.f, mx = 0.f;
  float4 n0, n1;
  {
    float4 gg = g4[tid], bb = b4[tid];
    n0.x = (v0.x - mu) * rstd * gg.x + bb.x; n0.y = (v0.y - mu) * rstd * gg.y + bb.y;
    n0.z = (v0.z - mu) * rstd * gg.z + bb.z; n0.w = (v0.w - mu) * rstd * gg.w + bb.w;
    gg = g4[tid + 256]; bb = b4[tid + 256];
    n1.x = (v1.x - mu) * rstd * gg.x + bb.x; n1.y = (v1.y - mu) * rstd * gg.y + bb.y;
    n1.z = (v1.z - mu) * rstd * gg.z + bb.z; n1.w = (v1.w - mu) * rstd * gg.w + bb.w;
    mn = fminf(mn, fminf(fminf(n0.x, n0.y), fminf(n0.z, n0.w)));
    mn = fminf(mn, fminf(fminf(n1.x, n1.y), fminf(n1.z, n1.w)));
    mx = fmaxf(mx, fmaxf(fmaxf(n0.x, n0.y), fmaxf(n0.z, n0.w)));
    mx = fmaxf(mx, fmaxf(fmaxf(n1.x, n1.y), fmaxf(n1.z, n1.w)));
  }
  mn = wred_min(mn); mx = wred_max(mx);
  if ((tid & 63) == 0) { red[tid >> 6] = mn; red[4 + (tid >> 6)] = mx; }
  __syncthreads();
  mn = fminf(fminf(red[0], red[1]), fminf(red[2], red[3]));
  mx = fmaxf(fmaxf(red[4], red[5]), fmaxf(red[6], red[7]));
  float scale = fmaxf((mx - mn) / QMAX, 1e-5f);
  float zp = rintf(-mn / scale);
  if (tid == 0) srow[row] = scale;
  ushort4 o0, o1;
  o0.x = f32i_to_bf16(fminf(fmaxf(rintf(n0.x / scale) + zp, 0.f), QMAX) - zp);
  o0.y = f32i_to_bf16(fminf(fmaxf(rintf(n0.y / scale) + zp, 0.f), QMAX) - zp);
  o0.z = f32i_to_bf16(fminf(fmaxf(rintf(n0.z / scale) + zp, 0.f), QMAX) - zp);
  o0.w = f32i_to_bf16(fminf(fmaxf(rintf(n0.w / scale) + zp, 0.f), QMAX) - zp);
  o1.x = f32i_to_bf16(fminf(fmaxf(rintf(n1.x / scale) + zp, 0.f), QMAX) - zp);
  o1.y = f32i_to_bf16(fminf(fmaxf(rintf(n1.y / scale) + zp, 0.f), QMAX) - zp);
  o1.z = f32i_to_bf16(fminf(fmaxf(rintf(n1.z / scale) + zp, 0.f), QMAX) - zp);
  o1.w = f32i_to_bf16(fminf(fmaxf(rintf(n1.w / scale) + zp, 0.f), QMAX) - zp);
  *(ushort4*)&out[(size_t)row * D_DIM + tid * 4] = o0;
  *(ushort4*)&out[(size_t)row * D_DIM + 1024 + tid * 4] = o1;
}

// ---- fused: h2 = part0+part1+bias+res; then LN+quant of h2 -> xi, sx ----
__global__ __launch_bounds__(256) void splitk_reduce_ln(
    const float* __restrict__ part,
    const float* __restrict__ bias, const float* __restrict__ res,
    float* __restrict__ h2out,
    const float* __restrict__ g, const float* __restrict__ bvec,
    u16* __restrict__ out, float* __restrict__ srow) {
  __shared__ float red[8];
  const int row = blockIdx.x, tid = threadIdx.x;
  const float4* p0 = (const float4*)(part + (size_t)row * D_DIM);
  const float4* p1 = (const float4*)(part + (size_t)S_LEN * D_DIM + (size_t)row * D_DIM);
  const float4* rr = (const float4*)(res + (size_t)row * D_DIM);
  const float4* b4 = (const float4*)bias;
  const float4* g4 = (const float4*)g;
  const float4* e4 = (const float4*)bvec;

  float4 a0 = p0[tid], a1 = p0[tid + 256];
  float4 q0 = p1[tid], q1 = p1[tid + 256];
  float4 r0 = rr[tid], r1 = rr[tid + 256];
  float4 c0 = b4[tid], c1 = b4[tid + 256];
  float4 v0, v1;
  v0.x = a0.x + q0.x + c0.x + r0.x; v0.y = a0.y + q0.y + c0.y + r0.y;
  v0.z = a0.z + q0.z + c0.z + r0.z; v0.w = a0.w + q0.w + c0.w + r0.w;
  v1.x = a1.x + q1.x + c1.x + r1.x; v1.y = a1.y + q1.y + c1.y + r1.y;
  v1.z = a1.z + q1.z + c1.z + r1.z; v1.w = a1.w + q1.w + c1.w + r1.w;
  float* h2r = h2out + (size_t)row * D_DIM;
  *(float4*)&h2r[tid * 4] = v0;
  *(float4*)&h2r[1024 + tid * 4] = v1;

  float s = v0.x + v0.y + v0.z + v0.w + v1.x + v1.y + v1.z + v1.w;
  float ss = v0.x * v0.x + v0.y * v0.y + v0.z * v0.z + v0.w * v0.w +
             v1.x * v1.x + v1.y * v1.y + v1.z * v1.z + v1.w * v1.w;
  s = wred_sum(s); ss = wred_sum(ss);
  if ((tid & 63) == 0) { red[tid >> 6] = s; red[4 + (tid >> 6)] = ss; }
  __syncthreads();
  float mu = (red[0] + red[1] + red[2] + red[3]) / (float)D_DIM;
  float var = (red[4] + red[5] + red[6] + red[7]) / (float)D_DIM - mu * mu;
  float rstd = 1.0f / sqrtf(var + 1e-5f);
  __syncthreads();

  float mn = 0.f, mx = 0.f;
  float4 n0, n1;
  {
    float4 gg = g4[tid], bb = e4[tid];
    n0.x = (v0.x - mu) * rstd * gg.x + bb.x; n0.y = (v0.y - mu) * rstd * gg.y + bb.y;
    n0.z = (v0.z - mu) * rstd * gg.z + bb.z; n0.w = (v0.w - mu) * rstd * gg.w + bb.w;
    gg = g4[tid + 256]; bb = e4[tid + 256];
    n1.x = (v1.x - mu) * rstd * gg.x + bb.x; n1.y = (v1.y - mu) * rstd * gg.y + bb.y;
    n1.z = (v1.z - mu) * rstd * gg.z + bb.z; n1.w = (v1.w - mu) * rstd * gg.w + bb.w;
    mn = fminf(mn, fminf(fminf(n0.x, n0.y), fminf(n0.z, n0.w)));
    mn = fminf(mn, fminf(fminf(n1.x, n1.y), fminf(n1.z, n1.w)));
    mx = fmaxf(mx, fmaxf(fmaxf(n0.x, n0.y), fmaxf(n0.z, n0.w)));
    mx = fmaxf(mx, fmaxf(fmaxf(n1.x, n1.y), fmaxf(n1.z, n1.w)));
  }
  mn = wred_min(mn); mx = wred_max(mx);
  if ((tid & 63) == 0) { red[tid >> 6] = mn; red[4 + (tid >> 6)] = mx; }
  __syncthreads();
  mn = fminf(fminf(red[0], red[1]), fminf(red[2], red[3]));
  mx = fmaxf(fmaxf(red[4], red[5]), fmaxf(red[6], red[7]));
  float scale = fmaxf((mx - mn) / QMAX, 1e-5f);
  float zp = rintf(-mn / scale);
  if (tid == 0) srow[row] = scale;
  ushort4 o0, o1;
  o0.x = f32i_to_bf16(fminf(fmaxf(rintf(n0.x / scale) + zp, 0.f), QMAX) - zp);
  o0.y = f32i_to_bf16(fminf(fmaxf(rintf(n0.y / scale) + zp, 0.f), QMAX) - zp);
  o0.z = f32i_to_bf16(fminf(fmaxf(rintf(n0.z / scale) + zp, 0.f), QMAX) - zp);
  o0.w = f32i_to_bf16(fminf(fmaxf(rintf(n0.w / scale) + zp, 0.f), QMAX) - zp);
  o1.x = f32i_to_bf16(fminf(fmaxf(rintf(n1.x / scale) + zp, 0.f), QMAX) - zp);
  o1.y = f32i_to_bf16(fminf(fmaxf(rintf(n1.y / scale) + zp, 0.f), QMAX) - zp);
  o1.z = f32i_to_bf16(fminf(fmaxf(rintf(n1.z / scale) + zp, 0.f), QMAX) - zp);
  o1.w = f32i_to_bf16(fminf(fmaxf(rintf(n1.w / scale) + zp, 0.f), QMAX) - zp);
  *(ushort4*)&out[(size_t)row * D_DIM + tid * 4] = o0;
  *(ushort4*)&out[(size_t)row * D_DIM + 1024 + tid * 4] = o1;
}

// ---- fp32 row -> quant -> bf16 int + scale (for attention ctx) ----
__global__ __launch_bounds__(256) void act_quant_bf16(const float* __restrict__ x,
                                                      u16* __restrict__ out,
                                                      float* __restrict__ srow,
                                                      int N) {
  __shared__ float red[8];
  const int row = blockIdx.x, tid = threadIdx.x;
  const float4* xr = (const float4*)(x + (size_t)row * N);
  const int N4 = N >> 2;
  float mn = 0.f, mx = 0.f;
  for (int i = tid; i < N4; i += 256) {
    float4 v = xr[i];
    mn = fminf(mn, fminf(fminf(v.x, v.y), fminf(v.z, v.w)));
    mx = fmaxf(mx, fmaxf(fmaxf(v.x, v.y), fmaxf(v.z, v.w)));
  }
  mn = wred_min(mn); mx = wred_max(mx);
  if ((tid & 63) == 0) { red[tid >> 6] = mn; red[4 + (tid >> 6)] = mx; }
  __syncthreads();
  mn = fminf(fminf(red[0], red[1]), fminf(red[2], red[3]));
  mx = fmaxf(fmaxf(red[4], red[5]), fmaxf(red[6], red[7]));
  float scale = fmaxf((mx - mn) / QMAX, 1e-5f);
  float zp = rintf(-mn / scale);
  if (tid == 0) srow[row] = scale;
  for (int i = tid; i < N4; i += 256) {
    float4 v = xr[i];
    ushort4 o;
    o.x = f32i_to_bf16(fminf(fmaxf(rintf(v.x / scale) + zp, 0.f), QMAX) - zp);
    o.y = f32i_to_bf16(fminf(fmaxf(rintf(v.y / scale) + zp, 0.f), QMAX) - zp);
    o.z = f32i_to_bf16(fminf(fmaxf(rintf(v.z / scale) + zp, 0.f), QMAX) - zp);
    o.w = f32i_to_bf16(fminf(fmaxf(rintf(v.w / scale) + zp, 0.f), QMAX) - zp);
    *(ushort4*)&out[(size_t)row * N + i * 4] = o;
  }
}

// ---- weight row quant -> bf16 int + per-row scale ----
__global__ __launch_bounds__(256) void wquant(const float* __restrict__ W,
                                              u16* __restrict__ Wi,
                                              float* __restrict__ sc, int K) {
  __shared__ float red[8];
  const int row = blockIdx.x, tid = threadIdx.x;
  const float4* wr = (const float4*)(W + (size_t)row * K);
  const int K4 = K >> 2;
  float mn = 0.f, mx = 0.f;
  for (int i = tid; i < K4; i += 256) {
    float4 v = wr[i];
    mn = fminf(mn, fminf(fminf(v.x, v.y), fminf(v.z, v.w)));
    mx = fmaxf(mx, fmaxf(fmaxf(v.x, v.y), fmaxf(v.z, v.w)));
  }
  mn = wred_min(mn); mx = wred_max(mx);
  if ((tid & 63) == 0) { red[tid >> 6] = mn; red[4 + (tid >> 6)] = mx; }
  __syncthreads();
  mn = fminf(fminf(red[0], red[1]), fminf(red[2], red[3]));
  mx = fmaxf(fmaxf(red[4], red[5]), fmaxf(red[6], red[7]));
  float scale = fmaxf((mx - mn) / QMAX, 1e-5f);
  float zp = rintf(-mn / scale);
  if (tid == 0) sc[row] = scale;
  for (int i = tid; i < K4; i += 256) {
    float4 v = wr[i];
    ushort4 o;
    o.x = f32i_to_bf16(fminf(fmaxf(rintf(v.x / scale) + zp, 0.f), QMAX) - zp);
    o.y = f32i_to_bf16(fminf(fmaxf(rintf(v.y / scale) + zp, 0.f), QMAX) - zp);
    o.z = f32i_to_bf16(fminf(fmaxf(rintf(v.z / scale) + zp, 0.f), QMAX) - zp);
    o.w = f32i_to_bf16(fminf(fmaxf(rintf(v.w / scale) + zp, 0.f), QMAX) - zp);
    *(ushort4*)&Wi[(size_t)row * K + i * 4] = o;
  }
}

// ---- requant: bf16 values + per-tile min/max -> bf16 ints (or fake-quant values) ----
__global__ __launch_bounds__(256) void requant(const u16* __restrict__ vals,
                                               const float* __restrict__ tmn,
                                               const float* __restrict__ tmx,
                                               int NT, u16* __restrict__ out,
                                               float* __restrict__ srow,
                                               int N, int value_mode) {
  __shared__ float red[8];
  const int row = blockIdx.x, tid = threadIdx.x;
  float mn = 0.f, mx = 0.f;
  if (tid < NT) {
    mn = tmn ? tmn[(size_t)row * NT + tid] : 0.f;
    mx = tmx[(size_t)row * NT + tid];
  }
  mn = wred_min(mn); mx = wred_max(mx);
  if ((tid & 63) == 0) { red[tid >> 6] = mn; red[4 + (tid >> 6)] = mx; }
  __syncthreads();
  mn = fminf(fminf(red[0], red[1]), fminf(red[2], red[3]));
  mx = fmaxf(fmaxf(red[4], red[5]), fmaxf(red[6], red[7]));
  mn = fminf(mn, 0.f); mx = fmaxf(mx, 0.f);
  float scale = fmaxf((mx - mn) / QMAX, 1e-5f);
  float zp = rintf(-mn / scale);
  if (srow && tid == 0) srow[row] = scale;
  const ushort4* vr = (const ushort4*)(vals + (size_t)row * N);
  ushort4* orow = (ushort4*)(out + (size_t)row * N);
  const int N4 = N >> 2;
  for (int i = tid; i < N4; i += 256) {
    ushort4 u = vr[i];
    float q0 = fminf(fmaxf(rintf(bf16_to_f32(u.x) / scale) + zp, 0.f), QMAX) - zp;
    float q1 = fminf(fmaxf(rintf(bf16_to_f32(u.y) / scale) + zp, 0.f), QMAX) - zp;
    float q2 = fminf(fmaxf(rintf(bf16_to_f32(u.z) / scale) + zp, 0.f), QMAX) - zp;
    float q3 = fminf(fmaxf(rintf(bf16_to_f32(u.w) / scale) + zp, 0.f), QMAX) - zp;
    ushort4 o;
    if (value_mode) {
      o.x = f32_to_bf16_rne(q0 * scale); o.y = f32_to_bf16_rne(q1 * scale);
      o.z = f32_to_bf16_rne(q2 * scale); o.w = f32_to_bf16_rne(q3 * scale);
    } else {
      o.x = f32i_to_bf16(q0); o.y = f32i_to_bf16(q1);
      o.z = f32i_to_bf16(q2); o.w = f32i_to_bf16(q3);
    }
    orow[i] = o;
  }
}

// ---- 3-stage pipelined 128x128x32 MFMA body: counted vmcnt, 1 barrier/K-step ----
// LDS layout swizzle: slot s of row r holds global k-chunk (s ^ (r&3)); reads use
// chunk' = lk ^ (lr&3). Source-side pre-swizzle keeps gload_lds dests linear (rule #21).
__device__ __forceinline__ void gemm128_acc_p3(
    const u16* __restrict__ A, const u16* __restrict__ B,
    int K, int bm, int bn, int k_begin, int k_end,
    u16* As, u16* Bs, f32x4 (&acc)[4][4]) {
  const int tid = threadIdx.x;
  const int wid = tid >> 6, lane = tid & 63;
  const int wr = wid >> 1, wc = wid & 1;
  const int lr = lane & 15, lk = lane >> 4;
  const int r0 = tid >> 2;
  const int r1 = 64 + r0;
  const int c0 = ((tid & 3) ^ (r0 & 3)) * 8;  // pre-swizzled source chunk (r1&3==r0&3)
  const size_t ldsb0 = (size_t)(wid * 64) * 8;
  const size_t ldsb1 = (size_t)(256 + wid * 64) * 8;
  const int cs = (lk ^ (lr & 3)) * 8;         // swizzled read chunk

  const u16* Ag0 = A + (size_t)(bm + r0) * K + c0;
  const u16* Ag1 = A + (size_t)(bm + r1) * K + c0;
  const u16* Bg0 = B + (size_t)(bn + r0) * K + c0;
  const u16* Bg1 = B + (size_t)(bn + r1) * K + c0;

  const int nt = (k_end - k_begin) >> 5;

#define STAGE_P3(t)                                   \
  {                                                   \
    const int _k = k_begin + (t) * 32;                \
    u16* _Ab = As + (size_t)((t) % 3) * 4096;         \
    u16* _Bb = Bs + (size_t)((t) % 3) * 4096;         \
    gload_lds16(Ag0 + _k, _Ab + ldsb0);               \
    gload_lds16(Ag1 + _k, _Ab + ldsb1);               \
    gload_lds16(Bg0 + _k, _Bb + ldsb0);               \
    gload_lds16(Bg1 + _k, _Bb + ldsb1);               \
  }

  STAGE_P3(0);
  if (nt > 1) STAGE_P3(1);

  for (int t = 0; t < nt; ++t) {
    // own 4 loads of tile t complete (t+1's may stay in flight), then join
    if (t + 1 < nt) asm volatile("s_waitcnt vmcnt(4)" ::: "memory");
    else            asm volatile("s_waitcnt vmcnt(0)" ::: "memory");
    __builtin_amdgcn_s_barrier();
    __builtin_amdgcn_sched_barrier(0);
    const u16* Ac = As + (size_t)(t % 3) * 4096;
    const u16* Bc = Bs + (size_t)(t % 3) * 4096;
    bf16x8 af[4], bf[4];
#pragma unroll
    for (int mi = 0; mi < 4; ++mi)
      af[mi] = *(const bf16x8*)&Ac[(size_t)(wr * 64 + mi * 16 + lr) * 32 + cs];
#pragma unroll
    for (int ni = 0; ni < 4; ++ni)
      bf[ni] = *(const bf16x8*)&Bc[(size_t)(wc * 64 + ni * 16 + lr) * 32 + cs];
    if (t + 2 < nt) STAGE_P3(t + 2);  // flies under MFMA + next iteration
#pragma unroll
    for (int mi = 0; mi < 4; ++mi)
#pragma unroll
      for (int ni = 0; ni < 4; ++ni)
        acc[mi][ni] = __builtin_amdgcn_mfma_f32_16x16x32_bf16(af[mi], bf[ni], acc[mi][ni], 0, 0, 0);
  }
#undef STAGE_P3
}

// ---- fused QKV: C = (acc*sa*sb + bias) [*0.125 for q] -> bf16 values + tile min/max ----
__global__ __launch_bounds__(256) void gemm_qkv128(
    const u16* __restrict__ A, const float* __restrict__ sa,
    const u16* __restrict__ Bq, const float* __restrict__ sbq, const float* __restrict__ biasq,
    u16* __restrict__ Cq, float* __restrict__ tqmn, float* __restrict__ tqmx,
    const u16* __restrict__ Bk, const float* __restrict__ sbk, const float* __restrict__ biask,
    u16* __restrict__ Ck, float* __restrict__ tkmn, float* __restrict__ tkmx,
    const u16* __restrict__ Bv, const float* __restrict__ sbv, const float* __restrict__ biasv,
    u16* __restrict__ Cv, float* __restrict__ tvmn, float* __restrict__ tvmx) {
  __shared__ __align__(16) u16 As[3 * 128 * 32], Bs[3 * 128 * 32];
  int bx, by; xcd_swz(bx, by);
  const int which = bx >> 4;          // 16 col-tiles per weight
  const int bn = (bx & 15) * 128;
  const int bm = by * 128;
  const u16* B = (which == 0) ? Bq : (which == 1) ? Bk : Bv;
  const float* sb = (which == 0) ? sbq : (which == 1) ? sbk : sbv;
  const float* bias = (which == 0) ? biasq : (which == 1) ? biask : biasv;
  u16* C = (which == 0) ? Cq : (which == 1) ? Ck : Cv;
  float* tmn = (which == 0) ? tqmn : (which == 1) ? tkmn : tvmn;
  float* tmx = (which == 0) ? tqmx : (which == 1) ? tkmx : tvmx;
  const float alpha = (which == 0) ? 0.125f : 1.0f;

  f32x4 acc[4][4] = {};
  gemm128_acc_p3(A, B, D_DIM, bm, bn, 0, D_DIM, As, Bs, acc);

  const int tid = threadIdx.x;
  const int wid = tid >> 6, lane = tid & 63;
  const int wr = wid >> 1, wc = wid & 1;
  const int lr = lane & 15, lk = lane >> 4;
  const int col0 = bn + wc * 64 + lr;
  const int rbase = bm + wr * 64 + lk * 4;
  const int tci = (bn >> 6) + wc;     // 64-col tile index, NT = 32
  float sbc[4], bc[4];
#pragma unroll
  for (int ni = 0; ni < 4; ++ni) { sbc[ni] = sb[col0 + ni * 16]; bc[ni] = bias[col0 + ni * 16]; }
#pragma unroll
  for (int mi = 0; mi < 4; ++mi) {
#pragma unroll
    for (int r = 0; r < 4; ++r) {
      const int row = rbase + mi * 16 + r;
      const float sar = sa[row];
      float v[4];
#pragma unroll
      for (int ni = 0; ni < 4; ++ni)
        v[ni] = (acc[mi][ni][r] * sar * sbc[ni] + bc[ni]) * alpha;
#pragma unroll
      for (int ni = 0; ni < 4; ++ni)
        C[(size_t)row * D_DIM + col0 + ni * 16] = f32_to_bf16_rne(v[ni]);
      float mnv = fminf(fminf(v[0], v[1]), fminf(v[2], v[3]));
      float mxv = fmaxf(fmaxf(v[0], v[1]), fmaxf(v[2], v[3]));
      mnv = fminf(mnv, __shfl_xor(mnv, 1, 64)); mxv = fmaxf(mxv, __shfl_xor(mxv, 1, 64));
      mnv = fminf(mnv, __shfl_xor(mnv, 2, 64)); mxv = fmaxf(mxv, __shfl_xor(mxv, 2, 64));
      mnv = fminf(mnv, __shfl_xor(mnv, 4, 64)); mxv = fmaxf(mxv, __shfl_xor(mxv, 4, 64));
      mnv = fminf(mnv, __shfl_xor(mnv, 8, 64)); mxv = fmaxf(mxv, __shfl_xor(mxv, 8, 64));
      if (lr == 0) {
        tmn[(size_t)row * 32 + tci] = mnv;
        tmx[(size_t)row * 32 + tci] = mxv;
      }
    }
  }
}

// ---- W1: C = relu(acc*sa*sb + bias) -> bf16 values + tile row-max ----
__global__ __launch_bounds__(256) void gemm_w1(
    const u16* __restrict__ A, const float* __restrict__ sa,
    const u16* __restrict__ B, const float* __restrict__ sb,
    const float* __restrict__ bias,
    u16* __restrict__ C, float* __restrict__ tmx) {
  __shared__ __align__(16) u16 As[3 * 128 * 32], Bs[3 * 128 * 32];
  int bx, by; xcd_swz(bx, by);
  const int bn = bx * 128, bm = by * 128;

  f32x4 acc[4][4] = {};
  gemm128_acc_p3(A, B, D_DIM, bm, bn, 0, D_DIM, As, Bs, acc);

  const int tid = threadIdx.x;
  const int wid = tid >> 6, lane = tid & 63;
  const int wr = wid >> 1, wc = wid & 1;
  const int lr = lane & 15, lk = lane >> 4;
  const int col0 = bn + wc * 64 + lr;
  const int rbase = bm + wr * 64 + lk * 4;
  const int tci = (bn >> 6) + wc;     // NT = 128
  float sbc[4], bc[4];
#pragma unroll
  for (int ni = 0; ni < 4; ++ni) { sbc[ni] = sb[col0 + ni * 16]; bc[ni] = bias[col0 + ni * 16]; }
#pragma unroll
  for (int mi = 0; mi < 4; ++mi) {
#pragma unroll
    for (int r = 0; r < 4; ++r) {
      const int row = rbase + mi * 16 + r;
      const float sar = sa[row];
      float v[4];
#pragma unroll
      for (int ni = 0; ni < 4; ++ni)
        v[ni] = fmaxf(acc[mi][ni][r] * sar * sbc[ni] + bc[ni], 0.f);
#pragma unroll
      for (int ni = 0; ni < 4; ++ni)
        C[(size_t)row * FF_DIM + col0 + ni * 16] = f32_to_bf16_rne(v[ni]);
      float mxv = fmaxf(fmaxf(v[0], v[1]), fmaxf(v[2], v[3]));
      mxv = fmaxf(mxv, __shfl_xor(mxv, 1, 64));
      mxv = fmaxf(mxv, __shfl_xor(mxv, 2, 64));
      mxv = fmaxf(mxv, __shfl_xor(mxv, 4, 64));
      mxv = fmaxf(mxv, __shfl_xor(mxv, 8, 64));
      if (lr == 0) tmx[(size_t)row * 128 + tci] = mxv;
    }
  }
}

// ---- split-K partial GEMM: part[z] = sa*sb*(A@B^T) over K-chunk z ----
__global__ __launch_bounds__(256) void gemm_splitk(
    const u16* __restrict__ A, const float* __restrict__ sa,
    const u16* __restrict__ B, const float* __restrict__ sb,
    float* __restrict__ part, int N, int K, int kchunk) {
  __shared__ __align__(16) u16 As[3 * 128 * 32], Bs[3 * 128 * 32];
  int bx, by; xcd_swz(bx, by);
  const int bm = by * 128, bn = bx * 128;
  const int ks = blockIdx.z;
  f32x4 acc[4][4] = {};
  gemm128_acc_p3(A, B, K, bm, bn, ks * kchunk, (ks + 1) * kchunk, As, Bs, acc);

  float* dst = part + (size_t)ks * S_LEN * N;
  const int tid = threadIdx.x;
  const int wid = tid >> 6, lane = tid & 63;
  const int wr = wid >> 1, wc = wid & 1;
  const int lr = lane & 15, lk = lane >> 4;
  const int col0 = bn + wc * 64 + lr;
  const int rbase = bm + wr * 64 + lk * 4;
#pragma unroll
  for (int ni = 0; ni < 4; ++ni) {
    const int col = col0 + ni * 16;
    const float sbc = sb[col];
#pragma unroll
    for (int mi = 0; mi < 4; ++mi)
#pragma unroll
      for (int r = 0; r < 4; ++r) {
        const int row = rbase + mi * 16 + r;
        dst[(size_t)row * N + col] = acc[mi][ni][r] * sa[row] * sbc;
      }
  }
}

// ---- split-K reduce: out = sum(part) + bias (+res) ----
__global__ __launch_bounds__(256) void splitk_reduce(
    const float* __restrict__ part, int nsplit,
    const float* __restrict__ bias, const float* __restrict__ res,
    float* __restrict__ out, int N) {
  const size_t stride4 = (size_t)S_LEN * N / 4;
  const int n4 = N >> 2;
  for (size_t i = (size_t)blockIdx.x * 256 + threadIdx.x; i < stride4;
       i += (size_t)gridDim.x * 256) {
    float4 s = ((const float4*)part)[i];
    for (int k = 1; k < nsplit; ++k) {
      float4 p = ((const float4*)part)[i + (size_t)k * stride4];
      s.x += p.x; s.y += p.y; s.z += p.z; s.w += p.w;
    }
    float4 b4 = ((const float4*)bias)[i % n4];
    s.x += b4.x; s.y += b4.y; s.z += b4.z; s.w += b4.w;
    if (res) {
      float4 r = ((const float4*)res)[i];
      s.x += r.x; s.y += r.y; s.z += r.z; s.w += r.w;
    }
    ((float4*)out)[i] = s;
  }
}

// ---- fused causal attention with quantized probs, MFMA both passes ----
__global__ __launch_bounds__(256) void attn_fused(
    const u16* __restrict__ qi, const float* __restrict__ sq,
    const u16* __restrict__ ki, const float* __restrict__ sk,
    const u16* __restrict__ vf, float* __restrict__ ctx) {
  __shared__ __align__(16) u16 Qs[64][72];
  __shared__ __align__(16) u16 Ks[64][72];
  __shared__ __align__(16) u16 Ps[64][72];
  __shared__ __align__(16) u16 Vt[64][72];
  const int bid = blockIdx.x;
  const int ti = (S_LEN / 64 - 1) - (bid >> 5);  // heavy tiles first
  const int h = bid & (H_NUM - 1);
  const int i0 = ti * 64;
  const int tid = threadIdx.x;
  const int wid = tid >> 6, lane = tid & 63;
  const int lr = lane & 15, g = lane >> 4;
  const size_t hbase = (size_t)h * HD_DIM;

  const int r_a = tid >> 3, ch_a = tid & 7;
  const int r_b = 32 + r_a;
  const int jr_v = tid & 63, ch_v = tid >> 6;

  for (int c = tid; c < 512; c += 256) {
    int r = c >> 3, ch = c & 7;
    *(float4*)&Qs[r][ch * 8] =
        *(const float4*)&qi[(size_t)(i0 + r) * D_DIM + hbase + ch * 8];
  }
  float sq4[4];
#pragma unroll
  for (int r = 0; r < 4; ++r) sq4[r] = sq[i0 + wid * 16 + g * 4 + r];
  __syncthreads();

  const int ntiles = i0 / 64 + 1;
  float m_r[4] = {-1e30f, -1e30f, -1e30f, -1e30f};
  float l_r[4] = {0.f, 0.f, 0.f, 0.f};

  float4 ka0 = *(const float4*)&ki[(size_t)r_a * D_DIM + hbase + ch_a * 8];
  float4 ka1 = *(const float4*)&ki[(size_t)r_b * D_DIM + hbase + ch_a * 8];
  for (int t = 0; t < ntiles; ++t) {
    __syncthreads();
    *(float4*)&Ks[r_a][ch_a * 8] = ka0;
    *(float4*)&Ks[r_b][ch_a * 8] = ka1;
    __syncthreads();
    if (t + 1 < ntiles) {
      const int jn = (t + 1) * 64;
      ka0 = *(const float4*)&ki[(size_t)(jn + r_a) * D_DIM + hbase + ch_a * 8];
      ka1 = *(const float4*)&ki[(size_t)(jn + r_b) * D_DIM + hbase + ch_a * 8];
    }

    bf16x8 aq0 = *(const bf16x8*)&Qs[wid * 16 + lr][g * 8];
    bf16x8 aq1 = *(const bf16x8*)&Qs[wid * 16 + lr][32 + g * 8];
    f32x4 accs[4] = {};
#pragma unroll
    for (int ni = 0; ni < 4; ++ni) {
      bf16x8 b0 = *(const bf16x8*)&Ks[ni * 16 + lr][g * 8];
      bf16x8 b1 = *(const bf16x8*)&Ks[ni * 16 + lr][32 + g * 8];
      accs[ni] = __builtin_amdgcn_mfma_f32_16x16x32_bf16(aq0, b0, accs[ni], 0, 0, 0);
      accs[ni] = __builtin_amdgcn_mfma_f32_16x16x32_bf16(aq1, b1, accs[ni], 0, 0, 0);
    }

    const int jt = t * 64;
    float sv[4][4];
#pragma unroll
    for (int ni = 0; ni < 4; ++ni) {
      const float skc = sk[jt + ni * 16 + lr];
#pragma unroll
      for (int r = 0; r < 4; ++r) sv[ni][r] = accs[ni][r] * sq4[r] * skc;
    }
    if (t == ntiles - 1) {
      const int jcol = jt + lr, irow = i0 + wid * 16 + g * 4;
#pragma unroll
      for (int ni = 0; ni < 4; ++ni)
#pragma unroll
        for (int r = 0; r < 4; ++r)
          if (jcol + ni * 16 > irow + r) sv[ni][r] = -1e30f;
    }
#pragma unroll
    for (int r = 0; r < 4; ++r) {
      float tmax = fmaxf(fmaxf(sv[0][r], sv[1][r]), fmaxf(sv[2][r], sv[3][r]));
      tmax = fmaxf(tmax, __shfl_xor(tmax, 1, 64));
      tmax = fmaxf(tmax, __shfl_xor(tmax, 2, 64));
      tmax = fmaxf(tmax, __shfl_xor(tmax, 4, 64));
      tmax = fmaxf(tmax, __shfl_xor(tmax, 8, 64));
      float mnew = fmaxf(m_r[r], tmax);
      float sum = __expf(sv[0][r] - mnew) + __expf(sv[1][r] - mnew) +
                  __expf(sv[2][r] - mnew) + __expf(sv[3][r] - mnew);
      sum += __shfl_xor(sum, 1, 64);
      sum += __shfl_xor(sum, 2, 64);
      sum += __shfl_xor(sum, 4, 64);
      sum += __shfl_xor(sum, 8, 64);
      l_r[r] = l_r[r] * __expf(m_r[r] - mnew) + sum;
      m_r[r] = mnew;
    }
  }

  float qsc[4], idn[4];
#pragma unroll
  for (int r = 0; r < 4; ++r) {
    float sc = fmaxf((1.0f / l_r[r]) / QMAX, 1e-5f);
    qsc[r] = sc;
    idn[r] = 1.0f / (l_r[r] * sc);
  }

  f32x4 acco[4] = {};
  float4 kb0 = *(const float4*)&ki[(size_t)r_a * D_DIM + hbase + ch_a * 8];
  float4 kb1 = *(const float4*)&ki[(size_t)r_b * D_DIM + hbase + ch_a * 8];
  float4 vb0 = *(const float4*)&vf[(size_t)jr_v * D_DIM + hbase + ch_v * 8];
  float4 vb1 = *(const float4*)&vf[(size_t)jr_v * D_DIM + hbase + (4 + ch_v) * 8];
  for (int t = 0; t < ntiles; ++t) {
    __syncthreads();
    *(float4*)&Ks[r_a][ch_a * 8] = kb0;
    *(float4*)&Ks[r_b][ch_a * 8] = kb1;
    {
      const u16* v0 = (const u16*)&vb0;
      const u16* v1 = (const u16*)&vb1;
#pragma unroll
      for (int e = 0; e < 8; ++e) Vt[ch_v * 8 + e][jr_v] = v0[e];
#pragma unroll
      for (int e = 0; e < 8; ++e) Vt[(4 + ch_v) * 8 + e][jr_v] = v1[e];
    }
    __syncthreads();
    if (t + 1 < ntiles) {
      const int jn = (t + 1) * 64;
      kb0 = *(const float4*)&ki[(size_t)(jn + r_a) * D_DIM + hbase + ch_a * 8];
      kb1 = *(const float4*)&ki[(size_t)(jn + r_b) * D_DIM + hbase + ch_a * 8];
      vb0 = *(const float4*)&vf[(size_t)(jn + jr_v) * D_DIM + hbase + ch_v * 8];
      vb1 = *(const float4*)&vf[(size_t)(jn + jr_v) * D_DIM + hbase + (4 + ch_v) * 8];
    }

    bf16x8 aq0 = *(const bf16x8*)&Qs[wid * 16 + lr][g * 8];
    bf16x8 aq1 = *(const bf16x8*)&Qs[wid * 16 + lr][32 + g * 8];
    f32x4 accs[4] = {};
#pragma unroll
    for (int ni = 0; ni < 4; ++ni) {
      bf16x8 b0 = *(const bf16x8*)&Ks[ni * 16 + lr][g * 8];
      bf16x8 b1 = *(const bf16x8*)&Ks[ni * 16 + lr][32 + g * 8];
      accs[ni] = __builtin_amdgcn_mfma_f32_16x16x32_bf16(aq0, b0, accs[ni], 0, 0, 0);
      accs[ni] = __builtin_amdgcn_mfma_f32_16x16x32_bf16(aq1, b1, accs[ni], 0, 0, 0);
    }

    const int jt = t * 64;
    const bool diag = (t == ntiles - 1);
    const int jcol = jt + lr, irow = i0 + wid * 16 + g * 4;
#pragma unroll
    for (int ni = 0; ni < 4; ++ni) {
      const float skc = sk[jt + ni * 16 + lr];
#pragma unroll
      for (int r = 0; r < 4; ++r) {
        float s = accs[ni][r] * sq4[r] * skc;
        if (diag && (jcol + ni * 16 > irow + r)) s = -1e30f;
        float e = __expf(s - m_r[r]);
        float q8 = fminf(fmaxf(rintf(e * idn[r]), 0.f), QMAX);
        Ps[wid * 16 + g * 4 + r][ni * 16 + lr] = f32i_to_bf16(q8);
      }
    }
    // Ps rows for this wave are wave-local: no barrier needed

    bf16x8 ap0 = *(const bf16x8*)&Ps[wid * 16 + lr][g * 8];
    bf16x8 ap1 = *(const bf16x8*)&Ps[wid * 16 + lr][32 + g * 8];
#pragma unroll
    for (int ni = 0; ni < 4; ++ni) {
      bf16x8 b0 = *(const bf16x8*)&Vt[ni * 16 + lr][g * 8];
      bf16x8 b1 = *(const bf16x8*)&Vt[ni * 16 + lr][32 + g * 8];
      acco[ni] = __builtin_amdgcn_mfma_f32_16x16x32_bf16(ap0, b0, acco[ni], 0, 0, 0);
      acco[ni] = __builtin_amdgcn_mfma_f32_16x16x32_bf16(ap1, b1, acco[ni], 0, 0, 0);
    }
  }

#pragma unroll
  for (int ni = 0; ni < 4; ++ni)
#pragma unroll
    for (int r = 0; r < 4; ++r) {
      const int row = i0 + wid * 16 + g * 4 + r;
      ctx[(size_t)row * D_DIM + hbase + ni * 16 + lr] = acco[ni][r] * qsc[r];
    }
}

extern "C" void kernel_launch(void* const* d_in, const int* in_sizes, int n_in,
                              void* d_out, int out_size, void* d_ws, size_t ws_size,
                              hipStream_t stream) {
  (void)in_sizes; (void)n_in; (void)out_size;
  const float* hs  = (const float*)d_in[0];
  const float* Wq  = (const float*)d_in[2];
  const float* bq  = (const float*)d_in[3];
  const float* Wk  = (const float*)d_in[4];
  const float* bk  = (const float*)d_in[5];
  const float* Wv  = (const float*)d_in[6];
  const float* bv  = (const float*)d_in[7];
  const float* Wo  = (const float*)d_in[8];
  const float* bo  = (const float*)d_in[9];
  const float* g1  = (const float*)d_in[10];
  const float* be1 = (const float*)d_in[11];
  const float* W1  = (const float*)d_in[12];
  const float* bf1 = (const float*)d_in[13];
  const float* W2  = (const float*)d_in[14];
  const float* bf2 = (const float*)d_in[15];
  const float* g2  = (const float*)d_in[16];
  const float* be2 = (const float*)d_in[17];
  float* out = (float*)d_out;

  const size_t SD = (size_t)S_LEN * D_DIM;
  const size_t SF = (size_t)S_LEN * FF_DIM;

  char* p = (char*)d_ws;
  auto alloc = [&](size_t bytes) { char* r = p; p += (bytes + 255) & ~(size_t)255; return r; };

  float* h2   = (float*)alloc(SD * 4);
  float* sx   = (float*)alloc(S_LEN * 4);
  float* sxf  = (float*)alloc(S_LEN * 4);
  float* sqv  = (float*)alloc(S_LEN * 4);
  float* skv  = (float*)alloc(S_LEN * 4);
  float* swq  = (float*)alloc(D_DIM * 4);
  float* swk  = (float*)alloc(D_DIM * 4);
  float* swv  = (float*)alloc(D_DIM * 4);
  float* swo  = (float*)alloc(D_DIM * 4);
  float* sw1  = (float*)alloc(FF_DIM * 4);
  float* sw2  = (float*)alloc(D_DIM * 4);
  float* tqmn = (float*)alloc(S_LEN * 32 * 4);
  float* tqmx = (float*)alloc(S_LEN * 32 * 4);
  float* tkmn = (float*)alloc(S_LEN * 32 * 4);
  float* tkmx = (float*)alloc(S_LEN * 32 * 4);
  float* tvmn = (float*)alloc(S_LEN * 32 * 4);
  float* tvmx = (float*)alloc(S_LEN * 32 * 4);
  float* tf1x = (float*)alloc(S_LEN * 128 * 4);
  u16* xi  = (u16*)alloc(SD * 2);
  u16* wqi = (u16*)alloc(SD * 2);
  u16* wki = (u16*)alloc(SD * 2);
  u16* wvi = (u16*)alloc(SD * 2);
  u16* woi = (u16*)alloc(SD * 2);
  u16* w1i = (u16*)alloc(SF * 2);
  u16* w2i = (u16*)alloc(SF * 2);
  char* arena = alloc(8 * SD * 2);   // 8 SD-u16 units, phase-aliased
  // phase QKV/attn:
  u16* qv   = (u16*)arena;           // units 0-1
  u16* kv   = qv + SD;               // 1-2
  u16* vv   = kv + SD;               // 2-3
  u16* qi8  = vv + SD;               // 3-4
  u16* ki8  = qi8 + SD;              // 4-5
  u16* vfb  = ki8 + SD;              // 5-6
  float* ctxb = (float*)(vfb + SD);  // 6-8 (fp32 SD)
  // phase Wo:
  float* pwo = (float*)arena;        // 0-4 (2*SD fp32)
  // phase FFN:
  u16* f1v = (u16*)arena;            // 0-4 (SF u16)
  u16* f1i = (u16*)(arena + 4 * SD * 2); // 4-8 (SF u16)
  float* pw2 = (float*)arena;        // 0-4 (2*SD fp32), f1v dead by then
  size_t need = (size_t)(p - (char*)d_ws);
  if (ws_size < need) return;  // fail loudly rather than corrupt

  dim3 blk(256);

  wquant<<<D_DIM, blk, 0, stream>>>(Wq, wqi, swq, D_DIM);
  wquant<<<D_DIM, blk, 0, stream>>>(Wk, wki, swk, D_DIM);
  wquant<<<D_DIM, blk, 0, stream>>>(Wv, wvi, swv, D_DIM);
  wquant<<<D_DIM, blk, 0, stream>>>(Wo, woi, swo, D_DIM);
  wquant<<<FF_DIM, blk, 0, stream>>>(W1, w1i, sw1, D_DIM);
  wquant<<<D_DIM, blk, 0, stream>>>(W2, w2i, sw2, FF_DIM);

  ln_quant_bf16<<<S_LEN, blk, 0, stream>>>(hs, g1, be1, xi, sx);

  dim3 gqkv(3 * D_DIM / 128, S_LEN / 128);   // 48 x 16 = 768 blocks
  gemm_qkv128<<<gqkv, blk, 0, stream>>>(xi, sx,
                                        wqi, swq, bq, qv, tqmn, tqmx,
                                        wki, swk, bk, kv, tkmn, tkmx,
                                        wvi, swv, bv, vv, tvmn, tvmx);

  requant<<<S_LEN, blk, 0, stream>>>(qv, tqmn, tqmx, 32, qi8, sqv, D_DIM, 0);
  requant<<<S_LEN, blk, 0, stream>>>(kv, tkmn, tkmx, 32, ki8, skv, D_DIM, 0);
  requant<<<S_LEN, blk, 0, stream>>>(vv, tvmn, tvmx, 32, vfb, nullptr, D_DIM, 1);

  attn_fused<<<(S_LEN / 64) * H_NUM, blk, 0, stream>>>(qi8, sqv, ki8, skv, vfb, ctxb);

  act_quant_bf16<<<S_LEN, blk, 0, stream>>>(ctxb, xi, sx, D_DIM);

  // Wo: split-K=2; fused reduce + residual(hs) + LN2 + quant
  dim3 gwo(D_DIM / 128, S_LEN / 128, 2);
  gemm_splitk<<<gwo, blk, 0, stream>>>(xi, sx, woi, swo, pwo, D_DIM, D_DIM, D_DIM / 2);
  splitk_reduce_ln<<<S_LEN, blk, 0, stream>>>(pwo, bo, hs, h2, g2, be2, xi, sx);

  dim3 gff(FF_DIM / 128, S_LEN / 128);       // 64 x 16 = 1024 blocks
  gemm_w1<<<gff, blk, 0, stream>>>(xi, sx, w1i, sw1, bf1, f1v, tf1x);
  requant<<<S_LEN, blk, 0, stream>>>(f1v, nullptr, tf1x, 128, f1i, sxf, FF_DIM, 0);

  // W2: split-K=2, reduce adds bias + residual(h2)
  dim3 gw2(D_DIM / 128, S_LEN / 128, 2);
  gemm_splitk<<<gw2, blk, 0, stream>>>(f1i, sxf, w2i, sw2, pw2, D_DIM, FF_DIM, FF_DIM / 2);
  splitk_reduce<<<2048, blk, 0, stream>>>(pw2, 2, bf2, h2, out, D_DIM);
}